// Round 14
// baseline (235401.782 us; speedup 1.0000x reference)
//
#include <hip/hip_runtime.h>
#include <math.h>

#define NB 128
#define NS 256
#define ND 512
#define NBS (NB*NS)   // 32768
#define KE 544        // 512 x | 10 back | 20 cnn | 1 bias | 1 pad
#define NC 2560       // 2048 cell gates + 512 leap hidden
#define NBLK 80       // loop blocks: 64 gate (32 cols each) + 16 leap (32 cols each)
#define NGB 64        // gate blocks
#define LDSZ 102464   // 96KB Wl + 4KB W2l + skipsh

typedef unsigned short u16;
typedef __attribute__((ext_vector_type(8))) short s8v;     // 8 bf16
typedef __attribute__((ext_vector_type(4))) float f4v;     // 4 f32 acc
typedef __attribute__((ext_vector_type(2))) float f2v;     // 8B asm payload
typedef __attribute__((ext_vector_type(4))) unsigned uv4;  // 16B asm payload
typedef __attribute__((ext_vector_type(2))) double dv2;    // 16B asm payload

static constexpr size_t PSA  = (size_t)NBS * KE;
static constexpr size_t PSWE = (size_t)NC  * KE;
static constexpr size_t PSWS = (size_t)NC  * ND;
static constexpr size_t PSH  = (size_t)NB  * ND;

// ---------------- device-global scratch ----------------
__device__ double g_A[(size_t)NBS * KE];
__device__ u16    g_Ab[3 * PSA];
__device__ float  g_Pre[(size_t)NBS * NC];    // layout [t][b][n]
__device__ double g_Aproj[(size_t)NBS * 40];
__device__ double g_gum[NS * NB * 2];
__device__ double g_hx[NB * ND];
__device__ u16    g_hxb[3 * NB * ND];
__device__ double g_c[NB * ND];
__device__ float  g_gbufF[NB * NC];           // fused path uses [128][2048] gates region
__device__ double g_final[NB * ND];
__device__ float  g_Wext[PSWE];
__device__ u16    g_Wextb[3 * PSWE];
__device__ float  g_Wstep[PSWS];
__device__ u16    g_Wstepb[3 * PSWS];
__device__ double g_lpart[32][NB][2];         // leap partial logits (16-col groups)
__device__ int    g_aflag[160 * 32];
__device__ int    g_hxf[NB * 32];
__device__ int    g_ok, g_bad, g_badstep, g_badfused;

__device__ __forceinline__ double sigd(double x) { return 1.0 / (1.0 + exp(-x)); }
__device__ __forceinline__ u16 f2bf(float f) {
    unsigned u = __float_as_uint(f);
    return (u16)((u + 0x7FFFu + ((u >> 16) & 1u)) >> 16);   // RNE
}
__device__ __forceinline__ float bf2f(u16 b) { return __uint_as_float(((unsigned)b) << 16); }
__device__ __forceinline__ void decomp3(float f, u16& b0, u16& b1, u16& b2) {
    b0 = f2bf(f); float r1 = f - bf2f(b0);
    b1 = f2bf(r1); float r2 = r1 - bf2f(b1);
    b2 = f2bf(r2);
}
__device__ __forceinline__ size_t pre_ix(int m /*b*NS+s*/, int n) {
    return ((size_t)(m & 255) * NB + (m >> 8)) * NC + n;    // -> [s][b][n]
}
__device__ __forceinline__ void put_Ab(size_t ix, float f) {
    u16 b0, b1, b2; decomp3(f, b0, b1, b2);
    g_Ab[ix] = b0; g_Ab[PSA + ix] = b1; g_Ab[2 * PSA + ix] = b2;
}

// ---- coherence-point (MALL) access helpers ----
__device__ __forceinline__ void sc_store_f32(float* p, float v) {
    asm volatile("global_store_dword %0, %1, off sc0 sc1" :: "v"(p), "v"(v) : "memory");
}
__device__ __forceinline__ void sc_store_u32(void* p, unsigned v) {
    asm volatile("global_store_dword %0, %1, off sc0 sc1" :: "v"(p), "v"(v) : "memory");
}
__device__ __forceinline__ void sc_store_d2(double* p, dv2 v) {
    asm volatile("global_store_dwordx4 %0, %1, off sc0 sc1" :: "v"(p), "v"(v) : "memory");
}
#define SC_WAIT() do { asm volatile("s_waitcnt vmcnt(0)" ::: "memory"); \
                       __builtin_amdgcn_sched_barrier(0); } while (0)

#define MFMA_BF16 __builtin_amdgcn_mfma_f32_16x16x32_bf16
#define STEP6(AP,AC,A0,A1,A2,B0,B1,B2) \
    AP = MFMA_BF16(A0, B0, AP, 0, 0, 0); \
    AC = MFMA_BF16(A0, B1, AC, 0, 0, 0); \
    AC = MFMA_BF16(A1, B0, AC, 0, 0, 0); \
    AC = MFMA_BF16(A0, B2, AC, 0, 0, 0); \
    AC = MFMA_BF16(A1, B1, AC, 0, 0, 0); \
    AC = MFMA_BF16(A2, B0, AC, 0, 0, 0);

// ---------------- bf16 MFMA layout probe ----------------
__global__ void probe_bf16() {
    int l = threadIdx.x, lr = l & 15, lk = l >> 4;
    s8v a, b;
#pragma unroll
    for (int e = 0; e < 8; ++e) {
        int k = 8 * lk + e;
        a[e] = (short)f2bf((float)(((3 * lr + 7 * k) % 13) + 1));
        b[e] = (short)f2bf((float)(((5 * k + 11 * lr) % 17) + 1));
    }
    f4v d = {0.f, 0.f, 0.f, 0.f};
    d = MFMA_BF16(a, b, d, 0, 0, 0);
    bool okl = true;
#pragma unroll
    for (int r = 0; r < 4; ++r) {
        int row = 4 * lk + r, col = lr;
        int e = 0;
        for (int k = 0; k < 32; ++k)
            e += (((3 * row + 7 * k) % 13) + 1) * (((5 * k + 11 * col) % 17) + 1);
        if (d[r] != (float)e) okl = false;
    }
    unsigned long long vote = __ballot(okl);
    if (l == 0) {
        g_ok = (vote == 0xFFFFFFFFFFFFFFFFull) ? 1 : 0;
        g_bad = 0; g_badstep = 0; g_badfused = 0;
    }
}

// ---------------- init (state + sync flags) ----------------
__global__ void init_state() {
    int i = blockIdx.x * 256 + threadIdx.x;
    if (i < 160 * 32) g_aflag[i] = 0;
    if (i < NB * 32)  g_hxf[i]  = 0;
    if (i < NB * ND) {
        g_hx[i] = 0.0; g_c[i] = 0.0;
        g_hxb[i] = 0; g_hxb[PSH + i] = 0; g_hxb[2 * PSH + i] = 0;
    }
}

// ---------------- weight repack + bf16x3 ----------------
__global__ __launch_bounds__(256) void build_w(const float* __restrict__ cWih,
                                               const float* __restrict__ cWhh,
                                               const float* __restrict__ W1,
                                               const float* __restrict__ b1) {
    int n = blockIdx.x;
    for (int c = threadIdx.x; c < KE; c += 256) {
        float we;
        if (n < 2048) we = (c < 512) ? cWih[(size_t)n * 512 + c] : 0.f;
        else {
            int n2 = n - 2048;
            if      (c < 512)  we = W1[(size_t)n2 * 1054 + 512 + c];
            else if (c < 522)  we = W1[(size_t)n2 * 1054 + 1024 + (c - 512)];
            else if (c < 542)  we = W1[(size_t)n2 * 1054 + 1034 + (c - 522)];
            else if (c == 542) we = b1[n2];
            else               we = 0.f;
        }
        size_t ix = (size_t)n * KE + c;
        g_Wext[ix] = we;
        u16 b0, b1_, b2; decomp3(we, b0, b1_, b2);
        g_Wextb[ix] = b0; g_Wextb[PSWE + ix] = b1_; g_Wextb[2 * PSWE + ix] = b2;
        if (c < 512) {
            float ws = (n < 2048) ? cWhh[(size_t)n * 512 + c]
                                  : W1[(size_t)(n - 2048) * 1054 + c];
            size_t ix2 = (size_t)n * ND + c;
            g_Wstep[ix2] = ws;
            decomp3(ws, b0, b1_, b2);
            g_Wstepb[ix2] = b0; g_Wstepb[PSWS + ix2] = b1_; g_Wstepb[2 * PSWS + ix2] = b2;
        }
    }
}

// ---------------- gumbel: JAX partitionable threefry2x32, key (0,42) ----------------
__device__ __forceinline__ unsigned rotl32(unsigned x, int r) { return (x << r) | (x >> (32 - r)); }

__global__ void gumbel_init() {
    unsigned p = blockIdx.x * 256 + threadIdx.x;
    if (p >= 65536u) return;
    unsigned k0 = 0u, k1 = 42u;
    unsigned ks2 = k0 ^ k1 ^ 0x1BD11BDAu;
    unsigned x0 = 0u, x1 = p;
    x0 += k0; x1 += k1;
#define RND(r) { x0 += x1; x1 = rotl32(x1, (r)); x1 ^= x0; }
    RND(13) RND(15) RND(26) RND(6)
    x0 += k1;  x1 += ks2 + 1u;
    RND(17) RND(29) RND(16) RND(24)
    x0 += ks2; x1 += k0 + 2u;
    RND(13) RND(15) RND(26) RND(6)
    x0 += k0;  x1 += k1 + 3u;
    RND(17) RND(29) RND(16) RND(24)
    x0 += k1;  x1 += ks2 + 4u;
    RND(13) RND(15) RND(26) RND(6)
    x0 += ks2; x1 += k0 + 5u;
#undef RND
    unsigned bits = x0 ^ x1;
    float u = __uint_as_float((bits >> 9) | 0x3f800000u) - 1.0f;
    g_gum[p] = log(-log((double)u + 1e-20) + 1e-20);
}

// ---------------- embedding gather+sum ----------------
__global__ __launch_bounds__(128) void embed_sum(const int* __restrict__ seqs,
                                                 const float* __restrict__ emb) {
    int bs = blockIdx.x;
    int tid = threadIdx.x;
    __shared__ int idxs[16];
    if (tid < 16) idxs[tid] = seqs[(size_t)bs * 16 + tid];
    __syncthreads();
    double a0 = 0, a1 = 0, a2 = 0, a3 = 0;
    for (int v = 0; v < 16; ++v) {
        const float4* row = (const float4*)(emb + (size_t)idxs[v] * ND);
        float4 e = row[tid];
        a0 += (double)e.x; a1 += (double)e.y; a2 += (double)e.z; a3 += (double)e.w;
    }
    size_t base = (size_t)bs * KE + tid * 4;
    double* o = g_A + base;
    o[0] = a0; o[1] = a1; o[2] = a2; o[3] = a3;
    put_Ab(base + 0, (float)a0); put_Ab(base + 1, (float)a1);
    put_Ab(base + 2, (float)a2); put_Ab(base + 3, (float)a3);
    if (tid == 0) {
        g_A[(size_t)bs * KE + 542] = 1.0; g_A[(size_t)bs * KE + 543] = 0.0;
        put_Ab((size_t)bs * KE + 542, 1.0f); put_Ab((size_t)bs * KE + 543, 0.0f);
    }
}

// ---------------- f64 vector GEMM (Aproj only) ----------------
__global__ __launch_bounds__(256) void gemm_f64(
    const double* __restrict__ A, int lda,
    const float* __restrict__ W, int ldw,
    double* __restrict__ C, int ldc,
    int M, int N, int K) {
    __shared__ double As[16][66];
    __shared__ double Ws[16][66];
    int m0 = blockIdx.x * 64, n0 = blockIdx.y * 64;
    int tid = threadIdx.x, tx = tid & 15, ty = tid >> 4;
    double acc[4][4] = {};
    for (int k0 = 0; k0 < K; k0 += 16) {
        for (int i = tid; i < 1024; i += 256) {
            int r = i >> 4, c = i & 15;
            As[c][r] = (m0 + r < M && k0 + c < K) ? A[(size_t)(m0 + r) * lda + k0 + c] : 0.0;
            Ws[c][r] = (n0 + r < N && k0 + c < K) ? (double)W[(size_t)(n0 + r) * ldw + k0 + c] : 0.0;
        }
        __syncthreads();
#pragma unroll
        for (int kk = 0; kk < 16; ++kk) {
            double a0 = As[kk][ty*4], a1 = As[kk][ty*4+1], a2 = As[kk][ty*4+2], a3 = As[kk][ty*4+3];
            double w0 = Ws[kk][tx*4], w1 = Ws[kk][tx*4+1], w2 = Ws[kk][tx*4+2], w3 = Ws[kk][tx*4+3];
            acc[0][0] += a0*w0; acc[0][1] += a0*w1; acc[0][2] += a0*w2; acc[0][3] += a0*w3;
            acc[1][0] += a1*w0; acc[1][1] += a1*w1; acc[1][2] += a1*w2; acc[1][3] += a1*w3;
            acc[2][0] += a2*w0; acc[2][1] += a2*w1; acc[2][2] += a2*w2; acc[2][3] += a2*w3;
            acc[3][0] += a3*w0; acc[3][1] += a3*w1; acc[3][2] += a3*w2; acc[3][3] += a3*w3;
        }
        __syncthreads();
    }
#pragma unroll
    for (int i = 0; i < 4; ++i)
#pragma unroll
        for (int j = 0; j < 4; ++j) {
            int m = m0 + ty*4 + i, n = n0 + tx*4 + j;
            if (m < M && n < N) C[(size_t)m * ldc + n] = acc[i][j];
        }
}

// ---------------- reverse LSTM ----------------
__global__ __launch_bounds__(64) void rev_lstm(const float* __restrict__ Whh) {
    int b = blockIdx.x;
    int tid = threadIdx.x;
    __shared__ double h[10], cc[10], g[40], wsh[400];
    for (int i = tid; i < 400; i += 64) wsh[i] = (double)Whh[i];
    if (tid < 10) { h[tid] = 0.0; cc[tid] = 0.0; }
    __syncthreads();
    for (int s = NS - 1; s >= 0; --s) {
        if (tid < 40) {
            double acc = g_Aproj[((size_t)b * NS + s) * 40 + tid];
#pragma unroll
            for (int k = 0; k < 10; ++k) acc += h[k] * wsh[tid * 10 + k];
            g[tid] = acc;
        }
        __syncthreads();
        if (tid < 10) {
            double gi = g[tid], gf = g[10 + tid], gg = g[20 + tid], go = g[30 + tid];
            double cn = sigd(gf) * cc[tid] + sigd(gi) * tanh(gg);
            cc[tid] = cn;
            double hn = sigd(go) * tanh(cn);
            h[tid] = hn;
            size_t ix = ((size_t)b * NS + s) * KE + 512 + tid;
            g_A[ix] = hn;
            put_Ab(ix, (float)hn);
        }
        __syncthreads();
    }
}

// ---------------- conv1d + relu ----------------
__global__ __launch_bounds__(256) void conv_relu(const float* __restrict__ w) {
    int b = blockIdx.x, s0 = blockIdx.y * 8;
    int tid = threadIdx.x, grp = tid >> 5, lane = tid & 31;
    __shared__ double xs[10][ND];
    for (int i = tid; i < 10 * ND; i += 256) {
        int r = i >> 9, d = i & (ND - 1);
        int s = s0 - 1 + r;
        xs[r][d] = (s >= 0 && s < NS) ? g_A[((size_t)b * NS + s) * KE + d] : 0.0;
    }
    __syncthreads();
    int s = s0 + grp;
    for (int o = 0; o < 20; ++o) {
        const float* wo = w + (size_t)o * 1536;
        double acc = 0.0;
        for (int d = lane; d < ND; d += 32) {
            acc += xs[grp][d]     * (double)wo[d*3]
                 + xs[grp + 1][d] * (double)wo[d*3 + 1]
                 + xs[grp + 2][d] * (double)wo[d*3 + 2];
        }
        for (int m = 16; m > 0; m >>= 1) acc += __shfl_xor(acc, m, 32);
        if (lane == 0) {
            double v = acc > 0.0 ? acc : 0.0;
            size_t ix = ((size_t)b * NS + s) * KE + 522 + o;
            g_A[ix] = v;
            put_Ab(ix, (float)v);
        }
    }
}

// ---------------- big GEMM: g_Pre[t][b][n] = g_A @ g_Wext^T ----------------
__global__ __launch_bounds__(256) void big_gemm() {
    __shared__ __align__(16) unsigned char shms[36864];
    int tid = threadIdx.x;
    int n0 = blockIdx.x * 64, m0 = blockIdx.y * 64;
    if (g_ok) {
        u16* usA = (u16*)shms;
        u16* usB = usA + 9216;
        int lane = tid & 63, wave = tid >> 6;
        int wm = (wave & 1) * 32, wn = (wave >> 1) * 32;
        int lr = lane & 15, lk = lane >> 4;
        f4v z = {0.f,0.f,0.f,0.f};
        f4v aP00=z,aP01=z,aP10=z,aP11=z, aC00=z,aC01=z,aC10=z,aC11=z;
        for (int k0 = 0; k0 < KE; k0 += 32) {
            for (int i = tid; i < 1536; i += 256) {
                if (i < 768) {
                    int p = i >> 8, rem = i & 255, r = rem >> 2, sg = rem & 3;
                    *(uint4*)(void*)(usA + p*3072 + r*48 + sg*8) =
                        *(const uint4*)(const void*)(g_Ab + (size_t)p*PSA + (size_t)(m0+r)*KE + k0 + sg*8);
                } else {
                    int j = i - 768;
                    int p = j >> 8, rem = j & 255, r = rem >> 2, sg = rem & 3;
                    *(uint4*)(void*)(usB + p*3072 + r*48 + sg*8) =
                        *(const uint4*)(const void*)(g_Wextb + (size_t)p*PSWE + (size_t)(n0+r)*KE + k0 + sg*8);
                }
            }
            __syncthreads();
            const u16* pa = usA + (wm + lr) * 48 + 8 * lk;
            const u16* pb = usB + (wn + lr) * 48 + 8 * lk;
            s8v a0_0 = *(const s8v*)(const void*)(pa);
            s8v a0_1 = *(const s8v*)(const void*)(pa + 768);
            s8v a1_0 = *(const s8v*)(const void*)(pa + 3072);
            s8v a1_1 = *(const s8v*)(const void*)(pa + 3840);
            s8v a2_0 = *(const s8v*)(const void*)(pa + 6144);
            s8v a2_1 = *(const s8v*)(const void*)(pa + 6912);
            s8v b0_0 = *(const s8v*)(const void*)(pb);
            s8v b0_1 = *(const s8v*)(const void*)(pb + 768);
            s8v b1_0 = *(const s8v*)(const void*)(pb + 3072);
            s8v b1_1 = *(const s8v*)(const void*)(pb + 3840);
            s8v b2_0 = *(const s8v*)(const void*)(pb + 6144);
            s8v b2_1 = *(const s8v*)(const void*)(pb + 6912);
            STEP6(aP00, aC00, a0_0, a1_0, a2_0, b0_0, b1_0, b2_0)
            STEP6(aP01, aC01, a0_0, a1_0, a2_0, b0_1, b1_1, b2_1)
            STEP6(aP10, aC10, a0_1, a1_1, a2_1, b0_0, b1_0, b2_0)
            STEP6(aP11, aC11, a0_1, a1_1, a2_1, b0_1, b1_1, b2_1)
            __syncthreads();
        }
        int rb = m0 + wm + 4 * lk, cb0 = n0 + wn + lr, cb1 = cb0 + 16;
#pragma unroll
        for (int r = 0; r < 4; ++r) {
            g_Pre[pre_ix(rb + r, cb0)]      = aP00[r] + aC00[r];
            g_Pre[pre_ix(rb + r, cb1)]      = aP01[r] + aC01[r];
            g_Pre[pre_ix(rb + 16 + r, cb0)] = aP10[r] + aC10[r];
            g_Pre[pre_ix(rb + 16 + r, cb1)] = aP11[r] + aC11[r];
        }
    } else {
        double* Asd = (double*)shms;
        double* Wsd = Asd + 64 * 33;
        int tx = tid & 15, ty = tid >> 4;
        double acc[4][4] = {};
        for (int k0 = 0; k0 < KE; k0 += 32) {
            for (int i = tid; i < 2048; i += 256) {
                int r = i >> 5, c = i & 31;
                Asd[r * 33 + c] = g_A[(size_t)(m0 + r) * KE + k0 + c];
                Wsd[r * 33 + c] = (double)g_Wext[(size_t)(n0 + r) * KE + k0 + c];
            }
            __syncthreads();
            for (int kk = 0; kk < 32; ++kk) {
                double a0 = Asd[(ty*4)*33+kk], a1 = Asd[(ty*4+1)*33+kk], a2 = Asd[(ty*4+2)*33+kk], a3 = Asd[(ty*4+3)*33+kk];
                double w0 = Wsd[(tx*4)*33+kk], w1 = Wsd[(tx*4+1)*33+kk], w2 = Wsd[(tx*4+2)*33+kk], w3 = Wsd[(tx*4+3)*33+kk];
                acc[0][0] += a0*w0; acc[0][1] += a0*w1; acc[0][2] += a0*w2; acc[0][3] += a0*w3;
                acc[1][0] += a1*w0; acc[1][1] += a1*w1; acc[1][2] += a1*w2; acc[1][3] += a1*w3;
                acc[2][0] += a2*w0; acc[2][1] += a2*w1; acc[2][2] += a2*w2; acc[2][3] += a2*w3;
                acc[3][0] += a3*w0; acc[3][1] += a3*w1; acc[3][2] += a3*w2; acc[3][3] += a3*w3;
            }
            __syncthreads();
        }
#pragma unroll
        for (int i = 0; i < 4; ++i)
#pragma unroll
            for (int j = 0; j < 4; ++j)
                g_Pre[pre_ix(m0 + ty*4 + i, n0 + tx*4 + j)] = (float)acc[i][j];
    }
}

// ---------------- sample-verify g_Pre ----------------
__global__ void verify_pre() {
    int s = blockIdx.x * 256 + threadIdx.x;
    unsigned m = ((unsigned)s * 2654435761u) & 32767u;
    unsigned n = ((unsigned)s * 40503u + 7u) % 2560u;
    double dot = 0.0;
    const double* ar = g_A + (size_t)m * KE;
    const float*  wr = g_Wext + (size_t)n * KE;
    for (int c = 0; c < KE; ++c) dot += ar[c] * (double)wr[c];
    double got = (double)g_Pre[pre_ix((int)m, (int)n)];
    if (fabs(got - dot) > 1e-4 * (1.0 + fabs(dot))) atomicOr(&g_bad, 1);
}

// ---------------- full vector recompute of g_Pre (only if ok && bad) ----------------
__global__ __launch_bounds__(256) void big_fix() {
    if (!(g_ok && g_bad)) return;
    __shared__ double As[64][33];
    __shared__ double Ws[64][33];
    int tid = threadIdx.x, tx = tid & 15, ty = tid >> 4;
    for (int tile = blockIdx.x; tile < (NC/64) * (NBS/64); tile += gridDim.x) {
        int n0 = (tile % (NC/64)) * 64, m0 = (tile / (NC/64)) * 64;
        double acc[4][4] = {};
        for (int k0 = 0; k0 < KE; k0 += 32) {
            for (int i = tid; i < 2048; i += 256) {
                int r = i >> 5, c = i & 31;
                As[r][c] = g_A[(size_t)(m0 + r) * KE + k0 + c];
                Ws[r][c] = (double)g_Wext[(size_t)(n0 + r) * KE + k0 + c];
            }
            __syncthreads();
            for (int kk = 0; kk < 32; ++kk) {
                double a0 = As[ty*4][kk], a1 = As[ty*4+1][kk], a2 = As[ty*4+2][kk], a3 = As[ty*4+3][kk];
                double w0 = Ws[tx*4][kk], w1 = Ws[tx*4+1][kk], w2 = Ws[tx*4+2][kk], w3 = Ws[tx*4+3][kk];
                acc[0][0] += a0*w0; acc[0][1] += a0*w1; acc[0][2] += a0*w2; acc[0][3] += a0*w3;
                acc[1][0] += a1*w0; acc[1][1] += a1*w1; acc[1][2] += a1*w2; acc[1][3] += a1*w3;
                acc[2][0] += a2*w0; acc[2][1] += a2*w1; acc[2][2] += a2*w2; acc[2][3] += a2*w3;
                acc[3][0] += a3*w0; acc[3][1] += a3*w1; acc[3][2] += a3*w2; acc[3][3] += a3*w3;
            }
            __syncthreads();
        }
#pragma unroll
        for (int i = 0; i < 4; ++i)
#pragma unroll
            for (int j = 0; j < 4; ++j)
                g_Pre[pre_ix(m0 + ty*4 + i, n0 + tx*4 + j)] = (float)acc[i][j];
        __syncthreads();
    }
}

// ---------------- synthetic hx for step probes ----------------
__global__ void synth_hx() {
    int i = blockIdx.x * 256 + threadIdx.x;
    if (i >= NB * ND) return;
    unsigned h = (unsigned)i * 2654435761u;
    float v = (float)((h >> 8) & 0xFFFFu) / 65536.0f - 0.5f;
    g_hx[i] = (double)v;
    u16 b0, b1, b2; decomp3(v, b0, b1, b2);
    g_hxb[i] = b0; g_hxb[PSH + i] = b1; g_hxb[2 * PSH + i] = b2;
}

// ---------------- standalone step GEMM (probe + host-fallback ladder, NC stride) ----------------
__global__ __launch_bounds__(256) void step_gemm(int t, int probe) {
    __shared__ double shd[3168];
    int tid = threadIdx.x;
    int m0 = blockIdx.x * 32, n0 = blockIdx.y * 64;
    int use_mfma = g_ok && (probe || !g_badstep);
    if (use_mfma) {
        int lane = tid & 63, wave = tid >> 6;
        int wm = (wave & 1) * 16, wn = (wave >> 1) * 32;
        int lr = lane & 15, lk = lane >> 4;
        size_t ha  = (size_t)(m0 + wm + lr) * ND;
        size_t wb0 = (size_t)(n0 + wn + lr) * ND;
        size_t wb1 = (size_t)(n0 + wn + 16 + lr) * ND;
        f4v z = {0.f,0.f,0.f,0.f};
        f4v aP0=z, aP1=z, aC0=z, aC1=z;
        for (int k0 = 0; k0 < ND; k0 += 32) {
            int kk = k0 + 8 * lk;
            s8v a0  = *(const s8v*)(const void*)(g_hxb + ha + kk);
            s8v a1  = *(const s8v*)(const void*)(g_hxb + PSH + ha + kk);
            s8v a2  = *(const s8v*)(const void*)(g_hxb + 2*PSH + ha + kk);
            s8v b00 = *(const s8v*)(const void*)(g_Wstepb + wb0 + kk);
            s8v b01 = *(const s8v*)(const void*)(g_Wstepb + wb1 + kk);
            s8v b10 = *(const s8v*)(const void*)(g_Wstepb + PSWS + wb0 + kk);
            s8v b11 = *(const s8v*)(const void*)(g_Wstepb + PSWS + wb1 + kk);
            s8v b20 = *(const s8v*)(const void*)(g_Wstepb + 2*PSWS + wb0 + kk);
            s8v b21 = *(const s8v*)(const void*)(g_Wstepb + 2*PSWS + wb1 + kk);
            STEP6(aP0, aC0, a0, a1, a2, b00, b10, b20)
            STEP6(aP1, aC1, a0, a1, a2, b01, b11, b21)
        }
        int rb = m0 + wm + 4 * lk, cb0 = n0 + wn + lr, cb1 = cb0 + 16;
#pragma unroll
        for (int r = 0; r < 4; ++r) {
            g_gbufF[(size_t)(rb + r) * NC + cb0] = aP0[r] + aC0[r]
                + g_Pre[((size_t)t * NB + rb + r) * NC + cb0];
            g_gbufF[(size_t)(rb + r) * NC + cb1] = aP1[r] + aC1[r]
                + g_Pre[((size_t)t * NB + rb + r) * NC + cb1];
        }
    } else {
        double* Asd = shd;
        double* Wsd = shd + 1056;
        int tx = tid & 15, ty = tid >> 4;
        double acc[2][4] = {};
        for (int k0 = 0; k0 < ND; k0 += 32) {
            for (int i = tid; i < 1024; i += 256) {
                int r = i >> 5, c = i & 31;
                Asd[r * 33 + c] = g_hx[(size_t)(m0 + r) * ND + k0 + c];
            }
            for (int i = tid; i < 2048; i += 256) {
                int r = i >> 5, c = i & 31;
                Wsd[r * 33 + c] = (double)g_Wstep[(size_t)(n0 + r) * ND + k0 + c];
            }
            __syncthreads();
            for (int kk = 0; kk < 32; ++kk) {
                double a0 = Asd[(ty*2)*33+kk], a1 = Asd[(ty*2+1)*33+kk];
                double w0 = Wsd[(tx*4)*33+kk], w1 = Wsd[(tx*4+1)*33+kk], w2 = Wsd[(tx*4+2)*33+kk], w3 = Wsd[(tx*4+3)*33+kk];
                acc[0][0] += a0*w0; acc[0][1] += a0*w1; acc[0][2] += a0*w2; acc[0][3] += a0*w3;
                acc[1][0] += a1*w0; acc[1][1] += a1*w1; acc[1][2] += a1*w2; acc[1][3] += a1*w3;
            }
            __syncthreads();
        }
#pragma unroll
        for (int i = 0; i < 2; ++i)
#pragma unroll
            for (int j = 0; j < 4; ++j) {
                int m = m0 + ty*2 + i, n = n0 + tx*4 + j;
                g_gbufF[(size_t)m * NC + n] = (float)(acc[i][j]
                    + (double)g_Pre[((size_t)t * NB + m) * NC + n]);
            }
    }
}

// ---------------- verify standalone step ----------------
__global__ void verify_step() {
    int s = blockIdx.x * 256 + threadIdx.x;
    unsigned m = ((unsigned)s * 2654435761u) & 127u;
    unsigned n = ((unsigned)s * 40503u + 7u) % 2560u;
    double dot = 0.0;
    const double* hr = g_hx + (size_t)m * ND;
    const float*  wr = g_Wstep + (size_t)n * ND;
    for (int c = 0; c < ND; ++c) dot += hr[c] * (double)wr[c];
    dot += (double)g_Pre[(size_t)m * NC + n];
    double got = (double)g_gbufF[(size_t)m * NC + n];
    if (fabs(got - dot) > 1e-4 * (1.0 + fabs(dot))) atomicOr(&g_badstep, 1);
}

// ---------------- verify fused probe output (gates 2048-stride + leap partials) ----------------
__global__ void verify_fused(const float* __restrict__ W2) {
    int s = blockIdx.x * 256 + threadIdx.x;    // 4096 samples
    unsigned m = ((unsigned)s * 2654435761u) & 127u;
    unsigned h2 = (unsigned)s * 40503u + 7u;
    const double* hr = g_hx + (size_t)m * ND;
    if (s & 1) {
        unsigned q = h2 & 31u;
        double p0 = 0.0, p1 = 0.0;
        for (int c = 0; c < 16; ++c) {
            int col = q * 16 + c;
            const float* wr = g_Wstep + (size_t)(2048 + col) * ND;
            double dot = 0.0;
            for (int k = 0; k < ND; ++k) dot += hr[k] * (double)wr[k];
            dot += (double)g_Pre[(size_t)m * NC + 2048 + col];
            double hh = dot > 0.0 ? dot : 0.0;
            p0 += hh * (double)W2[col];
            p1 += hh * (double)W2[512 + col];
        }
        if (fabs(g_lpart[q][m][0] - p0) > 1e-4 * (1.0 + fabs(p0)) ||
            fabs(g_lpart[q][m][1] - p1) > 1e-4 * (1.0 + fabs(p1)))
            atomicOr(&g_badfused, 1);
    } else {
        unsigned n = h2 % 2048u;
        double dot = 0.0;
        const float* wr = g_Wstep + (size_t)n * ND;
        for (int k = 0; k < ND; ++k) dot += hr[k] * (double)wr[k];
        dot += (double)g_Pre[(size_t)m * NC + n];
        double got = (double)g_gbufF[(size_t)m * 2048 + n];
        if (fabs(got - dot) > 1e-4 * (1.0 + fabs(dot))) atomicOr(&g_badfused, 1);
    }
}

// ---------------- standalone per-step update (host ladder, NC stride) ----------------
__global__ __launch_bounds__(256) void step_update(
    const float* __restrict__ W2, const float* __restrict__ b2,
    const int* __restrict__ lengths, int t) {
    __shared__ double red[8];
    __shared__ double skipsh[2];
    int b = blockIdx.x, tid = threadIdx.x, lane = tid & 63, wave = tid >> 6;
    const float* gb = g_gbufF + (size_t)b * NC;
    double p0 = 0.0, p1 = 0.0;
    for (int j = tid; j < ND; j += 256) {
        double h = (double)gb[2048 + j];
        h = h > 0.0 ? h : 0.0;
        p0 += h * (double)W2[j];
        p1 += h * (double)W2[ND + j];
    }
    for (int off = 32; off > 0; off >>= 1) {
        p0 += __shfl_down(p0, off, 64);
        p1 += __shfl_down(p1, off, 64);
    }
    if (lane == 0) { red[wave*2] = p0; red[wave*2+1] = p1; }
    __syncthreads();
    if (tid == 0) {
        double l0 = red[0]+red[2]+red[4]+red[6] + (double)b2[0];
        double l1 = red[1]+red[3]+red[5]+red[7] + (double)b2[1];
        double mx = fmax(l0, l1);
        double sh0 = l0 - mx, sh1 = l1 - mx;
        double lsum = log(exp(sh0) + exp(sh1));
        double y0 = (sh0 - lsum) - g_gum[(size_t)t * (NB * 2) + b * 2 + 0];
        double y1 = (sh1 - lsum) - g_gum[(size_t)t * (NB * 2) + b * 2 + 1];
        double xx0 = y0 / 1e-5, xx1 = y1 / 1e-5;
        double mm = fmax(xx0, xx1);
        double e0 = exp(xx0 - mm), e1 = exp(xx1 - mm);
        double inv = 1.0 / (e0 + e1);
        skipsh[0] = e0 * inv; skipsh[1] = e1 * inv;
    }
    __syncthreads();
    double s0 = skipsh[0], s1 = skipsh[1];
    bool isFinal = (t == lengths[b] - 1);
#pragma unroll
    for (int e = 0; e < 2; ++e) {
        int j = tid + 256 * e;
        size_t ix = (size_t)b * ND + j;
        double gi = (double)gb[j], gf = (double)gb[ND + j];
        double gg = (double)gb[2*ND + j], go = (double)gb[3*ND + j];
        double cn = sigd(gf) * g_c[ix] + sigd(gi) * tanh(gg);
        double shx = sigd(go) * tanh(cn);
        double hn = g_hx[ix] * s1 + shx * s0;
        g_c[ix] = cn; g_hx[ix] = hn;
        u16 w0, w1, w2x; decomp3((float)hn, w0, w1, w2x);
        g_hxb[ix] = w0; g_hxb[PSH + ix] = w1; g_hxb[2 * PSH + ix] = w2x;
        if (isFinal) g_final[ix] = hn;
    }
}

// ---------------- persistent flag-synced loop: 80 blocks x 32 cols, sc path ----------------
__global__ __launch_bounds__(512, 1) void loop_fused(const float* __restrict__ W2,
                                                     const float* __restrict__ b2,
                                                     const int* __restrict__ lengths,
                                                     int steps, int probe) {
    extern __shared__ unsigned char shm[];
    int bid = blockIdx.x, tid = threadIdx.x;
    int nc0 = bid * 32;
    int w = tid >> 6, lane = tid & 63;
    int lr = lane & 15, lk = lane >> 4;
    int path = g_ok && !g_badfused;
    // phase-B row ownership: blocks 0..63 own rows 2*bid, 2*bid+1
    int rsel = tid >> 8, ts = tid & 255;
    int row = 2 * bid + rsel;
    double c0 = 0.0, c1 = 0.0, h0 = 0.0, h1 = 0.0;   // state elems j=2ts, 2ts+1
    int mylen = (bid < NGB) ? lengths[row] : -1;
    u16*    Wl     = (u16*)shm;                      // 96KB bf16x3 (path)
    float*  Wfb    = (float*)shm;                    // 64KB f32 (fallback overlay)
    float*  W2l    = (float*)(shm + 98304);          // 4KB
    double* skp    = (double*)(shm + 102400);        // [2 rows][2]
    if (path) {
        for (int i = tid; i < 6144; i += 512) {
            int half = i >= 3072, ii = i & 3071;
            int p = ii >> 10, rem = ii & 1023, kk = rem >> 6, l = rem & 63;
            int col16 = l & 15, k8 = l >> 4;
            *(uint4*)(void*)(Wl + half*24576 + p*8192 + kk*512 + l*8) =
                *(const uint4*)(const void*)(g_Wstepb + (size_t)p*PSWS
                      + (size_t)(nc0 + half*16 + col16)*ND + kk*32 + k8*8);
        }
    } else {
        for (int i = tid; i < 32*512; i += 512)
            Wfb[i] = g_Wstep[(size_t)(nc0 + (i >> 9))*ND + (i & 511)];
    }
    for (int i = tid; i < 1024; i += 512) W2l[i] = W2[i];
    __syncthreads();
    int r0 = 16*w + 4*lk;
    float preA[4], preB[4];
    if (path) {
#pragma unroll
        for (int r = 0; r < 4; ++r) {
            preA[r] = g_Pre[((size_t)0 * NB + r0 + r) * NC + nc0 + lr];
            preB[r] = g_Pre[((size_t)0 * NB + r0 + r) * NC + nc0 + 16 + lr];
        }
    }
    for (int t = 0; t < steps; ++t) {
        if (path) {
            // ================= SC PATH =================
            if (t > 0) {
                for (;;) {
                    bool okp = true;
                    if (lane < 16)
                        okp = (__hip_atomic_load(&g_hxf[(16*w + lane)*32],
                               __ATOMIC_RELAXED, __HIP_MEMORY_SCOPE_AGENT) >= t);
                    if (__all(okp)) break;
                    __builtin_amdgcn_s_sleep(1);
                }
            }
            f4v z = {0.f,0.f,0.f,0.f};
            f4v aP0 = z, aC0 = z, aP1 = z, aC1 = z;
            size_t ha = (size_t)(16*w + lr) * ND;
#pragma unroll
            for (int h = 0; h < 2; ++h) {
                uv4 U0[8], U1[8], U2[8];
#pragma unroll
                for (int kk = 0; kk < 8; ++kk) {     // 24 MALL loads in flight
                    int kb = (8*h + kk)*32 + 8*lk;
                    const u16* p0 = g_hxb + ha + kb;
                    const u16* p1 = g_hxb + PSH + ha + kb;
                    const u16* p2 = g_hxb + 2*PSH + ha + kb;
                    asm volatile("global_load_dwordx4 %0, %3, off sc0 sc1\n\t"
                                 "global_load_dwordx4 %1, %4, off sc0 sc1\n\t"
                                 "global_load_dwordx4 %2, %5, off sc0 sc1"
                                 : "=v"(U0[kk]), "=v"(U1[kk]), "=v"(U2[kk])
                                 : "v"(p0), "v"(p1), "v"(p2));
                }
                SC_WAIT();
#pragma unroll
                for (int kk = 0; kk < 8; ++kk) {     // consume: both col halves
                    const u16* wp = Wl + (8*h + kk)*512 + lane*8;
                    s8v A0 = __builtin_bit_cast(s8v, U0[kk]);
                    s8v A1 = __builtin_bit_cast(s8v, U1[kk]);
                    s8v A2 = __builtin_bit_cast(s8v, U2[kk]);
                    s8v B00 = *(const s8v*)(const void*)(wp);
                    s8v B01 = *(const s8v*)(const void*)(wp + 8192);
                    s8v B02 = *(const s8v*)(const void*)(wp + 16384);
                    STEP6(aP0, aC0, A0, A1, A2, B00, B01, B02)
                    s8v B10 = *(const s8v*)(const void*)(wp + 24576);
                    s8v B11 = *(const s8v*)(const void*)(wp + 32768);
                    s8v B12 = *(const s8v*)(const void*)(wp + 40960);
                    STEP6(aP1, aC1, A0, A1, A2, B10, B11, B12)
                }
            }
            if (bid < NGB) {
#pragma unroll
                for (int r = 0; r < 4; ++r) {
                    sc_store_f32(g_gbufF + (size_t)(r0 + r) * 2048 + nc0 + lr,
                                 aP0[r] + aC0[r] + preA[r]);
                    sc_store_f32(g_gbufF + (size_t)(r0 + r) * 2048 + nc0 + 16 + lr,
                                 aP1[r] + aC1[r] + preB[r]);
                }
            } else {
                int colg = nc0 - 2048 + lr;
                double q00[4], q01[4], q10[4], q11[4];
#pragma unroll
                for (int r = 0; r < 4; ++r) {
                    float v0 = aP0[r] + aC0[r] + preA[r];
                    float v1 = aP1[r] + aC1[r] + preB[r];
                    double h0d = v0 > 0.f ? (double)v0 : 0.0;
                    double h1d = v1 > 0.f ? (double)v1 : 0.0;
                    q00[r] = h0d * (double)W2l[colg];
                    q01[r] = h0d * (double)W2l[512 + colg];
                    q10[r] = h1d * (double)W2l[colg + 16];
                    q11[r] = h1d * (double)W2l[512 + colg + 16];
                }
#pragma unroll
                for (int m = 8; m > 0; m >>= 1)
#pragma unroll
                    for (int r = 0; r < 4; ++r) {
                        q00[r] += __shfl_xor(q00[r], m, 16);
                        q01[r] += __shfl_xor(q01[r], m, 16);
                        q10[r] += __shfl_xor(q10[r], m, 16);
                        q11[r] += __shfl_xor(q11[r], m, 16);
                    }
                if (lr == 0) {
                    int g = (bid - NGB) * 2;
#pragma unroll
                    for (int r = 0; r < 4; ++r) {
                        dv2 qa; qa[0] = q00[r]; qa[1] = q01[r];
                        sc_store_d2(&g_lpart[g][r0 + r][0], qa);
                        dv2 qb; qb[0] = q10[r]; qb[1] = q11[r];
                        sc_store_d2(&g_lpart[g + 1][r0 + r][0], qb);
                    }
                }
            }
            asm volatile("s_waitcnt vmcnt(0)" ::: "memory");
            __syncthreads();
            if (tid == 0)
                __hip_atomic_store(&g_aflag[bid*32], t + 1, __ATOMIC_RELAXED,
                                   __HIP_MEMORY_SCOPE_AGENT);
            __syncthreads();
            {   // prefetch next Pre slice (cached)
                int tn = (t + 1 < steps) ? t + 1 : t;
#pragma unroll
                for (int r = 0; r < 4; ++r) {
                    preA[r] = g_Pre[((size_t)tn * NB + r0 + r) * NC + nc0 + lr];
                    preB[r] = g_Pre[((size_t)tn * NB + r0 + r) * NC + nc0 + 16 + lr];
                }
            }
            // ---- phase B: rows 2bid, 2bid+1 ----
            if (!probe && bid < NGB) {
                if (ts < NBLK) {
                    while (__hip_atomic_load(&g_aflag[ts*32], __ATOMIC_RELAXED,
                             __HIP_MEMORY_SCOPE_AGENT) < t + 1)
                        __builtin_amdgcn_s_sleep(1);
                }
                __syncthreads();
                f2v gi2, gf2, gg2, go2;
                {
                    const float* gp = g_gbufF + (size_t)row * 2048 + ts*2;
                    asm volatile("global_load_dwordx2 %0, %4, off sc0 sc1\n\t"
                                 "global_load_dwordx2 %1, %5, off sc0 sc1\n\t"
                                 "global_load_dwordx2 %2, %6, off sc0 sc1\n\t"
                                 "global_load_dwordx2 %3, %7, off sc0 sc1"
                                 : "=v"(gi2), "=v"(gf2), "=v"(gg2), "=v"(go2)
                                 : "v"(gp), "v"(gp + 512), "v"(gp + 1024), "v"(gp + 1536));
                }
                double p0 = 0.0, p1 = 0.0;
                if (ts < 32) {
                    dv2 lp;
                    const double* lpp = &g_lpart[ts][row][0];
                    asm volatile("global_load_dwordx4 %0, %1, off sc0 sc1"
                                 : "=v"(lp) : "v"(lpp));
                    asm volatile("s_waitcnt vmcnt(0)" ::: "memory");
                    p0 = lp[0]; p1 = lp[1];
                }
                __builtin_amdgcn_sched_barrier(0);
                if (ts < 64) {
#pragma unroll
                    for (int m = 16; m > 0; m >>= 1) {
                        p0 += __shfl_xor(p0, m, 32);
                        p1 += __shfl_xor(p1, m, 32);
                    }
                }
                if (ts == 0) {
                    double l0 = p0 + (double)b2[0], l1 = p1 + (double)b2[1];
                    double mx = fmax(l0, l1);
                    double sh0 = l0 - mx, sh1 = l1 - mx;
                    double lsum = log(exp(sh0) + exp(sh1));
                    double y0 = (sh0 - lsum) - g_gum[(size_t)t * (NB*2) + row*2 + 0];
                    double y1 = (sh1 - lsum) - g_gum[(size_t)t * (NB*2) + row*2 + 1];
                    double xx0 = y0 / 1e-5, xx1 = y1 / 1e-5;
                    double mm = fmax(xx0, xx1);
                    double e0 = exp(xx0 - mm), e1 = exp(xx1 - mm);
                    double inv = 1.0 / (e0 + e1);
                    skp[rsel*2 + 0] = e0 * inv; skp[rsel*2 + 1] = e1 * inv;
                }
                __syncthreads();
                SC_WAIT();
                double s0 = skp[rsel*2 + 0], s1 = skp[rsel*2 + 1];
                bool isFinal = (t == mylen - 1);
                u16 pw[3][2];
#pragma unroll
                for (int e = 0; e < 2; ++e) {
                    double gi = (double)gi2[e], gf = (double)gf2[e];
                    double gg = (double)gg2[e], go = (double)go2[e];
                    double& cr = e ? c1 : c0;
                    double& hr = e ? h1 : h0;
                    double cn = sigd(gf) * cr + sigd(gi) * tanh(gg);
                    double shx = sigd(go) * tanh(cn);
                    double hn = hr * s1 + shx * s0;
                    cr = cn; hr = hn;
                    decomp3((float)hn, pw[0][e], pw[1][e], pw[2][e]);
                    if (isFinal) g_final[(size_t)row * ND + ts*2 + e] = hn;
                }
                size_t ixp = (size_t)row * ND + ts*2;
#pragma unroll
                for (int p = 0; p < 3; ++p)
                    sc_store_u32((void*)(g_hxb + p*PSH + ixp),
                                 (unsigned)pw[p][0] | ((unsigned)pw[p][1] << 16));
                asm volatile("s_waitcnt vmcnt(0)" ::: "memory");
                __syncthreads();
                if (tid == 0) {
                    __hip_atomic_store(&g_hxf[(2*bid)*32], t + 1, __ATOMIC_RELAXED,
                                       __HIP_MEMORY_SCOPE_AGENT);
                    __hip_atomic_store(&g_hxf[(2*bid+1)*32], t + 1, __ATOMIC_RELAXED,
                                       __HIP_MEMORY_SCOPE_AGENT);
                }
            }
        } else {
            // ================= FENCED FALLBACK (f64 vector, 32 cols) =================
            if (t > 0) {
                if (tid < NB) {
                    while (__hip_atomic_load(&g_hxf[tid*32], __ATOMIC_RELAXED,
                             __HIP_MEMORY_SCOPE_AGENT) < t)
                        __builtin_amdgcn_s_sleep(1);
                }
                __syncthreads();
                if (tid == 0) __builtin_amdgcn_fence(__ATOMIC_ACQUIRE, "agent");
                __syncthreads();
            }
            int col = tid & 31, rgrp = tid >> 5;     // 16 rgrps x 8 rows
            double q0[8], q1[8];
#pragma unroll
            for (int rr = 0; rr < 8; ++rr) {
                int rw = rgrp*8 + rr;
                const double* hr = g_hx + (size_t)rw * ND;
                double dot = 0.0;
                for (int k = 0; k < ND; ++k) dot += hr[k] * (double)Wfb[col*512 + k];
                float v = (float)(dot + (double)g_Pre[((size_t)t * NB + rw) * NC + nc0 + col]);
                if (bid < NGB) {
                    g_gbufF[(size_t)rw * 2048 + nc0 + col] = v;
                    q0[rr] = 0.0; q1[rr] = 0.0;
                } else {
                    double hh = v > 0.f ? (double)v : 0.0;
                    q0[rr] = hh * (double)W2l[nc0 - 2048 + col];
                    q1[rr] = hh * (double)W2l[512 + nc0 - 2048 + col];
                }
            }
            if (bid >= NGB) {
#pragma unroll
                for (int m = 8; m > 0; m >>= 1)
#pragma unroll
                    for (int rr = 0; rr < 8; ++rr) {
                        q0[rr] += __shfl_xor(q0[rr], m, 16);
                        q1[rr] += __shfl_xor(q1[rr], m, 16);
                    }
                if ((col & 15) == 0) {
                    int g = (bid - NGB) * 2 + (col >> 4);
#pragma unroll
                    for (int rr = 0; rr < 8; ++rr) {
                        g_lpart[g][rgrp*8 + rr][0] = q0[rr];
                        g_lpart[g][rgrp*8 + rr][1] = q1[rr];
                    }
                }
            }
            __syncthreads();
            if (tid == 0) {
                __builtin_amdgcn_fence(__ATOMIC_RELEASE, "agent");
                __hip_atomic_store(&g_aflag[bid*32], t + 1, __ATOMIC_RELAXED,
                                   __HIP_MEMORY_SCOPE_AGENT);
            }
            __syncthreads();
            if (!probe && bid < NGB) {
                if (ts < NBLK) {
                    while (__hip_atomic_load(&g_aflag[ts*32], __ATOMIC_RELAXED,
                             __HIP_MEMORY_SCOPE_AGENT) < t + 1)
                        __builtin_amdgcn_s_sleep(1);
                }
                __syncthreads();
                if (tid == 0) __builtin_amdgcn_fence(__ATOMIC_ACQUIRE, "agent");
                __syncthreads();
                double p0 = 0.0, p1 = 0.0;
                if (ts < 32) { p0 = g_lpart[ts][row][0]; p1 = g_lpart[ts][row][1]; }
                if (ts < 64) {
#pragma unroll
                    for (int m = 16; m > 0; m >>= 1) {
                        p0 += __shfl_xor(p0, m, 32);
                        p1 += __shfl_xor(p1, m, 32);
                    }
                }
                if (ts == 0) {
                    double l0 = p0 + (double)b2[0], l1 = p1 + (double)b2[1];
                    double mx = fmax(l0, l1);
                    double sh0 = l0 - mx, sh1 = l1 - mx;
                    double lsum = log(exp(sh0) + exp(sh1));
                    double y0 = (sh0 - lsum) - g_gum[(size_t)t * (NB*2) + row*2 + 0];
                    double y1 = (sh1 - lsum) - g_gum[(size_t)t * (NB*2) + row*2 + 1];
                    double xx0 = y0 / 1e-5, xx1 = y1 / 1e-5;
                    double mm = fmax(xx0, xx1);
                    double e0 = exp(xx0 - mm), e1 = exp(xx1 - mm);
                    double inv = 1.0 / (e0 + e1);
                    skp[rsel*2 + 0] = e0 * inv; skp[rsel*2 + 1] = e1 * inv;
                }
                __syncthreads();
                double s0 = skp[rsel*2 + 0], s1 = skp[rsel*2 + 1];
                bool isFinal = (t == mylen - 1);
                const float* gb = g_gbufF + (size_t)row * 2048;
#pragma unroll
                for (int e = 0; e < 2; ++e) {
                    int j = ts*2 + e;
                    size_t ix = (size_t)row * ND + j;
                    double gi = (double)gb[j], gf = (double)gb[512 + j];
                    double gg = (double)gb[1024 + j], go = (double)gb[1536 + j];
                    double& cr = e ? c1 : c0;
                    double& hr = e ? h1 : h0;
                    double cn = sigd(gf) * cr + sigd(gi) * tanh(gg);
                    double shx = sigd(go) * tanh(cn);
                    double hn = hr * s1 + shx * s0;
                    cr = cn; hr = hn;
                    u16 w0_, w1_, w2_; decomp3((float)hn, w0_, w1_, w2_);
                    g_hxb[ix] = w0_; g_hxb[PSH + ix] = w1_; g_hxb[2*PSH + ix] = w2_;
                    g_hx[ix] = hn;
                    if (isFinal) g_final[ix] = hn;
                }
                __syncthreads();
                if (tid == 0) {
                    __builtin_amdgcn_fence(__ATOMIC_RELEASE, "agent");
                    __hip_atomic_store(&g_hxf[(2*bid)*32], t + 1, __ATOMIC_RELAXED,
                                       __HIP_MEMORY_SCOPE_AGENT);
                    __hip_atomic_store(&g_hxf[(2*bid+1)*32], t + 1, __ATOMIC_RELAXED,
                                       __HIP_MEMORY_SCOPE_AGENT);
                }
            }
        }
    }
}

// ---------------- final projection ----------------
__global__ __launch_bounds__(256) void final_out(const float* __restrict__ Wo,
                                                 const float* __restrict__ bo,
                                                 float* __restrict__ out) {
    int tid = threadIdx.x;
    int b = tid >> 1, k = tid & 1;
    double acc = 0.0;
    const double* f = g_final + (size_t)b * ND;
    const float* w = Wo + (size_t)k * ND;
    for (int d = 0; d < ND; ++d) acc += f[d] * (double)w[d];
    out[b * 2 + k] = (float)(acc + (double)bo[k]);
}

// ---------------- host launcher ----------------
extern "C" void kernel_launch(void* const* d_in, const int* in_sizes, int n_in,
                              void* d_out, int out_size, void* d_ws, size_t ws_size,
                              hipStream_t stream) {
    (void)in_sizes; (void)n_in; (void)d_ws; (void)ws_size; (void)out_size;
    const int*   seqs    = (const int*)d_in[0];
    const int*   lengths = (const int*)d_in[2];
    const float* emb     = (const float*)d_in[5];
    const float* revWih  = (const float*)d_in[6];
    const float* revWhh  = (const float*)d_in[7];
    const float* convw   = (const float*)d_in[8];
    const float* W1      = (const float*)d_in[9];
    const float* b1      = (const float*)d_in[10];
    const float* W2      = (const float*)d_in[11];
    const float* b2      = (const float*)d_in[12];
    const float* cWih    = (const float*)d_in[13];
    const float* cWhh    = (const float*)d_in[14];
    const float* Wo      = (const float*)d_in[15];
    const float* bo      = (const float*)d_in[16];
    float* out = (float*)d_out;

    double *A_p = nullptr, *Ap_p = nullptr;
    hipGetSymbolAddress((void**)&A_p,  HIP_SYMBOL(g_A));
    hipGetSymbolAddress((void**)&Ap_p, HIP_SYMBOL(g_Aproj));

    probe_bf16<<<1, 64, 0, stream>>>();
    build_w<<<NC, 256, 0, stream>>>(cWih, cWhh, W1, b1);
    gumbel_init<<<256, 256, 0, stream>>>();
    embed_sum<<<NBS, 128, 0, stream>>>(seqs, emb);

    gemm_f64<<<dim3(NBS / 64, 1), 256, 0, stream>>>(A_p, KE, revWih, ND, Ap_p, 40,
                                                    NBS, 40, ND);
    rev_lstm<<<NB, 64, 0, stream>>>(revWhh);
    conv_relu<<<dim3(NB, NS / 8), 256, 0, stream>>>(convw);

    big_gemm<<<dim3(NC / 64, NBS / 64), 256, 0, stream>>>();
    verify_pre<<<32, 256, 0, stream>>>();
    big_fix<<<2048, 256, 0, stream>>>();

    // probes on synthetic state
    synth_hx<<<256, 256, 0, stream>>>();
    step_gemm<<<dim3(4, 40), 256, 0, stream>>>(0, 1);
    verify_step<<<8, 256, 0, stream>>>();

    bool coop = (hipFuncSetAttribute((const void*)loop_fused,
                  hipFuncAttributeMaxDynamicSharedMemorySize, LDSZ) == hipSuccess);
    if (coop) {   // fused sc-path phase-A probe (1 step, B skipped)
        int steps1 = 1, probe1 = 1;
        void* pargs[] = { (void*)&W2, (void*)&b2, (void*)&lengths,
                          (void*)&steps1, (void*)&probe1 };
        hipError_t pe = hipLaunchCooperativeKernel((const void*)loop_fused,
                                                   dim3(NBLK), dim3(512), pargs,
                                                   LDSZ, stream);
        if (pe == hipSuccess) verify_fused<<<16, 256, 0, stream>>>(W2);
        else { (void)hipGetLastError(); coop = false; }
    }
    init_state<<<256, 256, 0, stream>>>();   // resets state + aflag/hxf

    bool launched = false;
    if (coop) {
        int stepsN = NS, probe0 = 0;
        void* args[] = { (void*)&W2, (void*)&b2, (void*)&lengths,
                         (void*)&stepsN, (void*)&probe0 };
        hipError_t ce = hipLaunchCooperativeKernel((const void*)loop_fused,
                                                   dim3(NBLK), dim3(512), args,
                                                   LDSZ, stream);
        if (ce == hipSuccess) launched = true;
        else (void)hipGetLastError();
    }
    if (!launched) {
        for (int t = 0; t < NS; ++t) {
            step_gemm<<<dim3(4, 40), 256, 0, stream>>>(t, 0);
            step_update<<<NB, 256, 0, stream>>>(W2, b2, lengths, t);
        }
    }
    final_out<<<1, 256, 0, stream>>>(Wo, bo, out);
}

// Round 15
// 49151.932 us; speedup vs baseline: 4.7893x; 4.7893x over previous
//
#include <hip/hip_runtime.h>
#include <math.h>

#define NB 128
#define NS 256
#define ND 512
#define NBS (NB*NS)   // 32768
#define KE 544        // 512 x | 10 back | 20 cnn | 1 bias | 1 pad
#define NC 2560       // 2048 cell gates + 512 leap hidden
#define NBLK 80       // loop blocks: 64 gate (32 cols) + 16 leap (32 cols)
#define NGB 64        // gate blocks
#define LDSZ 102464   // 96KB Wl + 4KB W2l + skp

typedef unsigned short u16;
typedef __attribute__((ext_vector_type(8))) short s8v;     // 8 bf16
typedef __attribute__((ext_vector_type(4))) float f4v;     // 4 f32 acc
typedef __attribute__((ext_vector_type(2))) float f2v;     // 8B asm payload
typedef __attribute__((ext_vector_type(4))) unsigned uv4;  // 16B asm payload
typedef __attribute__((ext_vector_type(2))) double dv2;    // 16B asm payload

static constexpr size_t PSA  = (size_t)NBS * KE;
static constexpr size_t PSWE = (size_t)NC  * KE;
static constexpr size_t PSWS = (size_t)NC  * ND;
static constexpr size_t PSH  = (size_t)NB  * ND;

// ---------------- device-global scratch ----------------
// cached-only set (preamble, fallback, host ladder):
__device__ double g_A[(size_t)NBS * KE];
__device__ u16    g_Ab[3 * PSA];
__device__ float  g_Pre[(size_t)NBS * NC];    // [t][b][n]
__device__ double g_Aproj[(size_t)NBS * 40];
__device__ double g_gum[NS * NB * 2];
__device__ double g_hx[NB * ND];
__device__ u16    g_hxb[3 * NB * ND];
__device__ double g_c[NB * ND];
__device__ float  g_gbufF[NB * NC];
__device__ double g_final[NB * ND];
__device__ float  g_Wext[PSWE];
__device__ u16    g_Wextb[3 * PSWE];
__device__ float  g_Wstep[PSWS];
__device__ u16    g_Wstepb[3 * PSWS];
__device__ double g_lpart[32][NB][2];
// sc-only set (persistent loop; never written through caches):
__device__ u16    g_hxbG[3 * NB * ND];
__device__ float  g_gbufG[NB * 2048];
__device__ double g_lpartG[32][NB][2];
// flags (atomics — coherent point):
__device__ int    g_aflag[160 * 32];
__device__ int    g_hxf[NB * 32];
__device__ int    g_ok, g_bad, g_badstep, g_badfused;

__device__ __forceinline__ double sigd(double x) { return 1.0 / (1.0 + exp(-x)); }
__device__ __forceinline__ u16 f2bf(float f) {
    unsigned u = __float_as_uint(f);
    return (u16)((u + 0x7FFFu + ((u >> 16) & 1u)) >> 16);   // RNE
}
__device__ __forceinline__ float bf2f(u16 b) { return __uint_as_float(((unsigned)b) << 16); }
__device__ __forceinline__ void decomp3(float f, u16& b0, u16& b1, u16& b2) {
    b0 = f2bf(f); float r1 = f - bf2f(b0);
    b1 = f2bf(r1); float r2 = r1 - bf2f(b1);
    b2 = f2bf(r2);
}
__device__ __forceinline__ size_t pre_ix(int m, int n) {
    return ((size_t)(m & 255) * NB + (m >> 8)) * NC + n;    // -> [s][b][n]
}
__device__ __forceinline__ void put_Ab(size_t ix, float f) {
    u16 b0, b1, b2; decomp3(f, b0, b1, b2);
    g_Ab[ix] = b0; g_Ab[PSA + ix] = b1; g_Ab[2 * PSA + ix] = b2;
}

// ---- coherence-point (MALL) access helpers ----
__device__ __forceinline__ void sc_store_f32(float* p, float v) {
    asm volatile("global_store_dword %0, %1, off sc0 sc1" :: "v"(p), "v"(v) : "memory");
}
__device__ __forceinline__ void sc_store_u16(u16* p, unsigned v) {
    asm volatile("global_store_short %0, %1, off sc0 sc1" :: "v"(p), "v"(v) : "memory");
}
__device__ __forceinline__ void sc_store_u32(void* p, unsigned v) {
    asm volatile("global_store_dword %0, %1, off sc0 sc1" :: "v"(p), "v"(v) : "memory");
}
__device__ __forceinline__ void sc_store_d2(double* p, dv2 v) {
    asm volatile("global_store_dwordx4 %0, %1, off sc0 sc1" :: "v"(p), "v"(v) : "memory");
}
#define SC_WAIT() do { asm volatile("s_waitcnt vmcnt(0)" ::: "memory"); \
                       __builtin_amdgcn_sched_barrier(0); } while (0)

#define MFMA_BF16 __builtin_amdgcn_mfma_f32_16x16x32_bf16
#define STEP6(AP,AC,A0,A1,A2,B0,B1,B2) \
    AP = MFMA_BF16(A0, B0, AP, 0, 0, 0); \
    AC = MFMA_BF16(A0, B1, AC, 0, 0, 0); \
    AC = MFMA_BF16(A1, B0, AC, 0, 0, 0); \
    AC = MFMA_BF16(A0, B2, AC, 0, 0, 0); \
    AC = MFMA_BF16(A1, B1, AC, 0, 0, 0); \
    AC = MFMA_BF16(A2, B0, AC, 0, 0, 0);

// ---------------- bf16 MFMA layout probe ----------------
__global__ void probe_bf16() {
    int l = threadIdx.x, lr = l & 15, lk = l >> 4;
    s8v a, b;
#pragma unroll
    for (int e = 0; e < 8; ++e) {
        int k = 8 * lk + e;
        a[e] = (short)f2bf((float)(((3 * lr + 7 * k) % 13) + 1));
        b[e] = (short)f2bf((float)(((5 * k + 11 * lr) % 17) + 1));
    }
    f4v d = {0.f, 0.f, 0.f, 0.f};
    d = MFMA_BF16(a, b, d, 0, 0, 0);
    bool okl = true;
#pragma unroll
    for (int r = 0; r < 4; ++r) {
        int row = 4 * lk + r, col = lr;
        int e = 0;
        for (int k = 0; k < 32; ++k)
            e += (((3 * row + 7 * k) % 13) + 1) * (((5 * k + 11 * col) % 17) + 1);
        if (d[r] != (float)e) okl = false;
    }
    unsigned long long vote = __ballot(okl);
    if (l == 0) {
        g_ok = (vote == 0xFFFFFFFFFFFFFFFFull) ? 1 : 0;
        g_bad = 0; g_badstep = 0; g_badfused = 0;
    }
}

// ---------------- init (state + flags; hxbG via sc only) ----------------
__global__ void init_state() {
    int i = blockIdx.x * 256 + threadIdx.x;
    if (i < 160 * 32) g_aflag[i] = 0;
    if (i < NB * 32)  g_hxf[i]  = 0;
    if (i < NB * ND) {
        g_hx[i] = 0.0; g_c[i] = 0.0;
        g_hxb[i] = 0; g_hxb[PSH + i] = 0; g_hxb[2 * PSH + i] = 0;
    }
    if (i < NB * ND / 2) {
#pragma unroll
        for (int p = 0; p < 3; ++p)
            sc_store_u32((void*)(g_hxbG + (size_t)p * PSH + 2 * i), 0u);
    }
}

// ---------------- weight repack + bf16x3 ----------------
__global__ __launch_bounds__(256) void build_w(const float* __restrict__ cWih,
                                               const float* __restrict__ cWhh,
                                               const float* __restrict__ W1,
                                               const float* __restrict__ b1) {
    int n = blockIdx.x;
    for (int c = threadIdx.x; c < KE; c += 256) {
        float we;
        if (n < 2048) we = (c < 512) ? cWih[(size_t)n * 512 + c] : 0.f;
        else {
            int n2 = n - 2048;
            if      (c < 512)  we = W1[(size_t)n2 * 1054 + 512 + c];
            else if (c < 522)  we = W1[(size_t)n2 * 1054 + 1024 + (c - 512)];
            else if (c < 542)  we = W1[(size_t)n2 * 1054 + 1034 + (c - 522)];
            else if (c == 542) we = b1[n2];
            else               we = 0.f;
        }
        size_t ix = (size_t)n * KE + c;
        g_Wext[ix] = we;
        u16 b0, b1_, b2; decomp3(we, b0, b1_, b2);
        g_Wextb[ix] = b0; g_Wextb[PSWE + ix] = b1_; g_Wextb[2 * PSWE + ix] = b2;
        if (c < 512) {
            float ws = (n < 2048) ? cWhh[(size_t)n * 512 + c]
                                  : W1[(size_t)(n - 2048) * 1054 + c];
            size_t ix2 = (size_t)n * ND + c;
            g_Wstep[ix2] = ws;
            decomp3(ws, b0, b1_, b2);
            g_Wstepb[ix2] = b0; g_Wstepb[PSWS + ix2] = b1_; g_Wstepb[2 * PSWS + ix2] = b2;
        }
    }
}

// ---------------- gumbel: JAX partitionable threefry2x32, key (0,42) ----------------
__device__ __forceinline__ unsigned rotl32(unsigned x, int r) { return (x << r) | (x >> (32 - r)); }

__global__ void gumbel_init() {
    unsigned p = blockIdx.x * 256 + threadIdx.x;
    if (p >= 65536u) return;
    unsigned k0 = 0u, k1 = 42u;
    unsigned ks2 = k0 ^ k1 ^ 0x1BD11BDAu;
    unsigned x0 = 0u, x1 = p;
    x0 += k0; x1 += k1;
#define RND(r) { x0 += x1; x1 = rotl32(x1, (r)); x1 ^= x0; }
    RND(13) RND(15) RND(26) RND(6)
    x0 += k1;  x1 += ks2 + 1u;
    RND(17) RND(29) RND(16) RND(24)
    x0 += ks2; x1 += k0 + 2u;
    RND(13) RND(15) RND(26) RND(6)
    x0 += k0;  x1 += k1 + 3u;
    RND(17) RND(29) RND(16) RND(24)
    x0 += k1;  x1 += ks2 + 4u;
    RND(13) RND(15) RND(26) RND(6)
    x0 += ks2; x1 += k0 + 5u;
#undef RND
    unsigned bits = x0 ^ x1;
    float u = __uint_as_float((bits >> 9) | 0x3f800000u) - 1.0f;
    g_gum[p] = log(-log((double)u + 1e-20) + 1e-20);
}

// ---------------- embedding gather+sum ----------------
__global__ __launch_bounds__(128) void embed_sum(const int* __restrict__ seqs,
                                                 const float* __restrict__ emb) {
    int bs = blockIdx.x;
    int tid = threadIdx.x;
    __shared__ int idxs[16];
    if (tid < 16) idxs[tid] = seqs[(size_t)bs * 16 + tid];
    __syncthreads();
    double a0 = 0, a1 = 0, a2 = 0, a3 = 0;
    for (int v = 0; v < 16; ++v) {
        const float4* row = (const float4*)(emb + (size_t)idxs[v] * ND);
        float4 e = row[tid];
        a0 += (double)e.x; a1 += (double)e.y; a2 += (double)e.z; a3 += (double)e.w;
    }
    size_t base = (size_t)bs * KE + tid * 4;
    double* o = g_A + base;
    o[0] = a0; o[1] = a1; o[2] = a2; o[3] = a3;
    put_Ab(base + 0, (float)a0); put_Ab(base + 1, (float)a1);
    put_Ab(base + 2, (float)a2); put_Ab(base + 3, (float)a3);
    if (tid == 0) {
        g_A[(size_t)bs * KE + 542] = 1.0; g_A[(size_t)bs * KE + 543] = 0.0;
        put_Ab((size_t)bs * KE + 542, 1.0f); put_Ab((size_t)bs * KE + 543, 0.0f);
    }
}

// ---------------- f64 vector GEMM (Aproj only) ----------------
__global__ __launch_bounds__(256) void gemm_f64(
    const double* __restrict__ A, int lda,
    const float* __restrict__ W, int ldw,
    double* __restrict__ C, int ldc,
    int M, int N, int K) {
    __shared__ double As[16][66];
    __shared__ double Ws[16][66];
    int m0 = blockIdx.x * 64, n0 = blockIdx.y * 64;
    int tid = threadIdx.x, tx = tid & 15, ty = tid >> 4;
    double acc[4][4] = {};
    for (int k0 = 0; k0 < K; k0 += 16) {
        for (int i = tid; i < 1024; i += 256) {
            int r = i >> 4, c = i & 15;
            As[c][r] = (m0 + r < M && k0 + c < K) ? A[(size_t)(m0 + r) * lda + k0 + c] : 0.0;
            Ws[c][r] = (n0 + r < N && k0 + c < K) ? (double)W[(size_t)(n0 + r) * ldw + k0 + c] : 0.0;
        }
        __syncthreads();
#pragma unroll
        for (int kk = 0; kk < 16; ++kk) {
            double a0 = As[kk][ty*4], a1 = As[kk][ty*4+1], a2 = As[kk][ty*4+2], a3 = As[kk][ty*4+3];
            double w0 = Ws[kk][tx*4], w1 = Ws[kk][tx*4+1], w2 = Ws[kk][tx*4+2], w3 = Ws[kk][tx*4+3];
            acc[0][0] += a0*w0; acc[0][1] += a0*w1; acc[0][2] += a0*w2; acc[0][3] += a0*w3;
            acc[1][0] += a1*w0; acc[1][1] += a1*w1; acc[1][2] += a1*w2; acc[1][3] += a1*w3;
            acc[2][0] += a2*w0; acc[2][1] += a2*w1; acc[2][2] += a2*w2; acc[2][3] += a2*w3;
            acc[3][0] += a3*w0; acc[3][1] += a3*w1; acc[3][2] += a3*w2; acc[3][3] += a3*w3;
        }
        __syncthreads();
    }
#pragma unroll
    for (int i = 0; i < 4; ++i)
#pragma unroll
        for (int j = 0; j < 4; ++j) {
            int m = m0 + ty*4 + i, n = n0 + tx*4 + j;
            if (m < M && n < N) C[(size_t)m * ldc + n] = acc[i][j];
        }
}

// ---------------- reverse LSTM ----------------
__global__ __launch_bounds__(64) void rev_lstm(const float* __restrict__ Whh) {
    int b = blockIdx.x;
    int tid = threadIdx.x;
    __shared__ double h[10], cc[10], g[40], wsh[400];
    for (int i = tid; i < 400; i += 64) wsh[i] = (double)Whh[i];
    if (tid < 10) { h[tid] = 0.0; cc[tid] = 0.0; }
    __syncthreads();
    for (int s = NS - 1; s >= 0; --s) {
        if (tid < 40) {
            double acc = g_Aproj[((size_t)b * NS + s) * 40 + tid];
#pragma unroll
            for (int k = 0; k < 10; ++k) acc += h[k] * wsh[tid * 10 + k];
            g[tid] = acc;
        }
        __syncthreads();
        if (tid < 10) {
            double gi = g[tid], gf = g[10 + tid], gg = g[20 + tid], go = g[30 + tid];
            double cn = sigd(gf) * cc[tid] + sigd(gi) * tanh(gg);
            cc[tid] = cn;
            double hn = sigd(go) * tanh(cn);
            h[tid] = hn;
            size_t ix = ((size_t)b * NS + s) * KE + 512 + tid;
            g_A[ix] = hn;
            put_Ab(ix, (float)hn);
        }
        __syncthreads();
    }
}

// ---------------- conv1d + relu ----------------
__global__ __launch_bounds__(256) void conv_relu(const float* __restrict__ w) {
    int b = blockIdx.x, s0 = blockIdx.y * 8;
    int tid = threadIdx.x, grp = tid >> 5, lane = tid & 31;
    __shared__ double xs[10][ND];
    for (int i = tid; i < 10 * ND; i += 256) {
        int r = i >> 9, d = i & (ND - 1);
        int s = s0 - 1 + r;
        xs[r][d] = (s >= 0 && s < NS) ? g_A[((size_t)b * NS + s) * KE + d] : 0.0;
    }
    __syncthreads();
    int s = s0 + grp;
    for (int o = 0; o < 20; ++o) {
        const float* wo = w + (size_t)o * 1536;
        double acc = 0.0;
        for (int d = lane; d < ND; d += 32) {
            acc += xs[grp][d]     * (double)wo[d*3]
                 + xs[grp + 1][d] * (double)wo[d*3 + 1]
                 + xs[grp + 2][d] * (double)wo[d*3 + 2];
        }
        for (int m = 16; m > 0; m >>= 1) acc += __shfl_xor(acc, m, 32);
        if (lane == 0) {
            double v = acc > 0.0 ? acc : 0.0;
            size_t ix = ((size_t)b * NS + s) * KE + 522 + o;
            g_A[ix] = v;
            put_Ab(ix, (float)v);
        }
    }
}

// ---------------- big GEMM: g_Pre[t][b][n] = g_A @ g_Wext^T ----------------
__global__ __launch_bounds__(256) void big_gemm() {
    __shared__ __align__(16) unsigned char shms[36864];
    int tid = threadIdx.x;
    int n0 = blockIdx.x * 64, m0 = blockIdx.y * 64;
    if (g_ok) {
        u16* usA = (u16*)shms;
        u16* usB = usA + 9216;
        int lane = tid & 63, wave = tid >> 6;
        int wm = (wave & 1) * 32, wn = (wave >> 1) * 32;
        int lr = lane & 15, lk = lane >> 4;
        f4v z = {0.f,0.f,0.f,0.f};
        f4v aP00=z,aP01=z,aP10=z,aP11=z, aC00=z,aC01=z,aC10=z,aC11=z;
        for (int k0 = 0; k0 < KE; k0 += 32) {
            for (int i = tid; i < 1536; i += 256) {
                if (i < 768) {
                    int p = i >> 8, rem = i & 255, r = rem >> 2, sg = rem & 3;
                    *(uint4*)(void*)(usA + p*3072 + r*48 + sg*8) =
                        *(const uint4*)(const void*)(g_Ab + (size_t)p*PSA + (size_t)(m0+r)*KE + k0 + sg*8);
                } else {
                    int j = i - 768;
                    int p = j >> 8, rem = j & 255, r = rem >> 2, sg = rem & 3;
                    *(uint4*)(void*)(usB + p*3072 + r*48 + sg*8) =
                        *(const uint4*)(const void*)(g_Wextb + (size_t)p*PSWE + (size_t)(n0+r)*KE + k0 + sg*8);
                }
            }
            __syncthreads();
            const u16* pa = usA + (wm + lr) * 48 + 8 * lk;
            const u16* pb = usB + (wn + lr) * 48 + 8 * lk;
            s8v a0_0 = *(const s8v*)(const void*)(pa);
            s8v a0_1 = *(const s8v*)(const void*)(pa + 768);
            s8v a1_0 = *(const s8v*)(const void*)(pa + 3072);
            s8v a1_1 = *(const s8v*)(const void*)(pa + 3840);
            s8v a2_0 = *(const s8v*)(const void*)(pa + 6144);
            s8v a2_1 = *(const s8v*)(const void*)(pa + 6912);
            s8v b0_0 = *(const s8v*)(const void*)(pb);
            s8v b0_1 = *(const s8v*)(const void*)(pb + 768);
            s8v b1_0 = *(const s8v*)(const void*)(pb + 3072);
            s8v b1_1 = *(const s8v*)(const void*)(pb + 3840);
            s8v b2_0 = *(const s8v*)(const void*)(pb + 6144);
            s8v b2_1 = *(const s8v*)(const void*)(pb + 6912);
            STEP6(aP00, aC00, a0_0, a1_0, a2_0, b0_0, b1_0, b2_0)
            STEP6(aP01, aC01, a0_0, a1_0, a2_0, b0_1, b1_1, b2_1)
            STEP6(aP10, aC10, a0_1, a1_1, a2_1, b0_0, b1_0, b2_0)
            STEP6(aP11, aC11, a0_1, a1_1, a2_1, b0_1, b1_1, b2_1)
            __syncthreads();
        }
        int rb = m0 + wm + 4 * lk, cb0 = n0 + wn + lr, cb1 = cb0 + 16;
#pragma unroll
        for (int r = 0; r < 4; ++r) {
            g_Pre[pre_ix(rb + r, cb0)]      = aP00[r] + aC00[r];
            g_Pre[pre_ix(rb + r, cb1)]      = aP01[r] + aC01[r];
            g_Pre[pre_ix(rb + 16 + r, cb0)] = aP10[r] + aC10[r];
            g_Pre[pre_ix(rb + 16 + r, cb1)] = aP11[r] + aC11[r];
        }
    } else {
        double* Asd = (double*)shms;
        double* Wsd = Asd + 64 * 33;
        int tx = tid & 15, ty = tid >> 4;
        double acc[4][4] = {};
        for (int k0 = 0; k0 < KE; k0 += 32) {
            for (int i = tid; i < 2048; i += 256) {
                int r = i >> 5, c = i & 31;
                Asd[r * 33 + c] = g_A[(size_t)(m0 + r) * KE + k0 + c];
                Wsd[r * 33 + c] = (double)g_Wext[(size_t)(n0 + r) * KE + k0 + c];
            }
            __syncthreads();
            for (int kk = 0; kk < 32; ++kk) {
                double a0 = Asd[(ty*4)*33+kk], a1 = Asd[(ty*4+1)*33+kk], a2 = Asd[(ty*4+2)*33+kk], a3 = Asd[(ty*4+3)*33+kk];
                double w0 = Wsd[(tx*4)*33+kk], w1 = Wsd[(tx*4+1)*33+kk], w2 = Wsd[(tx*4+2)*33+kk], w3 = Wsd[(tx*4+3)*33+kk];
                acc[0][0] += a0*w0; acc[0][1] += a0*w1; acc[0][2] += a0*w2; acc[0][3] += a0*w3;
                acc[1][0] += a1*w0; acc[1][1] += a1*w1; acc[1][2] += a1*w2; acc[1][3] += a1*w3;
                acc[2][0] += a2*w0; acc[2][1] += a2*w1; acc[2][2] += a2*w2; acc[2][3] += a2*w3;
                acc[3][0] += a3*w0; acc[3][1] += a3*w1; acc[3][2] += a3*w2; acc[3][3] += a3*w3;
            }
            __syncthreads();
        }
#pragma unroll
        for (int i = 0; i < 4; ++i)
#pragma unroll
            for (int j = 0; j < 4; ++j)
                g_Pre[pre_ix(m0 + ty*4 + i, n0 + tx*4 + j)] = (float)acc[i][j];
    }
}

// ---------------- sample-verify g_Pre ----------------
__global__ void verify_pre() {
    int s = blockIdx.x * 256 + threadIdx.x;
    unsigned m = ((unsigned)s * 2654435761u) & 32767u;
    unsigned n = ((unsigned)s * 40503u + 7u) % 2560u;
    double dot = 0.0;
    const double* ar = g_A + (size_t)m * KE;
    const float*  wr = g_Wext + (size_t)n * KE;
    for (int c = 0; c < KE; ++c) dot += ar[c] * (double)wr[c];
    double got = (double)g_Pre[pre_ix((int)m, (int)n)];
    if (fabs(got - dot) > 1e-4 * (1.0 + fabs(dot))) atomicOr(&g_bad, 1);
}

// ---------------- full vector recompute of g_Pre (only if ok && bad) ----------------
__global__ __launch_bounds__(256) void big_fix() {
    if (!(g_ok && g_bad)) return;
    __shared__ double As[64][33];
    __shared__ double Ws[64][33];
    int tid = threadIdx.x, tx = tid & 15, ty = tid >> 4;
    for (int tile = blockIdx.x; tile < (NC/64) * (NBS/64); tile += gridDim.x) {
        int n0 = (tile % (NC/64)) * 64, m0 = (tile / (NC/64)) * 64;
        double acc[4][4] = {};
        for (int k0 = 0; k0 < KE; k0 += 32) {
            for (int i = tid; i < 2048; i += 256) {
                int r = i >> 5, c = i & 31;
                As[r][c] = g_A[(size_t)(m0 + r) * KE + k0 + c];
                Ws[r][c] = (double)g_Wext[(size_t)(n0 + r) * KE + k0 + c];
            }
            __syncthreads();
            for (int kk = 0; kk < 32; ++kk) {
                double a0 = As[ty*4][kk], a1 = As[ty*4+1][kk], a2 = As[ty*4+2][kk], a3 = As[ty*4+3][kk];
                double w0 = Ws[tx*4][kk], w1 = Ws[tx*4+1][kk], w2 = Ws[tx*4+2][kk], w3 = Ws[tx*4+3][kk];
                acc[0][0] += a0*w0; acc[0][1] += a0*w1; acc[0][2] += a0*w2; acc[0][3] += a0*w3;
                acc[1][0] += a1*w0; acc[1][1] += a1*w1; acc[1][2] += a1*w2; acc[1][3] += a1*w3;
                acc[2][0] += a2*w0; acc[2][1] += a2*w1; acc[2][2] += a2*w2; acc[2][3] += a2*w3;
                acc[3][0] += a3*w0; acc[3][1] += a3*w1; acc[3][2] += a3*w2; acc[3][3] += a3*w3;
            }
            __syncthreads();
        }
#pragma unroll
        for (int i = 0; i < 4; ++i)
#pragma unroll
            for (int j = 0; j < 4; ++j)
                g_Pre[pre_ix(m0 + ty*4 + i, n0 + tx*4 + j)] = (float)acc[i][j];
        __syncthreads();
    }
}

// ---------------- synthetic hx (cached set + sc set) ----------------
__global__ void synth_hx() {
    int i = blockIdx.x * 256 + threadIdx.x;
    if (i >= NB * ND) return;
    unsigned h = (unsigned)i * 2654435761u;
    float v = (float)((h >> 8) & 0xFFFFu) / 65536.0f - 0.5f;
    g_hx[i] = (double)v;
    u16 b0, b1, b2; decomp3(v, b0, b1, b2);
    g_hxb[i] = b0; g_hxb[PSH + i] = b1; g_hxb[2 * PSH + i] = b2;
    sc_store_u16(g_hxbG + i, b0);
    sc_store_u16(g_hxbG + PSH + i, b1);
    sc_store_u16(g_hxbG + 2 * PSH + i, b2);
}

// ---------------- standalone step GEMM (probe + host ladder; cached set) ----------------
__global__ __launch_bounds__(256) void step_gemm(int t, int probe) {
    __shared__ double shd[3168];
    int tid = threadIdx.x;
    int m0 = blockIdx.x * 32, n0 = blockIdx.y * 64;
    int use_mfma = g_ok && (probe || !g_badstep);
    if (use_mfma) {
        int lane = tid & 63, wave = tid >> 6;
        int wm = (wave & 1) * 16, wn = (wave >> 1) * 32;
        int lr = lane & 15, lk = lane >> 4;
        size_t ha  = (size_t)(m0 + wm + lr) * ND;
        size_t wb0 = (size_t)(n0 + wn + lr) * ND;
        size_t wb1 = (size_t)(n0 + wn + 16 + lr) * ND;
        f4v z = {0.f,0.f,0.f,0.f};
        f4v aP0=z, aP1=z, aC0=z, aC1=z;
        for (int k0 = 0; k0 < ND; k0 += 32) {
            int kk = k0 + 8 * lk;
            s8v a0  = *(const s8v*)(const void*)(g_hxb + ha + kk);
            s8v a1  = *(const s8v*)(const void*)(g_hxb + PSH + ha + kk);
            s8v a2  = *(const s8v*)(const void*)(g_hxb + 2*PSH + ha + kk);
            s8v b00 = *(const s8v*)(const void*)(g_Wstepb + wb0 + kk);
            s8v b01 = *(const s8v*)(const void*)(g_Wstepb + wb1 + kk);
            s8v b10 = *(const s8v*)(const void*)(g_Wstepb + PSWS + wb0 + kk);
            s8v b11 = *(const s8v*)(const void*)(g_Wstepb + PSWS + wb1 + kk);
            s8v b20 = *(const s8v*)(const void*)(g_Wstepb + 2*PSWS + wb0 + kk);
            s8v b21 = *(const s8v*)(const void*)(g_Wstepb + 2*PSWS + wb1 + kk);
            STEP6(aP0, aC0, a0, a1, a2, b00, b10, b20)
            STEP6(aP1, aC1, a0, a1, a2, b01, b11, b21)
        }
        int rb = m0 + wm + 4 * lk, cb0 = n0 + wn + lr, cb1 = cb0 + 16;
#pragma unroll
        for (int r = 0; r < 4; ++r) {
            g_gbufF[(size_t)(rb + r) * NC + cb0] = aP0[r] + aC0[r]
                + g_Pre[((size_t)t * NB + rb + r) * NC + cb0];
            g_gbufF[(size_t)(rb + r) * NC + cb1] = aP1[r] + aC1[r]
                + g_Pre[((size_t)t * NB + rb + r) * NC + cb1];
        }
    } else {
        double* Asd = shd;
        double* Wsd = shd + 1056;
        int tx = tid & 15, ty = tid >> 4;
        double acc[2][4] = {};
        for (int k0 = 0; k0 < ND; k0 += 32) {
            for (int i = tid; i < 1024; i += 256) {
                int r = i >> 5, c = i & 31;
                Asd[r * 33 + c] = g_hx[(size_t)(m0 + r) * ND + k0 + c];
            }
            for (int i = tid; i < 2048; i += 256) {
                int r = i >> 5, c = i & 31;
                Wsd[r * 33 + c] = (double)g_Wstep[(size_t)(n0 + r) * ND + k0 + c];
            }
            __syncthreads();
            for (int kk = 0; kk < 32; ++kk) {
                double a0 = Asd[(ty*2)*33+kk], a1 = Asd[(ty*2+1)*33+kk];
                double w0 = Wsd[(tx*4)*33+kk], w1 = Wsd[(tx*4+1)*33+kk], w2 = Wsd[(tx*4+2)*33+kk], w3 = Wsd[(tx*4+3)*33+kk];
                acc[0][0] += a0*w0; acc[0][1] += a0*w1; acc[0][2] += a0*w2; acc[0][3] += a0*w3;
                acc[1][0] += a1*w0; acc[1][1] += a1*w1; acc[1][2] += a1*w2; acc[1][3] += a1*w3;
            }
            __syncthreads();
        }
#pragma unroll
        for (int i = 0; i < 2; ++i)
#pragma unroll
            for (int j = 0; j < 4; ++j) {
                int m = m0 + ty*2 + i, n = n0 + tx*4 + j;
                g_gbufF[(size_t)m * NC + n] = (float)(acc[i][j]
                    + (double)g_Pre[((size_t)t * NB + m) * NC + n]);
            }
    }
}

// ---------------- verify standalone step ----------------
__global__ void verify_step() {
    int s = blockIdx.x * 256 + threadIdx.x;
    unsigned m = ((unsigned)s * 2654435761u) & 127u;
    unsigned n = ((unsigned)s * 40503u + 7u) % 2560u;
    double dot = 0.0;
    const double* hr = g_hx + (size_t)m * ND;
    const float*  wr = g_Wstep + (size_t)n * ND;
    for (int c = 0; c < ND; ++c) dot += hr[c] * (double)wr[c];
    dot += (double)g_Pre[(size_t)m * NC + n];
    double got = (double)g_gbufF[(size_t)m * NC + n];
    if (fabs(got - dot) > 1e-4 * (1.0 + fabs(dot))) atomicOr(&g_badstep, 1);
}

// ---------------- verify fused probe output (sc buffers) ----------------
__global__ void verify_fused(const float* __restrict__ W2) {
    int s = blockIdx.x * 256 + threadIdx.x;    // 4096 samples
    unsigned m = ((unsigned)s * 2654435761u) & 127u;
    unsigned h2 = (unsigned)s * 40503u + 7u;
    const double* hr = g_hx + (size_t)m * ND;
    if (s & 1) {
        unsigned q = h2 & 31u;
        double p0 = 0.0, p1 = 0.0;
        for (int c = 0; c < 16; ++c) {
            int col = q * 16 + c;
            const float* wr = g_Wstep + (size_t)(2048 + col) * ND;
            double dot = 0.0;
            for (int k = 0; k < ND; ++k) dot += hr[k] * (double)wr[k];
            dot += (double)g_Pre[(size_t)m * NC + 2048 + col];
            double hh = dot > 0.0 ? dot : 0.0;
            p0 += hh * (double)W2[col];
            p1 += hh * (double)W2[512 + col];
        }
        if (fabs(g_lpartG[q][m][0] - p0) > 1e-4 * (1.0 + fabs(p0)) ||
            fabs(g_lpartG[q][m][1] - p1) > 1e-4 * (1.0 + fabs(p1)))
            atomicOr(&g_badfused, 1);
    } else {
        unsigned n = h2 % 2048u;
        double dot = 0.0;
        const float* wr = g_Wstep + (size_t)n * ND;
        for (int k = 0; k < ND; ++k) dot += hr[k] * (double)wr[k];
        dot += (double)g_Pre[(size_t)m * NC + n];
        double got = (double)g_gbufG[(size_t)m * 2048 + n];
        if (fabs(got - dot) > 1e-4 * (1.0 + fabs(dot))) atomicOr(&g_badfused, 1);
    }
}

// ---------------- standalone per-step update (host ladder; cached set) ----------------
__global__ __launch_bounds__(256) void step_update(
    const float* __restrict__ W2, const float* __restrict__ b2,
    const int* __restrict__ lengths, int t) {
    __shared__ double red[8];
    __shared__ double skipsh[2];
    int b = blockIdx.x, tid = threadIdx.x, lane = tid & 63, wave = tid >> 6;
    const float* gb = g_gbufF + (size_t)b * NC;
    double p0 = 0.0, p1 = 0.0;
    for (int j = tid; j < ND; j += 256) {
        double h = (double)gb[2048 + j];
        h = h > 0.0 ? h : 0.0;
        p0 += h * (double)W2[j];
        p1 += h * (double)W2[ND + j];
    }
    for (int off = 32; off > 0; off >>= 1) {
        p0 += __shfl_down(p0, off, 64);
        p1 += __shfl_down(p1, off, 64);
    }
    if (lane == 0) { red[wave*2] = p0; red[wave*2+1] = p1; }
    __syncthreads();
    if (tid == 0) {
        double l0 = red[0]+red[2]+red[4]+red[6] + (double)b2[0];
        double l1 = red[1]+red[3]+red[5]+red[7] + (double)b2[1];
        double mx = fmax(l0, l1);
        double sh0 = l0 - mx, sh1 = l1 - mx;
        double lsum = log(exp(sh0) + exp(sh1));
        double y0 = (sh0 - lsum) - g_gum[(size_t)t * (NB * 2) + b * 2 + 0];
        double y1 = (sh1 - lsum) - g_gum[(size_t)t * (NB * 2) + b * 2 + 1];
        double xx0 = y0 / 1e-5, xx1 = y1 / 1e-5;
        double mm = fmax(xx0, xx1);
        double e0 = exp(xx0 - mm), e1 = exp(xx1 - mm);
        double inv = 1.0 / (e0 + e1);
        skipsh[0] = e0 * inv; skipsh[1] = e1 * inv;
    }
    __syncthreads();
    double s0 = skipsh[0], s1 = skipsh[1];
    bool isFinal = (t == lengths[b] - 1);
#pragma unroll
    for (int e = 0; e < 2; ++e) {
        int j = tid + 256 * e;
        size_t ix = (size_t)b * ND + j;
        double gi = (double)gb[j], gf = (double)gb[ND + j];
        double gg = (double)gb[2*ND + j], go = (double)gb[3*ND + j];
        double cn = sigd(gf) * g_c[ix] + sigd(gi) * tanh(gg);
        double shx = sigd(go) * tanh(cn);
        double hn = g_hx[ix] * s1 + shx * s0;
        g_c[ix] = cn; g_hx[ix] = hn;
        u16 w0, w1, w2x; decomp3((float)hn, w0, w1, w2x);
        g_hxb[ix] = w0; g_hxb[PSH + ix] = w1; g_hxb[2 * PSH + ix] = w2x;
        if (isFinal) g_final[ix] = hn;
    }
}

// ---------------- persistent flag-synced loop: 80 blocks x 32 cols, sc path ----------------
__global__ __launch_bounds__(512, 1) void loop_fused(const float* __restrict__ W2,
                                                     const float* __restrict__ b2,
                                                     const int* __restrict__ lengths,
                                                     int steps, int probe) {
    extern __shared__ unsigned char shm[];
    int bid = blockIdx.x, tid = threadIdx.x;
    int nc0 = bid * 32;
    int w = tid >> 6, lane = tid & 63;
    int lr = lane & 15, lk = lane >> 4;
    int path = g_ok && !g_badfused;
    int rsel = tid >> 8, ts = tid & 255;
    int row = 2 * bid + rsel;
    double c0 = 0.0, c1 = 0.0, h0 = 0.0, h1 = 0.0;
    int mylen = (bid < NGB) ? lengths[row] : -1;
    u16*    Wl  = (u16*)shm;                      // 96KB bf16x3 (path)
    float*  Wfb = (float*)shm;                    // fallback overlay, stride 521
    float*  W2l = (float*)(shm + 98304);          // 4KB
    double* skp = (double*)(shm + 102400);
    if (path) {
        for (int i = tid; i < 6144; i += 512) {
            int half = i >= 3072, ii = i & 3071;
            int p = ii >> 10, rem = ii & 1023, kk = rem >> 6, l = rem & 63;
            int col16 = l & 15, k8 = l >> 4;
            *(uint4*)(void*)(Wl + half*24576 + p*8192 + kk*512 + l*8) =
                *(const uint4*)(const void*)(g_Wstepb + (size_t)p*PSWS
                      + (size_t)(nc0 + half*16 + col16)*ND + kk*32 + k8*8);
        }
    } else {
        for (int i = tid; i < 32*512; i += 512)
            Wfb[(i >> 9)*521 + (i & 511)] = g_Wstep[(size_t)(nc0 + (i >> 9))*ND + (i & 511)];
    }
    for (int i = tid; i < 1024; i += 512) W2l[i] = W2[i];
    __syncthreads();
    int r0 = 16*w + 4*lk;
    float preA[4], preB[4];
    if (path) {
#pragma unroll
        for (int r = 0; r < 4; ++r) {
            preA[r] = g_Pre[((size_t)0 * NB + r0 + r) * NC + nc0 + lr];
            preB[r] = g_Pre[((size_t)0 * NB + r0 + r) * NC + nc0 + 16 + lr];
        }
    }
    for (int t = 0; t < steps; ++t) {
        if (path) {
            // ================= SC PATH =================
            if (t > 0) {
                for (;;) {
                    bool okp = true;
                    if (lane < 16)
                        okp = (__hip_atomic_load(&g_hxf[(16*w + lane)*32],
                               __ATOMIC_RELAXED, __HIP_MEMORY_SCOPE_AGENT) >= t);
                    if (__all(okp)) break;
                    __builtin_amdgcn_s_sleep(1);
                }
                __builtin_amdgcn_sched_barrier(0);
            }
            f4v z = {0.f,0.f,0.f,0.f};
            f4v aP0 = z, aC0 = z, aP1 = z, aC1 = z;
            size_t ha = (size_t)(16*w + lr) * ND;
#pragma unroll
            for (int q4 = 0; q4 < 4; ++q4) {         // 4 batches of 12 loads
                uv4 U0[4], U1[4], U2[4];
#pragma unroll
                for (int kk = 0; kk < 4; ++kk) {
                    int kb = (q4*4 + kk)*32 + 8*lk;
                    const u16* p0 = g_hxbG + ha + kb;
                    const u16* p1 = g_hxbG + PSH + ha + kb;
                    const u16* p2 = g_hxbG + 2*PSH + ha + kb;
                    asm volatile("global_load_dwordx4 %0, %1, off sc0 sc1"
                                 : "=v"(U0[kk]) : "v"(p0));
                    asm volatile("global_load_dwordx4 %0, %1, off sc0 sc1"
                                 : "=v"(U1[kk]) : "v"(p1));
                    asm volatile("global_load_dwordx4 %0, %1, off sc0 sc1"
                                 : "=v"(U2[kk]) : "v"(p2));
                }
                SC_WAIT();
#pragma unroll
                for (int kk = 0; kk < 4; ++kk) {
                    const u16* wp = Wl + (q4*4 + kk)*512 + lane*8;
                    s8v A0 = __builtin_bit_cast(s8v, U0[kk]);
                    s8v A1 = __builtin_bit_cast(s8v, U1[kk]);
                    s8v A2 = __builtin_bit_cast(s8v, U2[kk]);
                    s8v B00 = *(const s8v*)(const void*)(wp);
                    s8v B01 = *(const s8v*)(const void*)(wp + 8192);
                    s8v B02 = *(const s8v*)(const void*)(wp + 16384);
                    STEP6(aP0, aC0, A0, A1, A2, B00, B01, B02)
                    s8v B10 = *(const s8v*)(const void*)(wp + 24576);
                    s8v B11 = *(const s8v*)(const void*)(wp + 32768);
                    s8v B12 = *(const s8v*)(const void*)(wp + 40960);
                    STEP6(aP1, aC1, A0, A1, A2, B10, B11, B12)
                }
            }
            if (bid < NGB) {
#pragma unroll
                for (int r = 0; r < 4; ++r) {
                    sc_store_f32(g_gbufG + (size_t)(r0 + r) * 2048 + nc0 + lr,
                                 aP0[r] + aC0[r] + preA[r]);
                    sc_store_f32(g_gbufG + (size_t)(r0 + r) * 2048 + nc0 + 16 + lr,
                                 aP1[r] + aC1[r] + preB[r]);
                }
            } else {
                int colg = nc0 - 2048 + lr;
                double q00[4], q01[4], q10[4], q11[4];
#pragma unroll
                for (int r = 0; r < 4; ++r) {
                    float v0 = aP0[r] + aC0[r] + preA[r];
                    float v1 = aP1[r] + aC1[r] + preB[r];
                    double h0d = v0 > 0.f ? (double)v0 : 0.0;
                    double h1d = v1 > 0.f ? (double)v1 : 0.0;
                    q00[r] = h0d * (double)W2l[colg];
                    q01[r] = h0d * (double)W2l[512 + colg];
                    q10[r] = h1d * (double)W2l[colg + 16];
                    q11[r] = h1d * (double)W2l[512 + colg + 16];
                }
#pragma unroll
                for (int m = 8; m > 0; m >>= 1)
#pragma unroll
                    for (int r = 0; r < 4; ++r) {
                        q00[r] += __shfl_xor(q00[r], m, 16);
                        q01[r] += __shfl_xor(q01[r], m, 16);
                        q10[r] += __shfl_xor(q10[r], m, 16);
                        q11[r] += __shfl_xor(q11[r], m, 16);
                    }
                if (lr == 0) {
                    int g = (bid - NGB) * 2;
#pragma unroll
                    for (int r = 0; r < 4; ++r) {
                        dv2 qa; qa[0] = q00[r]; qa[1] = q01[r];
                        sc_store_d2(&g_lpartG[g][r0 + r][0], qa);
                        dv2 qb; qb[0] = q10[r]; qb[1] = q11[r];
                        sc_store_d2(&g_lpartG[g + 1][r0 + r][0], qb);
                    }
                }
            }
            asm volatile("s_waitcnt vmcnt(0)" ::: "memory");
            __syncthreads();
            if (tid == 0)
                __hip_atomic_store(&g_aflag[bid*32], t + 1, __ATOMIC_RELAXED,
                                   __HIP_MEMORY_SCOPE_AGENT);
            __syncthreads();
            {   // prefetch next Pre slice (read-only, cached)
                int tn = (t + 1 < steps) ? t + 1 : t;
#pragma unroll
                for (int r = 0; r < 4; ++r) {
                    preA[r] = g_Pre[((size_t)tn * NB + r0 + r) * NC + nc0 + lr];
                    preB[r] = g_Pre[((size_t)tn * NB + r0 + r) * NC + nc0 + 16 + lr];
                }
            }
            // ---- phase B: rows 2bid, 2bid+1 ----
            if (!probe && bid < NGB) {
                if (ts < NBLK) {
                    while (__hip_atomic_load(&g_aflag[ts*32], __ATOMIC_RELAXED,
                             __HIP_MEMORY_SCOPE_AGENT) < t + 1)
                        __builtin_amdgcn_s_sleep(1);
                }
                __syncthreads();
                __builtin_amdgcn_sched_barrier(0);
                f2v gi2, gf2, gg2, go2;
                {
                    const float* gp = g_gbufG + (size_t)row * 2048 + ts*2;
                    asm volatile("global_load_dwordx2 %0, %1, off sc0 sc1"
                                 : "=v"(gi2) : "v"(gp));
                    asm volatile("global_load_dwordx2 %0, %1, off sc0 sc1"
                                 : "=v"(gf2) : "v"(gp + 512));
                    asm volatile("global_load_dwordx2 %0, %1, off sc0 sc1"
                                 : "=v"(gg2) : "v"(gp + 1024));
                    asm volatile("global_load_dwordx2 %0, %1, off sc0 sc1"
                                 : "=v"(go2) : "v"(gp + 1536));
                }
                double p0 = 0.0, p1 = 0.0;
                if (ts < 32) {
                    dv2 lp;
                    const double* lpp = &g_lpartG[ts][row][0];
                    asm volatile("global_load_dwordx4 %0, %1, off sc0 sc1"
                                 : "=v"(lp) : "v"(lpp));
                    asm volatile("s_waitcnt vmcnt(0)" ::: "memory");
                    p0 = lp[0]; p1 = lp[1];
                }
                __builtin_amdgcn_sched_barrier(0);
                if (ts < 64) {
#pragma unroll
                    for (int m = 16; m > 0; m >>= 1) {
                        p0 += __shfl_xor(p0, m, 32);
                        p1 += __shfl_xor(p1, m, 32);
                    }
                }
                if (ts == 0) {
                    double l0 = p0 + (double)b2[0], l1 = p1 + (double)b2[1];
                    double mx = fmax(l0, l1);
                    double sh0 = l0 - mx, sh1 = l1 - mx;
                    double lsum = log(exp(sh0) + exp(sh1));
                    double y0 = (sh0 - lsum) - g_gum[(size_t)t * (NB*2) + row*2 + 0];
                    double y1 = (sh1 - lsum) - g_gum[(size_t)t * (NB*2) + row*2 + 1];
                    double xx0 = y0 / 1e-5, xx1 = y1 / 1e-5;
                    double mm = fmax(xx0, xx1);
                    double e0 = exp(xx0 - mm), e1 = exp(xx1 - mm);
                    double inv = 1.0 / (e0 + e1);
                    skp[rsel*2 + 0] = e0 * inv; skp[rsel*2 + 1] = e1 * inv;
                }
                __syncthreads();
                SC_WAIT();
                double s0 = skp[rsel*2 + 0], s1 = skp[rsel*2 + 1];
                bool isFinal = (t == mylen - 1);
                u16 pw[3][2];
#pragma unroll
                for (int e = 0; e < 2; ++e) {
                    double gi = (double)gi2[e], gf = (double)gf2[e];
                    double gg = (double)gg2[e], go = (double)go2[e];
                    double& cr = e ? c1 : c0;
                    double& hr = e ? h1 : h0;
                    double cn = sigd(gf) * cr + sigd(gi) * tanh(gg);
                    double shx = sigd(go) * tanh(cn);
                    double hn = hr * s1 + shx * s0;
                    cr = cn; hr = hn;
                    decomp3((float)hn, pw[0][e], pw[1][e], pw[2][e]);
                    if (isFinal) g_final[(size_t)row * ND + ts*2 + e] = hn;
                }
                size_t ixp = (size_t)row * ND + ts*2;
#pragma unroll
                for (int p = 0; p < 3; ++p)
                    sc_store_u32((void*)(g_hxbG + p*PSH + ixp),
                                 (unsigned)pw[p][0] | ((unsigned)pw[p][1] << 16));
                asm volatile("s_waitcnt vmcnt(0)" ::: "memory");
                __syncthreads();
                if (tid == 0) {
                    __hip_atomic_store(&g_hxf[(2*bid)*32], t + 1, __ATOMIC_RELAXED,
                                       __HIP_MEMORY_SCOPE_AGENT);
                    __hip_atomic_store(&g_hxf[(2*bid+1)*32], t + 1, __ATOMIC_RELAXED,
                                       __HIP_MEMORY_SCOPE_AGENT);
                }
            }
        } else {
            // ================= FENCED FALLBACK (f64 vector, cached set) =================
            if (t > 0) {
                if (tid < NB) {
                    while (__hip_atomic_load(&g_hxf[tid*32], __ATOMIC_RELAXED,
                             __HIP_MEMORY_SCOPE_AGENT) < t)
                        __builtin_amdgcn_s_sleep(1);
                }
                __syncthreads();
                if (tid == 0) __builtin_amdgcn_fence(__ATOMIC_ACQUIRE, "agent");
                __syncthreads();
            }
            int col = tid & 31, rgrp = tid >> 5;
            double q0[8], q1[8];
#pragma unroll
            for (int rr = 0; rr < 8; ++rr) {
                int rw = rgrp*8 + rr;
                const double* hr = g_hx + (size_t)rw * ND;
                double dot = 0.0;
                for (int k = 0; k < ND; ++k) dot += hr[k] * (double)Wfb[col*521 + k];
                float v = (float)(dot + (double)g_Pre[((size_t)t * NB + rw) * NC + nc0 + col]);
                if (bid < NGB) {
                    g_gbufF[(size_t)rw * 2048 + nc0 + col] = v;
                    q0[rr] = 0.0; q1[rr] = 0.0;
                } else {
                    double hh = v > 0.f ? (double)v : 0.0;
                    q0[rr] = hh * (double)W2l[nc0 - 2048 + col];
                    q1[rr] = hh * (double)W2l[512 + nc0 - 2048 + col];
                }
            }
            if (bid >= NGB) {
#pragma unroll
                for (int m = 8; m > 0; m >>= 1)
#pragma unroll
                    for (int rr = 0; rr < 8; ++rr) {
                        q0[rr] += __shfl_xor(q0[rr], m, 16);
                        q1[rr] += __shfl_xor(q1[rr], m, 16);
                    }
                if ((col & 15) == 0) {
                    int g = (bid - NGB) * 2 + (col >> 4);
#pragma unroll
                    for (int rr = 0; rr < 8; ++rr) {
                        g_lpart[g][rgrp*8 + rr][0] = q0[rr];
                        g_lpart[g][rgrp*8 + rr][1] = q1[rr];
                    }
                }
            }
            __syncthreads();
            if (tid == 0) {
                __builtin_amdgcn_fence(__ATOMIC_RELEASE, "agent");
                __hip_atomic_store(&g_aflag[bid*32], t + 1, __ATOMIC_RELAXED,
                                   __HIP_MEMORY_SCOPE_AGENT);
            }
            __syncthreads();
            if (!probe && bid < NGB) {
                if (ts < NBLK) {
                    while (__hip_atomic_load(&g_aflag[ts*32], __ATOMIC_RELAXED,
                             __HIP_MEMORY_SCOPE_AGENT) < t + 1)
                        __builtin_amdgcn_s_sleep(1);
                }
                __syncthreads();
                if (tid == 0) __builtin_amdgcn_fence(__ATOMIC_ACQUIRE, "agent");
                __syncthreads();
                double p0 = 0.0, p1 = 0.0;
                if (ts < 32) { p0 = g_lpart[ts][row][0]; p1 = g_lpart[ts][row][1]; }
                if (ts < 64) {
#pragma unroll
                    for (int m = 16; m > 0; m >>= 1) {
                        p0 += __shfl_xor(p0, m, 32);
                        p1 += __shfl_xor(p1, m, 32);
                    }
                }
                if (ts == 0) {
                    double l0 = p0 + (double)b2[0], l1 = p1 + (double)b2[1];
                    double mx = fmax(l0, l1);
                    double sh0 = l0 - mx, sh1 = l1 - mx;
                    double lsum = log(exp(sh0) + exp(sh1));
                    double y0 = (sh0 - lsum) - g_gum[(size_t)t * (NB*2) + row*2 + 0];
                    double y1 = (sh1 - lsum) - g_gum[(size_t)t * (NB*2) + row*2 + 1];
                    double xx0 = y0 / 1e-5, xx1 = y1 / 1e-5;
                    double mm = fmax(xx0, xx1);
                    double e0 = exp(xx0 - mm), e1 = exp(xx1 - mm);
                    double inv = 1.0 / (e0 + e1);
                    skp[rsel*2 + 0] = e0 * inv; skp[rsel*2 + 1] = e1 * inv;
                }
                __syncthreads();
                double s0 = skp[rsel*2 + 0], s1 = skp[rsel*2 + 1];
                bool isFinal = (t == mylen - 1);
                const float* gb = g_gbufF + (size_t)row * 2048;
#pragma unroll
                for (int e = 0; e < 2; ++e) {
                    int j = ts*2 + e;
                    size_t ix = (size_t)row * ND + j;
                    double gi = (double)gb[j], gf = (double)gb[512 + j];
                    double gg = (double)gb[1024 + j], go = (double)gb[1536 + j];
                    double& cr = e ? c1 : c0;
                    double& hr = e ? h1 : h0;
                    double cn = sigd(gf) * cr + sigd(gi) * tanh(gg);
                    double shx = sigd(go) * tanh(cn);
                    double hn = hr * s1 + shx * s0;
                    cr = cn; hr = hn;
                    g_hx[ix] = hn;
                    if (isFinal) g_final[ix] = hn;
                }
                __syncthreads();
                if (tid == 0) {
                    __builtin_amdgcn_fence(__ATOMIC_RELEASE, "agent");
                    __hip_atomic_store(&g_hxf[(2*bid)*32], t + 1, __ATOMIC_RELAXED,
                                       __HIP_MEMORY_SCOPE_AGENT);
                    __hip_atomic_store(&g_hxf[(2*bid+1)*32], t + 1, __ATOMIC_RELAXED,
                                       __HIP_MEMORY_SCOPE_AGENT);
                }
            }
        }
    }
}

// ---------------- final projection ----------------
__global__ __launch_bounds__(256) void final_out(const float* __restrict__ Wo,
                                                 const float* __restrict__ bo,
                                                 float* __restrict__ out) {
    int tid = threadIdx.x;
    int b = tid >> 1, k = tid & 1;
    double acc = 0.0;
    const double* f = g_final + (size_t)b * ND;
    const float* w = Wo + (size_t)k * ND;
    for (int d = 0; d < ND; ++d) acc += f[d] * (double)w[d];
    out[b * 2 + k] = (float)(acc + (double)bo[k]);
}

// ---------------- host launcher ----------------
extern "C" void kernel_launch(void* const* d_in, const int* in_sizes, int n_in,
                              void* d_out, int out_size, void* d_ws, size_t ws_size,
                              hipStream_t stream) {
    (void)in_sizes; (void)n_in; (void)d_ws; (void)ws_size; (void)out_size;
    const int*   seqs    = (const int*)d_in[0];
    const int*   lengths = (const int*)d_in[2];
    const float* emb     = (const float*)d_in[5];
    const float* revWih  = (const float*)d_in[6];
    const float* revWhh  = (const float*)d_in[7];
    const float* convw   = (const float*)d_in[8];
    const float* W1      = (const float*)d_in[9];
    const float* b1      = (const float*)d_in[10];
    const float* W2      = (const float*)d_in[11];
    const float* b2      = (const float*)d_in[12];
    const float* cWih    = (const float*)d_in[13];
    const float* cWhh    = (const float*)d_in[14];
    const float* Wo      = (const float*)d_in[15];
    const float* bo      = (const float*)d_in[16];
    float* out = (float*)d_out;

    double *A_p = nullptr, *Ap_p = nullptr;
    hipGetSymbolAddress((void**)&A_p,  HIP_SYMBOL(g_A));
    hipGetSymbolAddress((void**)&Ap_p, HIP_SYMBOL(g_Aproj));

    probe_bf16<<<1, 64, 0, stream>>>();
    build_w<<<NC, 256, 0, stream>>>(cWih, cWhh, W1, b1);
    gumbel_init<<<256, 256, 0, stream>>>();
    embed_sum<<<NBS, 128, 0, stream>>>(seqs, emb);

    gemm_f64<<<dim3(NBS / 64, 1), 256, 0, stream>>>(A_p, KE, revWih, ND, Ap_p, 40,
                                                    NBS, 40, ND);
    rev_lstm<<<NB, 64, 0, stream>>>(revWhh);
    conv_relu<<<dim3(NB, NS / 8), 256, 0, stream>>>(convw);

    big_gemm<<<dim3(NC / 64, NBS / 64), 256, 0, stream>>>();
    verify_pre<<<32, 256, 0, stream>>>();
    big_fix<<<2048, 256, 0, stream>>>();

    // probes on synthetic state
    synth_hx<<<256, 256, 0, stream>>>();
    step_gemm<<<dim3(4, 40), 256, 0, stream>>>(0, 1);
    verify_step<<<8, 256, 0, stream>>>();

    bool coop = (hipFuncSetAttribute((const void*)loop_fused,
                  hipFuncAttributeMaxDynamicSharedMemorySize, LDSZ) == hipSuccess);
    if (coop) {   // fused sc-path phase-A probe (1 step, B skipped)
        int steps1 = 1, probe1 = 1;
        void* pargs[] = { (void*)&W2, (void*)&b2, (void*)&lengths,
                          (void*)&steps1, (void*)&probe1 };
        hipError_t pe = hipLaunchCooperativeKernel((const void*)loop_fused,
                                                   dim3(NBLK), dim3(512), pargs,
                                                   LDSZ, stream);
        if (pe == hipSuccess) verify_fused<<<16, 256, 0, stream>>>(W2);
        else { (void)hipGetLastError(); coop = false; }
    }
    init_state<<<256, 256, 0, stream>>>();   // resets state + flags + hxbG(sc)

    bool launched = false;
    if (coop) {
        int stepsN = NS, probe0 = 0;
        void* args[] = { (void*)&W2, (void*)&b2, (void*)&lengths,
                         (void*)&stepsN, (void*)&probe0 };
        hipError_t ce = hipLaunchCooperativeKernel((const void*)loop_fused,
                                                   dim3(NBLK), dim3(512), args,
                                                   LDSZ, stream);
        if (ce == hipSuccess) launched = true;
        else (void)hipGetLastError();
    }
    if (!launched) {
        for (int t = 0; t < NS; ++t) {
            step_gemm<<<dim3(4, 40), 256, 0, stream>>>(t, 0);
            step_update<<<NB, 256, 0, stream>>>(W2, b2, lengths, t);
        }
    }
    final_out<<<1, 256, 0, stream>>>(Wo, bo, out);
}

// Round 16
// 10070.780 us; speedup vs baseline: 23.3747x; 4.8806x over previous
//
#include <hip/hip_runtime.h>
#include <math.h>

#define NB 128
#define NS 256
#define ND 512
#define NBS (NB*NS)   // 32768
#define KE 544        // 512 x | 10 back | 20 cnn | 1 bias | 1 pad
#define NC 2560       // 2048 cell gates + 512 leap hidden
#define NBLK 80       // loop blocks: 64 gate (32 cols) + 16 leap (32 cols)
#define NGB 64        // gate blocks
#define LDSZ 102464   // 96KB Wl + 4KB W2l + skp

typedef unsigned short u16;
typedef __attribute__((ext_vector_type(8))) short s8v;     // 8 bf16
typedef __attribute__((ext_vector_type(4))) float f4v;     // 4 f32 acc
typedef __attribute__((ext_vector_type(2))) float f2v;     // 8B asm payload
typedef __attribute__((ext_vector_type(4))) unsigned uv4;  // 16B asm payload
typedef __attribute__((ext_vector_type(2))) double dv2;    // 16B asm payload

static constexpr size_t PSA  = (size_t)NBS * KE;
static constexpr size_t PSWE = (size_t)NC  * KE;
static constexpr size_t PSWS = (size_t)NC  * ND;
static constexpr size_t PSH  = (size_t)NB  * ND;

// ---------------- device-global scratch ----------------
// cached-only set (preamble, fallback, host ladder):
__device__ double g_A[(size_t)NBS * KE];
__device__ u16    g_Ab[3 * PSA];
__device__ float  g_Pre[(size_t)NBS * NC];    // [t][b][n]
__device__ double g_Aproj[(size_t)NBS * 40];
__device__ double g_gum[NS * NB * 2];
__device__ double g_hx[NB * ND];
__device__ u16    g_hxb[3 * NB * ND];
__device__ double g_c[NB * ND];
__device__ float  g_gbufF[NB * NC];
__device__ double g_final[NB * ND];
__device__ float  g_Wext[PSWE];
__device__ u16    g_Wextb[3 * PSWE];
__device__ float  g_Wstep[PSWS];
__device__ u16    g_Wstepb[3 * PSWS];
__device__ double g_lpart[32][NB][2];
// sc-only set (persistent loop; never written through caches):
__device__ u16    g_hxbG[3 * NB * ND];
__device__ float  g_gbufG[NB * 2048];
__device__ double g_lpartG[32][NB][2];
// flags (atomics — coherent point):
__device__ int    g_aflag[160 * 32];
__device__ int    g_hxf[NB * 32];
__device__ int    g_ok, g_bad, g_badstep, g_badfused;

__device__ __forceinline__ double sigd(double x) { return 1.0 / (1.0 + exp(-x)); }
__device__ __forceinline__ u16 f2bf(float f) {
    unsigned u = __float_as_uint(f);
    return (u16)((u + 0x7FFFu + ((u >> 16) & 1u)) >> 16);   // RNE
}
__device__ __forceinline__ float bf2f(u16 b) { return __uint_as_float(((unsigned)b) << 16); }
__device__ __forceinline__ void decomp3(float f, u16& b0, u16& b1, u16& b2) {
    b0 = f2bf(f); float r1 = f - bf2f(b0);
    b1 = f2bf(r1); float r2 = r1 - bf2f(b1);
    b2 = f2bf(r2);
}
__device__ __forceinline__ size_t pre_ix(int m, int n) {
    return ((size_t)(m & 255) * NB + (m >> 8)) * NC + n;    // -> [s][b][n]
}
__device__ __forceinline__ void put_Ab(size_t ix, float f) {
    u16 b0, b1, b2; decomp3(f, b0, b1, b2);
    g_Ab[ix] = b0; g_Ab[PSA + ix] = b1; g_Ab[2 * PSA + ix] = b2;
}

// ---- coherence-point (MALL) access helpers ----
__device__ __forceinline__ void sc_store_f32(float* p, float v) {
    asm volatile("global_store_dword %0, %1, off sc0 sc1" :: "v"(p), "v"(v) : "memory");
}
__device__ __forceinline__ void sc_store_u16(u16* p, unsigned v) {
    asm volatile("global_store_short %0, %1, off sc0 sc1" :: "v"(p), "v"(v) : "memory");
}
__device__ __forceinline__ void sc_store_u32(void* p, unsigned v) {
    asm volatile("global_store_dword %0, %1, off sc0 sc1" :: "v"(p), "v"(v) : "memory");
}
__device__ __forceinline__ void sc_store_d2(double* p, dv2 v) {
    asm volatile("global_store_dwordx4 %0, %1, off sc0 sc1" :: "v"(p), "v"(v) : "memory");
}
#define SC_WAIT() do { asm volatile("s_waitcnt vmcnt(0)" ::: "memory"); \
                       __builtin_amdgcn_sched_barrier(0); } while (0)

#define MFMA_BF16 __builtin_amdgcn_mfma_f32_16x16x32_bf16
#define STEP6(AP,AC,A0,A1,A2,B0,B1,B2) \
    AP = MFMA_BF16(A0, B0, AP, 0, 0, 0); \
    AC = MFMA_BF16(A0, B1, AC, 0, 0, 0); \
    AC = MFMA_BF16(A1, B0, AC, 0, 0, 0); \
    AC = MFMA_BF16(A0, B2, AC, 0, 0, 0); \
    AC = MFMA_BF16(A1, B1, AC, 0, 0, 0); \
    AC = MFMA_BF16(A2, B0, AC, 0, 0, 0);

// ---------------- bf16 MFMA layout probe ----------------
__global__ void probe_bf16() {
    int l = threadIdx.x, lr = l & 15, lk = l >> 4;
    s8v a, b;
#pragma unroll
    for (int e = 0; e < 8; ++e) {
        int k = 8 * lk + e;
        a[e] = (short)f2bf((float)(((3 * lr + 7 * k) % 13) + 1));
        b[e] = (short)f2bf((float)(((5 * k + 11 * lr) % 17) + 1));
    }
    f4v d = {0.f, 0.f, 0.f, 0.f};
    d = MFMA_BF16(a, b, d, 0, 0, 0);
    bool okl = true;
#pragma unroll
    for (int r = 0; r < 4; ++r) {
        int row = 4 * lk + r, col = lr;
        int e = 0;
        for (int k = 0; k < 32; ++k)
            e += (((3 * row + 7 * k) % 13) + 1) * (((5 * k + 11 * col) % 17) + 1);
        if (d[r] != (float)e) okl = false;
    }
    unsigned long long vote = __ballot(okl);
    if (l == 0) {
        g_ok = (vote == 0xFFFFFFFFFFFFFFFFull) ? 1 : 0;
        g_bad = 0; g_badstep = 0; g_badfused = 0;
    }
}

// ---------------- init (state + flags; hxbG via sc only) ----------------
__global__ void init_state() {
    int i = blockIdx.x * 256 + threadIdx.x;
    if (i < 160 * 32) g_aflag[i] = 0;
    if (i < NB * 32)  g_hxf[i]  = 0;
    if (i < NB * ND) {
        g_hx[i] = 0.0; g_c[i] = 0.0;
        g_hxb[i] = 0; g_hxb[PSH + i] = 0; g_hxb[2 * PSH + i] = 0;
    }
    if (i < NB * ND / 2) {
#pragma unroll
        for (int p = 0; p < 3; ++p)
            sc_store_u32((void*)(g_hxbG + (size_t)p * PSH + 2 * i), 0u);
    }
}

// ---------------- weight repack + bf16x3 ----------------
__global__ __launch_bounds__(256) void build_w(const float* __restrict__ cWih,
                                               const float* __restrict__ cWhh,
                                               const float* __restrict__ W1,
                                               const float* __restrict__ b1) {
    int n = blockIdx.x;
    for (int c = threadIdx.x; c < KE; c += 256) {
        float we;
        if (n < 2048) we = (c < 512) ? cWih[(size_t)n * 512 + c] : 0.f;
        else {
            int n2 = n - 2048;
            if      (c < 512)  we = W1[(size_t)n2 * 1054 + 512 + c];
            else if (c < 522)  we = W1[(size_t)n2 * 1054 + 1024 + (c - 512)];
            else if (c < 542)  we = W1[(size_t)n2 * 1054 + 1034 + (c - 522)];
            else if (c == 542) we = b1[n2];
            else               we = 0.f;
        }
        size_t ix = (size_t)n * KE + c;
        g_Wext[ix] = we;
        u16 b0, b1_, b2; decomp3(we, b0, b1_, b2);
        g_Wextb[ix] = b0; g_Wextb[PSWE + ix] = b1_; g_Wextb[2 * PSWE + ix] = b2;
        if (c < 512) {
            float ws = (n < 2048) ? cWhh[(size_t)n * 512 + c]
                                  : W1[(size_t)(n - 2048) * 1054 + c];
            size_t ix2 = (size_t)n * ND + c;
            g_Wstep[ix2] = ws;
            decomp3(ws, b0, b1_, b2);
            g_Wstepb[ix2] = b0; g_Wstepb[PSWS + ix2] = b1_; g_Wstepb[2 * PSWS + ix2] = b2;
        }
    }
}

// ---------------- gumbel: JAX partitionable threefry2x32, key (0,42) ----------------
__device__ __forceinline__ unsigned rotl32(unsigned x, int r) { return (x << r) | (x >> (32 - r)); }

__global__ void gumbel_init() {
    unsigned p = blockIdx.x * 256 + threadIdx.x;
    if (p >= 65536u) return;
    unsigned k0 = 0u, k1 = 42u;
    unsigned ks2 = k0 ^ k1 ^ 0x1BD11BDAu;
    unsigned x0 = 0u, x1 = p;
    x0 += k0; x1 += k1;
#define RND(r) { x0 += x1; x1 = rotl32(x1, (r)); x1 ^= x0; }
    RND(13) RND(15) RND(26) RND(6)
    x0 += k1;  x1 += ks2 + 1u;
    RND(17) RND(29) RND(16) RND(24)
    x0 += ks2; x1 += k0 + 2u;
    RND(13) RND(15) RND(26) RND(6)
    x0 += k0;  x1 += k1 + 3u;
    RND(17) RND(29) RND(16) RND(24)
    x0 += k1;  x1 += ks2 + 4u;
    RND(13) RND(15) RND(26) RND(6)
    x0 += ks2; x1 += k0 + 5u;
#undef RND
    unsigned bits = x0 ^ x1;
    float u = __uint_as_float((bits >> 9) | 0x3f800000u) - 1.0f;
    g_gum[p] = log(-log((double)u + 1e-20) + 1e-20);
}

// ---------------- embedding gather+sum ----------------
__global__ __launch_bounds__(128) void embed_sum(const int* __restrict__ seqs,
                                                 const float* __restrict__ emb) {
    int bs = blockIdx.x;
    int tid = threadIdx.x;
    __shared__ int idxs[16];
    if (tid < 16) idxs[tid] = seqs[(size_t)bs * 16 + tid];
    __syncthreads();
    double a0 = 0, a1 = 0, a2 = 0, a3 = 0;
    for (int v = 0; v < 16; ++v) {
        const float4* row = (const float4*)(emb + (size_t)idxs[v] * ND);
        float4 e = row[tid];
        a0 += (double)e.x; a1 += (double)e.y; a2 += (double)e.z; a3 += (double)e.w;
    }
    size_t base = (size_t)bs * KE + tid * 4;
    double* o = g_A + base;
    o[0] = a0; o[1] = a1; o[2] = a2; o[3] = a3;
    put_Ab(base + 0, (float)a0); put_Ab(base + 1, (float)a1);
    put_Ab(base + 2, (float)a2); put_Ab(base + 3, (float)a3);
    if (tid == 0) {
        g_A[(size_t)bs * KE + 542] = 1.0; g_A[(size_t)bs * KE + 543] = 0.0;
        put_Ab((size_t)bs * KE + 542, 1.0f); put_Ab((size_t)bs * KE + 543, 0.0f);
    }
}

// ---------------- f64 vector GEMM (Aproj only) ----------------
__global__ __launch_bounds__(256) void gemm_f64(
    const double* __restrict__ A, int lda,
    const float* __restrict__ W, int ldw,
    double* __restrict__ C, int ldc,
    int M, int N, int K) {
    __shared__ double As[16][66];
    __shared__ double Ws[16][66];
    int m0 = blockIdx.x * 64, n0 = blockIdx.y * 64;
    int tid = threadIdx.x, tx = tid & 15, ty = tid >> 4;
    double acc[4][4] = {};
    for (int k0 = 0; k0 < K; k0 += 16) {
        for (int i = tid; i < 1024; i += 256) {
            int r = i >> 4, c = i & 15;
            As[c][r] = (m0 + r < M && k0 + c < K) ? A[(size_t)(m0 + r) * lda + k0 + c] : 0.0;
            Ws[c][r] = (n0 + r < N && k0 + c < K) ? (double)W[(size_t)(n0 + r) * ldw + k0 + c] : 0.0;
        }
        __syncthreads();
#pragma unroll
        for (int kk = 0; kk < 16; ++kk) {
            double a0 = As[kk][ty*4], a1 = As[kk][ty*4+1], a2 = As[kk][ty*4+2], a3 = As[kk][ty*4+3];
            double w0 = Ws[kk][tx*4], w1 = Ws[kk][tx*4+1], w2 = Ws[kk][tx*4+2], w3 = Ws[kk][tx*4+3];
            acc[0][0] += a0*w0; acc[0][1] += a0*w1; acc[0][2] += a0*w2; acc[0][3] += a0*w3;
            acc[1][0] += a1*w0; acc[1][1] += a1*w1; acc[1][2] += a1*w2; acc[1][3] += a1*w3;
            acc[2][0] += a2*w0; acc[2][1] += a2*w1; acc[2][2] += a2*w2; acc[2][3] += a2*w3;
            acc[3][0] += a3*w0; acc[3][1] += a3*w1; acc[3][2] += a3*w2; acc[3][3] += a3*w3;
        }
        __syncthreads();
    }
#pragma unroll
    for (int i = 0; i < 4; ++i)
#pragma unroll
        for (int j = 0; j < 4; ++j) {
            int m = m0 + ty*4 + i, n = n0 + tx*4 + j;
            if (m < M && n < N) C[(size_t)m * ldc + n] = acc[i][j];
        }
}

// ---------------- reverse LSTM ----------------
__global__ __launch_bounds__(64) void rev_lstm(const float* __restrict__ Whh) {
    int b = blockIdx.x;
    int tid = threadIdx.x;
    __shared__ double h[10], cc[10], g[40], wsh[400];
    for (int i = tid; i < 400; i += 64) wsh[i] = (double)Whh[i];
    if (tid < 10) { h[tid] = 0.0; cc[tid] = 0.0; }
    __syncthreads();
    for (int s = NS - 1; s >= 0; --s) {
        if (tid < 40) {
            double acc = g_Aproj[((size_t)b * NS + s) * 40 + tid];
#pragma unroll
            for (int k = 0; k < 10; ++k) acc += h[k] * wsh[tid * 10 + k];
            g[tid] = acc;
        }
        __syncthreads();
        if (tid < 10) {
            double gi = g[tid], gf = g[10 + tid], gg = g[20 + tid], go = g[30 + tid];
            double cn = sigd(gf) * cc[tid] + sigd(gi) * tanh(gg);
            cc[tid] = cn;
            double hn = sigd(go) * tanh(cn);
            h[tid] = hn;
            size_t ix = ((size_t)b * NS + s) * KE + 512 + tid;
            g_A[ix] = hn;
            put_Ab(ix, (float)hn);
        }
        __syncthreads();
    }
}

// ---------------- conv1d + relu ----------------
__global__ __launch_bounds__(256) void conv_relu(const float* __restrict__ w) {
    int b = blockIdx.x, s0 = blockIdx.y * 8;
    int tid = threadIdx.x, grp = tid >> 5, lane = tid & 31;
    __shared__ double xs[10][ND];
    for (int i = tid; i < 10 * ND; i += 256) {
        int r = i >> 9, d = i & (ND - 1);
        int s = s0 - 1 + r;
        xs[r][d] = (s >= 0 && s < NS) ? g_A[((size_t)b * NS + s) * KE + d] : 0.0;
    }
    __syncthreads();
    int s = s0 + grp;
    for (int o = 0; o < 20; ++o) {
        const float* wo = w + (size_t)o * 1536;
        double acc = 0.0;
        for (int d = lane; d < ND; d += 32) {
            acc += xs[grp][d]     * (double)wo[d*3]
                 + xs[grp + 1][d] * (double)wo[d*3 + 1]
                 + xs[grp + 2][d] * (double)wo[d*3 + 2];
        }
        for (int m = 16; m > 0; m >>= 1) acc += __shfl_xor(acc, m, 32);
        if (lane == 0) {
            double v = acc > 0.0 ? acc : 0.0;
            size_t ix = ((size_t)b * NS + s) * KE + 522 + o;
            g_A[ix] = v;
            put_Ab(ix, (float)v);
        }
    }
}

// ---------------- big GEMM: g_Pre[t][b][n] = g_A @ g_Wext^T ----------------
__global__ __launch_bounds__(256) void big_gemm() {
    __shared__ __align__(16) unsigned char shms[36864];
    int tid = threadIdx.x;
    int n0 = blockIdx.x * 64, m0 = blockIdx.y * 64;
    if (g_ok) {
        u16* usA = (u16*)shms;
        u16* usB = usA + 9216;
        int lane = tid & 63, wave = tid >> 6;
        int wm = (wave & 1) * 32, wn = (wave >> 1) * 32;
        int lr = lane & 15, lk = lane >> 4;
        f4v z = {0.f,0.f,0.f,0.f};
        f4v aP00=z,aP01=z,aP10=z,aP11=z, aC00=z,aC01=z,aC10=z,aC11=z;
        for (int k0 = 0; k0 < KE; k0 += 32) {
            for (int i = tid; i < 1536; i += 256) {
                if (i < 768) {
                    int p = i >> 8, rem = i & 255, r = rem >> 2, sg = rem & 3;
                    *(uint4*)(void*)(usA + p*3072 + r*48 + sg*8) =
                        *(const uint4*)(const void*)(g_Ab + (size_t)p*PSA + (size_t)(m0+r)*KE + k0 + sg*8);
                } else {
                    int j = i - 768;
                    int p = j >> 8, rem = j & 255, r = rem >> 2, sg = rem & 3;
                    *(uint4*)(void*)(usB + p*3072 + r*48 + sg*8) =
                        *(const uint4*)(const void*)(g_Wextb + (size_t)p*PSWE + (size_t)(n0+r)*KE + k0 + sg*8);
                }
            }
            __syncthreads();
            const u16* pa = usA + (wm + lr) * 48 + 8 * lk;
            const u16* pb = usB + (wn + lr) * 48 + 8 * lk;
            s8v a0_0 = *(const s8v*)(const void*)(pa);
            s8v a0_1 = *(const s8v*)(const void*)(pa + 768);
            s8v a1_0 = *(const s8v*)(const void*)(pa + 3072);
            s8v a1_1 = *(const s8v*)(const void*)(pa + 3840);
            s8v a2_0 = *(const s8v*)(const void*)(pa + 6144);
            s8v a2_1 = *(const s8v*)(const void*)(pa + 6912);
            s8v b0_0 = *(const s8v*)(const void*)(pb);
            s8v b0_1 = *(const s8v*)(const void*)(pb + 768);
            s8v b1_0 = *(const s8v*)(const void*)(pb + 3072);
            s8v b1_1 = *(const s8v*)(const void*)(pb + 3840);
            s8v b2_0 = *(const s8v*)(const void*)(pb + 6144);
            s8v b2_1 = *(const s8v*)(const void*)(pb + 6912);
            STEP6(aP00, aC00, a0_0, a1_0, a2_0, b0_0, b1_0, b2_0)
            STEP6(aP01, aC01, a0_0, a1_0, a2_0, b0_1, b1_1, b2_1)
            STEP6(aP10, aC10, a0_1, a1_1, a2_1, b0_0, b1_0, b2_0)
            STEP6(aP11, aC11, a0_1, a1_1, a2_1, b0_1, b1_1, b2_1)
            __syncthreads();
        }
        int rb = m0 + wm + 4 * lk, cb0 = n0 + wn + lr, cb1 = cb0 + 16;
#pragma unroll
        for (int r = 0; r < 4; ++r) {
            g_Pre[pre_ix(rb + r, cb0)]      = aP00[r] + aC00[r];
            g_Pre[pre_ix(rb + r, cb1)]      = aP01[r] + aC01[r];
            g_Pre[pre_ix(rb + 16 + r, cb0)] = aP10[r] + aC10[r];
            g_Pre[pre_ix(rb + 16 + r, cb1)] = aP11[r] + aC11[r];
        }
    } else {
        double* Asd = (double*)shms;
        double* Wsd = Asd + 64 * 33;
        int tx = tid & 15, ty = tid >> 4;
        double acc[4][4] = {};
        for (int k0 = 0; k0 < KE; k0 += 32) {
            for (int i = tid; i < 2048; i += 256) {
                int r = i >> 5, c = i & 31;
                Asd[r * 33 + c] = g_A[(size_t)(m0 + r) * KE + k0 + c];
                Wsd[r * 33 + c] = (double)g_Wext[(size_t)(n0 + r) * KE + k0 + c];
            }
            __syncthreads();
            for (int kk = 0; kk < 32; ++kk) {
                double a0 = Asd[(ty*4)*33+kk], a1 = Asd[(ty*4+1)*33+kk], a2 = Asd[(ty*4+2)*33+kk], a3 = Asd[(ty*4+3)*33+kk];
                double w0 = Wsd[(tx*4)*33+kk], w1 = Wsd[(tx*4+1)*33+kk], w2 = Wsd[(tx*4+2)*33+kk], w3 = Wsd[(tx*4+3)*33+kk];
                acc[0][0] += a0*w0; acc[0][1] += a0*w1; acc[0][2] += a0*w2; acc[0][3] += a0*w3;
                acc[1][0] += a1*w0; acc[1][1] += a1*w1; acc[1][2] += a1*w2; acc[1][3] += a1*w3;
                acc[2][0] += a2*w0; acc[2][1] += a2*w1; acc[2][2] += a2*w2; acc[2][3] += a2*w3;
                acc[3][0] += a3*w0; acc[3][1] += a3*w1; acc[3][2] += a3*w2; acc[3][3] += a3*w3;
            }
            __syncthreads();
        }
#pragma unroll
        for (int i = 0; i < 4; ++i)
#pragma unroll
            for (int j = 0; j < 4; ++j)
                g_Pre[pre_ix(m0 + ty*4 + i, n0 + tx*4 + j)] = (float)acc[i][j];
    }
}

// ---------------- sample-verify g_Pre ----------------
__global__ void verify_pre() {
    int s = blockIdx.x * 256 + threadIdx.x;
    unsigned m = ((unsigned)s * 2654435761u) & 32767u;
    unsigned n = ((unsigned)s * 40503u + 7u) % 2560u;
    double dot = 0.0;
    const double* ar = g_A + (size_t)m * KE;
    const float*  wr = g_Wext + (size_t)n * KE;
    for (int c = 0; c < KE; ++c) dot += ar[c] * (double)wr[c];
    double got = (double)g_Pre[pre_ix((int)m, (int)n)];
    if (fabs(got - dot) > 1e-4 * (1.0 + fabs(dot))) atomicOr(&g_bad, 1);
}

// ---------------- full vector recompute of g_Pre (only if ok && bad) ----------------
__global__ __launch_bounds__(256) void big_fix() {
    if (!(g_ok && g_bad)) return;
    __shared__ double As[64][33];
    __shared__ double Ws[64][33];
    int tid = threadIdx.x, tx = tid & 15, ty = tid >> 4;
    for (int tile = blockIdx.x; tile < (NC/64) * (NBS/64); tile += gridDim.x) {
        int n0 = (tile % (NC/64)) * 64, m0 = (tile / (NC/64)) * 64;
        double acc[4][4] = {};
        for (int k0 = 0; k0 < KE; k0 += 32) {
            for (int i = tid; i < 2048; i += 256) {
                int r = i >> 5, c = i & 31;
                As[r][c] = g_A[(size_t)(m0 + r) * KE + k0 + c];
                Ws[r][c] = (double)g_Wext[(size_t)(n0 + r) * KE + k0 + c];
            }
            __syncthreads();
            for (int kk = 0; kk < 32; ++kk) {
                double a0 = As[ty*4][kk], a1 = As[ty*4+1][kk], a2 = As[ty*4+2][kk], a3 = As[ty*4+3][kk];
                double w0 = Ws[tx*4][kk], w1 = Ws[tx*4+1][kk], w2 = Ws[tx*4+2][kk], w3 = Ws[tx*4+3][kk];
                acc[0][0] += a0*w0; acc[0][1] += a0*w1; acc[0][2] += a0*w2; acc[0][3] += a0*w3;
                acc[1][0] += a1*w0; acc[1][1] += a1*w1; acc[1][2] += a1*w2; acc[1][3] += a1*w3;
                acc[2][0] += a2*w0; acc[2][1] += a2*w1; acc[2][2] += a2*w2; acc[2][3] += a2*w3;
                acc[3][0] += a3*w0; acc[3][1] += a3*w1; acc[3][2] += a3*w2; acc[3][3] += a3*w3;
            }
            __syncthreads();
        }
#pragma unroll
        for (int i = 0; i < 4; ++i)
#pragma unroll
            for (int j = 0; j < 4; ++j)
                g_Pre[pre_ix(m0 + ty*4 + i, n0 + tx*4 + j)] = (float)acc[i][j];
        __syncthreads();
    }
}

// ---------------- synthetic hx (cached set + sc set) ----------------
__global__ void synth_hx() {
    int i = blockIdx.x * 256 + threadIdx.x;
    if (i >= NB * ND) return;
    unsigned h = (unsigned)i * 2654435761u;
    float v = (float)((h >> 8) & 0xFFFFu) / 65536.0f - 0.5f;
    g_hx[i] = (double)v;
    u16 b0, b1, b2; decomp3(v, b0, b1, b2);
    g_hxb[i] = b0; g_hxb[PSH + i] = b1; g_hxb[2 * PSH + i] = b2;
    sc_store_u16(g_hxbG + i, b0);
    sc_store_u16(g_hxbG + PSH + i, b1);
    sc_store_u16(g_hxbG + 2 * PSH + i, b2);
}

// ---------------- standalone step GEMM (probe + host ladder; cached set) ----------------
__global__ __launch_bounds__(256) void step_gemm(int t, int probe) {
    __shared__ double shd[3168];
    int tid = threadIdx.x;
    int m0 = blockIdx.x * 32, n0 = blockIdx.y * 64;
    int use_mfma = g_ok && (probe || !g_badstep);
    if (use_mfma) {
        int lane = tid & 63, wave = tid >> 6;
        int wm = (wave & 1) * 16, wn = (wave >> 1) * 32;
        int lr = lane & 15, lk = lane >> 4;
        size_t ha  = (size_t)(m0 + wm + lr) * ND;
        size_t wb0 = (size_t)(n0 + wn + lr) * ND;
        size_t wb1 = (size_t)(n0 + wn + 16 + lr) * ND;
        f4v z = {0.f,0.f,0.f,0.f};
        f4v aP0=z, aP1=z, aC0=z, aC1=z;
        for (int k0 = 0; k0 < ND; k0 += 32) {
            int kk = k0 + 8 * lk;
            s8v a0  = *(const s8v*)(const void*)(g_hxb + ha + kk);
            s8v a1  = *(const s8v*)(const void*)(g_hxb + PSH + ha + kk);
            s8v a2  = *(const s8v*)(const void*)(g_hxb + 2*PSH + ha + kk);
            s8v b00 = *(const s8v*)(const void*)(g_Wstepb + wb0 + kk);
            s8v b01 = *(const s8v*)(const void*)(g_Wstepb + wb1 + kk);
            s8v b10 = *(const s8v*)(const void*)(g_Wstepb + PSWS + wb0 + kk);
            s8v b11 = *(const s8v*)(const void*)(g_Wstepb + PSWS + wb1 + kk);
            s8v b20 = *(const s8v*)(const void*)(g_Wstepb + 2*PSWS + wb0 + kk);
            s8v b21 = *(const s8v*)(const void*)(g_Wstepb + 2*PSWS + wb1 + kk);
            STEP6(aP0, aC0, a0, a1, a2, b00, b10, b20)
            STEP6(aP1, aC1, a0, a1, a2, b01, b11, b21)
        }
        int rb = m0 + wm + 4 * lk, cb0 = n0 + wn + lr, cb1 = cb0 + 16;
#pragma unroll
        for (int r = 0; r < 4; ++r) {
            g_gbufF[(size_t)(rb + r) * NC + cb0] = aP0[r] + aC0[r]
                + g_Pre[((size_t)t * NB + rb + r) * NC + cb0];
            g_gbufF[(size_t)(rb + r) * NC + cb1] = aP1[r] + aC1[r]
                + g_Pre[((size_t)t * NB + rb + r) * NC + cb1];
        }
    } else {
        double* Asd = shd;
        double* Wsd = shd + 1056;
        int tx = tid & 15, ty = tid >> 4;
        double acc[2][4] = {};
        for (int k0 = 0; k0 < ND; k0 += 32) {
            for (int i = tid; i < 1024; i += 256) {
                int r = i >> 5, c = i & 31;
                Asd[r * 33 + c] = g_hx[(size_t)(m0 + r) * ND + k0 + c];
            }
            for (int i = tid; i < 2048; i += 256) {
                int r = i >> 5, c = i & 31;
                Wsd[r * 33 + c] = (double)g_Wstep[(size_t)(n0 + r) * ND + k0 + c];
            }
            __syncthreads();
            for (int kk = 0; kk < 32; ++kk) {
                double a0 = Asd[(ty*2)*33+kk], a1 = Asd[(ty*2+1)*33+kk];
                double w0 = Wsd[(tx*4)*33+kk], w1 = Wsd[(tx*4+1)*33+kk], w2 = Wsd[(tx*4+2)*33+kk], w3 = Wsd[(tx*4+3)*33+kk];
                acc[0][0] += a0*w0; acc[0][1] += a0*w1; acc[0][2] += a0*w2; acc[0][3] += a0*w3;
                acc[1][0] += a1*w0; acc[1][1] += a1*w1; acc[1][2] += a1*w2; acc[1][3] += a1*w3;
            }
            __syncthreads();
        }
#pragma unroll
        for (int i = 0; i < 2; ++i)
#pragma unroll
            for (int j = 0; j < 4; ++j) {
                int m = m0 + ty*2 + i, n = n0 + tx*4 + j;
                g_gbufF[(size_t)m * NC + n] = (float)(acc[i][j]
                    + (double)g_Pre[((size_t)t * NB + m) * NC + n]);
            }
    }
}

// ---------------- verify standalone step ----------------
__global__ void verify_step() {
    int s = blockIdx.x * 256 + threadIdx.x;
    unsigned m = ((unsigned)s * 2654435761u) & 127u;
    unsigned n = ((unsigned)s * 40503u + 7u) % 2560u;
    double dot = 0.0;
    const double* hr = g_hx + (size_t)m * ND;
    const float*  wr = g_Wstep + (size_t)n * ND;
    for (int c = 0; c < ND; ++c) dot += hr[c] * (double)wr[c];
    dot += (double)g_Pre[(size_t)m * NC + n];
    double got = (double)g_gbufF[(size_t)m * NC + n];
    if (fabs(got - dot) > 1e-4 * (1.0 + fabs(dot))) atomicOr(&g_badstep, 1);
}

// ---------------- verify fused probe output (sc buffers) ----------------
__global__ void verify_fused(const float* __restrict__ W2) {
    int s = blockIdx.x * 256 + threadIdx.x;    // 4096 samples
    unsigned m = ((unsigned)s * 2654435761u) & 127u;
    unsigned h2 = (unsigned)s * 40503u + 7u;
    const double* hr = g_hx + (size_t)m * ND;
    if (s & 1) {
        unsigned q = h2 & 31u;
        double p0 = 0.0, p1 = 0.0;
        for (int c = 0; c < 16; ++c) {
            int col = q * 16 + c;
            const float* wr = g_Wstep + (size_t)(2048 + col) * ND;
            double dot = 0.0;
            for (int k = 0; k < ND; ++k) dot += hr[k] * (double)wr[k];
            dot += (double)g_Pre[(size_t)m * NC + 2048 + col];
            double hh = dot > 0.0 ? dot : 0.0;
            p0 += hh * (double)W2[col];
            p1 += hh * (double)W2[512 + col];
        }
        if (fabs(g_lpartG[q][m][0] - p0) > 1e-4 * (1.0 + fabs(p0)) ||
            fabs(g_lpartG[q][m][1] - p1) > 1e-4 * (1.0 + fabs(p1)))
            atomicOr(&g_badfused, 1);
    } else {
        unsigned n = h2 % 2048u;
        double dot = 0.0;
        const float* wr = g_Wstep + (size_t)n * ND;
        for (int k = 0; k < ND; ++k) dot += hr[k] * (double)wr[k];
        dot += (double)g_Pre[(size_t)m * NC + n];
        double got = (double)g_gbufG[(size_t)m * 2048 + n];
        if (fabs(got - dot) > 1e-4 * (1.0 + fabs(dot))) atomicOr(&g_badfused, 1);
    }
}

// ---------------- standalone per-step update (host ladder; cached set) ----------------
__global__ __launch_bounds__(256) void step_update(
    const float* __restrict__ W2, const float* __restrict__ b2,
    const int* __restrict__ lengths, int t) {
    __shared__ double red[8];
    __shared__ double skipsh[2];
    int b = blockIdx.x, tid = threadIdx.x, lane = tid & 63, wave = tid >> 6;
    const float* gb = g_gbufF + (size_t)b * NC;
    double p0 = 0.0, p1 = 0.0;
    for (int j = tid; j < ND; j += 256) {
        double h = (double)gb[2048 + j];
        h = h > 0.0 ? h : 0.0;
        p0 += h * (double)W2[j];
        p1 += h * (double)W2[ND + j];
    }
    for (int off = 32; off > 0; off >>= 1) {
        p0 += __shfl_down(p0, off, 64);
        p1 += __shfl_down(p1, off, 64);
    }
    if (lane == 0) { red[wave*2] = p0; red[wave*2+1] = p1; }
    __syncthreads();
    if (tid == 0) {
        double l0 = red[0]+red[2]+red[4]+red[6] + (double)b2[0];
        double l1 = red[1]+red[3]+red[5]+red[7] + (double)b2[1];
        double mx = fmax(l0, l1);
        double sh0 = l0 - mx, sh1 = l1 - mx;
        double lsum = log(exp(sh0) + exp(sh1));
        double y0 = (sh0 - lsum) - g_gum[(size_t)t * (NB * 2) + b * 2 + 0];
        double y1 = (sh1 - lsum) - g_gum[(size_t)t * (NB * 2) + b * 2 + 1];
        double xx0 = y0 / 1e-5, xx1 = y1 / 1e-5;
        double mm = fmax(xx0, xx1);
        double e0 = exp(xx0 - mm), e1 = exp(xx1 - mm);
        double inv = 1.0 / (e0 + e1);
        skipsh[0] = e0 * inv; skipsh[1] = e1 * inv;
    }
    __syncthreads();
    double s0 = skipsh[0], s1 = skipsh[1];
    bool isFinal = (t == lengths[b] - 1);
#pragma unroll
    for (int e = 0; e < 2; ++e) {
        int j = tid + 256 * e;
        size_t ix = (size_t)b * ND + j;
        double gi = (double)gb[j], gf = (double)gb[ND + j];
        double gg = (double)gb[2*ND + j], go = (double)gb[3*ND + j];
        double cn = sigd(gf) * g_c[ix] + sigd(gi) * tanh(gg);
        double shx = sigd(go) * tanh(cn);
        double hn = g_hx[ix] * s1 + shx * s0;
        g_c[ix] = cn; g_hx[ix] = hn;
        u16 w0, w1, w2x; decomp3((float)hn, w0, w1, w2x);
        g_hxb[ix] = w0; g_hxb[PSH + ix] = w1; g_hxb[2 * PSH + ix] = w2x;
        if (isFinal) g_final[ix] = hn;
    }
}

// ---------------- persistent flag-synced loop: 80 blocks x 32 cols, sc path ----------------
__global__ __launch_bounds__(512, 1) void loop_fused(const float* __restrict__ W2,
                                                     const float* __restrict__ b2,
                                                     const int* __restrict__ lengths,
                                                     int steps, int probe) {
    extern __shared__ unsigned char shm[];
    int bid = blockIdx.x, tid = threadIdx.x;
    int nc0 = bid * 32;
    int w = tid >> 6, lane = tid & 63;
    int lr = lane & 15, lk = lane >> 4;
    int path = g_ok && !g_badfused;
    int rsel = tid >> 8, ts = tid & 255;
    int row = 2 * bid + rsel;
    double c0 = 0.0, c1 = 0.0, h0 = 0.0, h1 = 0.0;
    int mylen = (bid < NGB) ? lengths[row] : -1;
    u16*    Wl  = (u16*)shm;                      // 96KB bf16x3 (path)
    float*  Wfb = (float*)shm;                    // fallback overlay, stride 521
    float*  W2l = (float*)(shm + 98304);          // 4KB
    double* skp = (double*)(shm + 102400);
    if (path) {
        for (int i = tid; i < 6144; i += 512) {
            int half = i >= 3072;
            int ii = i - half * 3072;              // FIXED (was i & 3071 — wrong mask)
            int p = ii >> 10, rem = ii & 1023, kk = rem >> 6, l = rem & 63;
            int col16 = l & 15, k8 = l >> 4;
            *(uint4*)(void*)(Wl + half*24576 + p*8192 + kk*512 + l*8) =
                *(const uint4*)(const void*)(g_Wstepb + (size_t)p*PSWS
                      + (size_t)(nc0 + half*16 + col16)*ND + kk*32 + k8*8);
        }
    } else {
        for (int i = tid; i < 32*512; i += 512)
            Wfb[(i >> 9)*521 + (i & 511)] = g_Wstep[(size_t)(nc0 + (i >> 9))*ND + (i & 511)];
    }
    for (int i = tid; i < 1024; i += 512) W2l[i] = W2[i];
    __syncthreads();
    int r0 = 16*w + 4*lk;
    float preA[4], preB[4];
    if (path) {
#pragma unroll
        for (int r = 0; r < 4; ++r) {
            preA[r] = g_Pre[((size_t)0 * NB + r0 + r) * NC + nc0 + lr];
            preB[r] = g_Pre[((size_t)0 * NB + r0 + r) * NC + nc0 + 16 + lr];
        }
    }
    for (int t = 0; t < steps; ++t) {
        if (path) {
            // ================= SC PATH =================
            if (t > 0) {
                for (;;) {
                    bool okp = true;
                    if (lane < 16)
                        okp = (__hip_atomic_load(&g_hxf[(16*w + lane)*32],
                               __ATOMIC_RELAXED, __HIP_MEMORY_SCOPE_AGENT) >= t);
                    if (__all(okp)) break;
                    __builtin_amdgcn_s_sleep(1);
                }
                __builtin_amdgcn_sched_barrier(0);
            }
            f4v z = {0.f,0.f,0.f,0.f};
            f4v aP0 = z, aC0 = z, aP1 = z, aC1 = z;
            size_t ha = (size_t)(16*w + lr) * ND;
#pragma unroll
            for (int q4 = 0; q4 < 4; ++q4) {         // 4 batches of 12 loads
                uv4 U0[4], U1[4], U2[4];
#pragma unroll
                for (int kk = 0; kk < 4; ++kk) {
                    int kb = (q4*4 + kk)*32 + 8*lk;
                    const u16* p0 = g_hxbG + ha + kb;
                    const u16* p1 = g_hxbG + PSH + ha + kb;
                    const u16* p2 = g_hxbG + 2*PSH + ha + kb;
                    asm volatile("global_load_dwordx4 %0, %1, off sc0 sc1"
                                 : "=v"(U0[kk]) : "v"(p0));
                    asm volatile("global_load_dwordx4 %0, %1, off sc0 sc1"
                                 : "=v"(U1[kk]) : "v"(p1));
                    asm volatile("global_load_dwordx4 %0, %1, off sc0 sc1"
                                 : "=v"(U2[kk]) : "v"(p2));
                }
                SC_WAIT();
#pragma unroll
                for (int kk = 0; kk < 4; ++kk) {
                    const u16* wp = Wl + (q4*4 + kk)*512 + lane*8;
                    s8v A0 = __builtin_bit_cast(s8v, U0[kk]);
                    s8v A1 = __builtin_bit_cast(s8v, U1[kk]);
                    s8v A2 = __builtin_bit_cast(s8v, U2[kk]);
                    s8v B00 = *(const s8v*)(const void*)(wp);
                    s8v B01 = *(const s8v*)(const void*)(wp + 8192);
                    s8v B02 = *(const s8v*)(const void*)(wp + 16384);
                    STEP6(aP0, aC0, A0, A1, A2, B00, B01, B02)
                    s8v B10 = *(const s8v*)(const void*)(wp + 24576);
                    s8v B11 = *(const s8v*)(const void*)(wp + 32768);
                    s8v B12 = *(const s8v*)(const void*)(wp + 40960);
                    STEP6(aP1, aC1, A0, A1, A2, B10, B11, B12)
                }
            }
            if (bid < NGB) {
#pragma unroll
                for (int r = 0; r < 4; ++r) {
                    sc_store_f32(g_gbufG + (size_t)(r0 + r) * 2048 + nc0 + lr,
                                 aP0[r] + aC0[r] + preA[r]);
                    sc_store_f32(g_gbufG + (size_t)(r0 + r) * 2048 + nc0 + 16 + lr,
                                 aP1[r] + aC1[r] + preB[r]);
                }
            } else {
                int colg = nc0 - 2048 + lr;
                double q00[4], q01[4], q10[4], q11[4];
#pragma unroll
                for (int r = 0; r < 4; ++r) {
                    float v0 = aP0[r] + aC0[r] + preA[r];
                    float v1 = aP1[r] + aC1[r] + preB[r];
                    double h0d = v0 > 0.f ? (double)v0 : 0.0;
                    double h1d = v1 > 0.f ? (double)v1 : 0.0;
                    q00[r] = h0d * (double)W2l[colg];
                    q01[r] = h0d * (double)W2l[512 + colg];
                    q10[r] = h1d * (double)W2l[colg + 16];
                    q11[r] = h1d * (double)W2l[512 + colg + 16];
                }
#pragma unroll
                for (int m = 8; m > 0; m >>= 1)
#pragma unroll
                    for (int r = 0; r < 4; ++r) {
                        q00[r] += __shfl_xor(q00[r], m, 16);
                        q01[r] += __shfl_xor(q01[r], m, 16);
                        q10[r] += __shfl_xor(q10[r], m, 16);
                        q11[r] += __shfl_xor(q11[r], m, 16);
                    }
                if (lr == 0) {
                    int g = (bid - NGB) * 2;
#pragma unroll
                    for (int r = 0; r < 4; ++r) {
                        dv2 qa; qa[0] = q00[r]; qa[1] = q01[r];
                        sc_store_d2(&g_lpartG[g][r0 + r][0], qa);
                        dv2 qb; qb[0] = q10[r]; qb[1] = q11[r];
                        sc_store_d2(&g_lpartG[g + 1][r0 + r][0], qb);
                    }
                }
            }
            asm volatile("s_waitcnt vmcnt(0)" ::: "memory");
            __syncthreads();
            if (tid == 0)
                __hip_atomic_store(&g_aflag[bid*32], t + 1, __ATOMIC_RELAXED,
                                   __HIP_MEMORY_SCOPE_AGENT);
            __syncthreads();
            {   // prefetch next Pre slice (read-only, cached)
                int tn = (t + 1 < steps) ? t + 1 : t;
#pragma unroll
                for (int r = 0; r < 4; ++r) {
                    preA[r] = g_Pre[((size_t)tn * NB + r0 + r) * NC + nc0 + lr];
                    preB[r] = g_Pre[((size_t)tn * NB + r0 + r) * NC + nc0 + 16 + lr];
                }
            }
            // ---- phase B: rows 2bid, 2bid+1 ----
            if (!probe && bid < NGB) {
                if (ts < NBLK) {
                    while (__hip_atomic_load(&g_aflag[ts*32], __ATOMIC_RELAXED,
                             __HIP_MEMORY_SCOPE_AGENT) < t + 1)
                        __builtin_amdgcn_s_sleep(1);
                }
                __syncthreads();
                __builtin_amdgcn_sched_barrier(0);
                f2v gi2, gf2, gg2, go2;
                {
                    const float* gp = g_gbufG + (size_t)row * 2048 + ts*2;
                    asm volatile("global_load_dwordx2 %0, %1, off sc0 sc1"
                                 : "=v"(gi2) : "v"(gp));
                    asm volatile("global_load_dwordx2 %0, %1, off sc0 sc1"
                                 : "=v"(gf2) : "v"(gp + 512));
                    asm volatile("global_load_dwordx2 %0, %1, off sc0 sc1"
                                 : "=v"(gg2) : "v"(gp + 1024));
                    asm volatile("global_load_dwordx2 %0, %1, off sc0 sc1"
                                 : "=v"(go2) : "v"(gp + 1536));
                }
                double p0 = 0.0, p1 = 0.0;
                if (ts < 32) {
                    dv2 lp;
                    const double* lpp = &g_lpartG[ts][row][0];
                    asm volatile("global_load_dwordx4 %0, %1, off sc0 sc1"
                                 : "=v"(lp) : "v"(lpp));
                    asm volatile("s_waitcnt vmcnt(0)" ::: "memory");
                    p0 = lp[0]; p1 = lp[1];
                }
                __builtin_amdgcn_sched_barrier(0);
                if (ts < 64) {
#pragma unroll
                    for (int m = 16; m > 0; m >>= 1) {
                        p0 += __shfl_xor(p0, m, 32);
                        p1 += __shfl_xor(p1, m, 32);
                    }
                }
                if (ts == 0) {
                    double l0 = p0 + (double)b2[0], l1 = p1 + (double)b2[1];
                    double mx = fmax(l0, l1);
                    double sh0 = l0 - mx, sh1 = l1 - mx;
                    double lsum = log(exp(sh0) + exp(sh1));
                    double y0 = (sh0 - lsum) - g_gum[(size_t)t * (NB*2) + row*2 + 0];
                    double y1 = (sh1 - lsum) - g_gum[(size_t)t * (NB*2) + row*2 + 1];
                    double xx0 = y0 / 1e-5, xx1 = y1 / 1e-5;
                    double mm = fmax(xx0, xx1);
                    double e0 = exp(xx0 - mm), e1 = exp(xx1 - mm);
                    double inv = 1.0 / (e0 + e1);
                    skp[rsel*2 + 0] = e0 * inv; skp[rsel*2 + 1] = e1 * inv;
                }
                __syncthreads();
                SC_WAIT();
                double s0 = skp[rsel*2 + 0], s1 = skp[rsel*2 + 1];
                bool isFinal = (t == mylen - 1);
                u16 pw[3][2];
#pragma unroll
                for (int e = 0; e < 2; ++e) {
                    double gi = (double)gi2[e], gf = (double)gf2[e];
                    double gg = (double)gg2[e], go = (double)go2[e];
                    double& cr = e ? c1 : c0;
                    double& hr = e ? h1 : h0;
                    double cn = sigd(gf) * cr + sigd(gi) * tanh(gg);
                    double shx = sigd(go) * tanh(cn);
                    double hn = hr * s1 + shx * s0;
                    cr = cn; hr = hn;
                    decomp3((float)hn, pw[0][e], pw[1][e], pw[2][e]);
                    if (isFinal) g_final[(size_t)row * ND + ts*2 + e] = hn;
                }
                size_t ixp = (size_t)row * ND + ts*2;
#pragma unroll
                for (int p = 0; p < 3; ++p)
                    sc_store_u32((void*)(g_hxbG + p*PSH + ixp),
                                 (unsigned)pw[p][0] | ((unsigned)pw[p][1] << 16));
                asm volatile("s_waitcnt vmcnt(0)" ::: "memory");
                __syncthreads();
                if (tid == 0) {
                    __hip_atomic_store(&g_hxf[(2*bid)*32], t + 1, __ATOMIC_RELAXED,
                                       __HIP_MEMORY_SCOPE_AGENT);
                    __hip_atomic_store(&g_hxf[(2*bid+1)*32], t + 1, __ATOMIC_RELAXED,
                                       __HIP_MEMORY_SCOPE_AGENT);
                }
            }
        } else {
            // ================= FENCED FALLBACK (f64 vector, cached set) =================
            if (t > 0) {
                if (tid < NB) {
                    while (__hip_atomic_load(&g_hxf[tid*32], __ATOMIC_RELAXED,
                             __HIP_MEMORY_SCOPE_AGENT) < t)
                        __builtin_amdgcn_s_sleep(1);
                }
                __syncthreads();
                if (tid == 0) __builtin_amdgcn_fence(__ATOMIC_ACQUIRE, "agent");
                __syncthreads();
            }
            int col = tid & 31, rgrp = tid >> 5;
            double q0[8], q1[8];
#pragma unroll
            for (int rr = 0; rr < 8; ++rr) {
                int rw = rgrp*8 + rr;
                const double* hr = g_hx + (size_t)rw * ND;
                double dot = 0.0;
                for (int k = 0; k < ND; ++k) dot += hr[k] * (double)Wfb[col*521 + k];
                float v = (float)(dot + (double)g_Pre[((size_t)t * NB + rw) * NC + nc0 + col]);
                if (bid < NGB) {
                    g_gbufF[(size_t)rw * 2048 + nc0 + col] = v;
                    q0[rr] = 0.0; q1[rr] = 0.0;
                } else {
                    double hh = v > 0.f ? (double)v : 0.0;
                    q0[rr] = hh * (double)W2l[nc0 - 2048 + col];
                    q1[rr] = hh * (double)W2l[512 + nc0 - 2048 + col];
                }
            }
            if (bid >= NGB) {
#pragma unroll
                for (int m = 8; m > 0; m >>= 1)
#pragma unroll
                    for (int rr = 0; rr < 8; ++rr) {
                        q0[rr] += __shfl_xor(q0[rr], m, 16);
                        q1[rr] += __shfl_xor(q1[rr], m, 16);
                    }
                if ((col & 15) == 0) {
                    int g = (bid - NGB) * 2 + (col >> 4);
#pragma unroll
                    for (int rr = 0; rr < 8; ++rr) {
                        g_lpart[g][rgrp*8 + rr][0] = q0[rr];
                        g_lpart[g][rgrp*8 + rr][1] = q1[rr];
                    }
                }
            }
            __syncthreads();
            if (tid == 0) {
                __builtin_amdgcn_fence(__ATOMIC_RELEASE, "agent");
                __hip_atomic_store(&g_aflag[bid*32], t + 1, __ATOMIC_RELAXED,
                                   __HIP_MEMORY_SCOPE_AGENT);
            }
            __syncthreads();
            if (!probe && bid < NGB) {
                if (ts < NBLK) {
                    while (__hip_atomic_load(&g_aflag[ts*32], __ATOMIC_RELAXED,
                             __HIP_MEMORY_SCOPE_AGENT) < t + 1)
                        __builtin_amdgcn_s_sleep(1);
                }
                __syncthreads();
                if (tid == 0) __builtin_amdgcn_fence(__ATOMIC_ACQUIRE, "agent");
                __syncthreads();
                double p0 = 0.0, p1 = 0.0;
                if (ts < 32) { p0 = g_lpart[ts][row][0]; p1 = g_lpart[ts][row][1]; }
                if (ts < 64) {
#pragma unroll
                    for (int m = 16; m > 0; m >>= 1) {
                        p0 += __shfl_xor(p0, m, 32);
                        p1 += __shfl_xor(p1, m, 32);
                    }
                }
                if (ts == 0) {
                    double l0 = p0 + (double)b2[0], l1 = p1 + (double)b2[1];
                    double mx = fmax(l0, l1);
                    double sh0 = l0 - mx, sh1 = l1 - mx;
                    double lsum = log(exp(sh0) + exp(sh1));
                    double y0 = (sh0 - lsum) - g_gum[(size_t)t * (NB*2) + row*2 + 0];
                    double y1 = (sh1 - lsum) - g_gum[(size_t)t * (NB*2) + row*2 + 1];
                    double xx0 = y0 / 1e-5, xx1 = y1 / 1e-5;
                    double mm = fmax(xx0, xx1);
                    double e0 = exp(xx0 - mm), e1 = exp(xx1 - mm);
                    double inv = 1.0 / (e0 + e1);
                    skp[rsel*2 + 0] = e0 * inv; skp[rsel*2 + 1] = e1 * inv;
                }
                __syncthreads();
                double s0 = skp[rsel*2 + 0], s1 = skp[rsel*2 + 1];
                bool isFinal = (t == mylen - 1);
                const float* gb = g_gbufF + (size_t)row * 2048;
#pragma unroll
                for (int e = 0; e < 2; ++e) {
                    int j = ts*2 + e;
                    size_t ix = (size_t)row * ND + j;
                    double gi = (double)gb[j], gf = (double)gb[512 + j];
                    double gg = (double)gb[1024 + j], go = (double)gb[1536 + j];
                    double& cr = e ? c1 : c0;
                    double& hr = e ? h1 : h0;
                    double cn = sigd(gf) * cr + sigd(gi) * tanh(gg);
                    double shx = sigd(go) * tanh(cn);
                    double hn = hr * s1 + shx * s0;
                    cr = cn; hr = hn;
                    g_hx[ix] = hn;
                    if (isFinal) g_final[ix] = hn;
                }
                __syncthreads();
                if (tid == 0) {
                    __builtin_amdgcn_fence(__ATOMIC_RELEASE, "agent");
                    __hip_atomic_store(&g_hxf[(2*bid)*32], t + 1, __ATOMIC_RELAXED,
                                       __HIP_MEMORY_SCOPE_AGENT);
                    __hip_atomic_store(&g_hxf[(2*bid+1)*32], t + 1, __ATOMIC_RELAXED,
                                       __HIP_MEMORY_SCOPE_AGENT);
                }
            }
        }
    }
}

// ---------------- final projection ----------------
__global__ __launch_bounds__(256) void final_out(const float* __restrict__ Wo,
                                                 const float* __restrict__ bo,
                                                 float* __restrict__ out) {
    int tid = threadIdx.x;
    int b = tid >> 1, k = tid & 1;
    double acc = 0.0;
    const double* f = g_final + (size_t)b * ND;
    const float* w = Wo + (size_t)k * ND;
    for (int d = 0; d < ND; ++d) acc += f[d] * (double)w[d];
    out[b * 2 + k] = (float)(acc + (double)bo[k]);
}

// ---------------- host launcher ----------------
extern "C" void kernel_launch(void* const* d_in, const int* in_sizes, int n_in,
                              void* d_out, int out_size, void* d_ws, size_t ws_size,
                              hipStream_t stream) {
    (void)in_sizes; (void)n_in; (void)d_ws; (void)ws_size; (void)out_size;
    const int*   seqs    = (const int*)d_in[0];
    const int*   lengths = (const int*)d_in[2];
    const float* emb     = (const float*)d_in[5];
    const float* revWih  = (const float*)d_in[6];
    const float* revWhh  = (const float*)d_in[7];
    const float* convw   = (const float*)d_in[8];
    const float* W1      = (const float*)d_in[9];
    const float* b1      = (const float*)d_in[10];
    const float* W2      = (const float*)d_in[11];
    const float* b2      = (const float*)d_in[12];
    const float* cWih    = (const float*)d_in[13];
    const float* cWhh    = (const float*)d_in[14];
    const float* Wo      = (const float*)d_in[15];
    const float* bo      = (const float*)d_in[16];
    float* out = (float*)d_out;

    double *A_p = nullptr, *Ap_p = nullptr;
    hipGetSymbolAddress((void**)&A_p,  HIP_SYMBOL(g_A));
    hipGetSymbolAddress((void**)&Ap_p, HIP_SYMBOL(g_Aproj));

    probe_bf16<<<1, 64, 0, stream>>>();
    build_w<<<NC, 256, 0, stream>>>(cWih, cWhh, W1, b1);
    gumbel_init<<<256, 256, 0, stream>>>();
    embed_sum<<<NBS, 128, 0, stream>>>(seqs, emb);

    gemm_f64<<<dim3(NBS / 64, 1), 256, 0, stream>>>(A_p, KE, revWih, ND, Ap_p, 40,
                                                    NBS, 40, ND);
    rev_lstm<<<NB, 64, 0, stream>>>(revWhh);
    conv_relu<<<dim3(NB, NS / 8), 256, 0, stream>>>(convw);

    big_gemm<<<dim3(NC / 64, NBS / 64), 256, 0, stream>>>();
    verify_pre<<<32, 256, 0, stream>>>();
    big_fix<<<2048, 256, 0, stream>>>();

    // probes on synthetic state
    synth_hx<<<256, 256, 0, stream>>>();
    step_gemm<<<dim3(4, 40), 256, 0, stream>>>(0, 1);
    verify_step<<<8, 256, 0, stream>>>();

    bool coop = (hipFuncSetAttribute((const void*)loop_fused,
                  hipFuncAttributeMaxDynamicSharedMemorySize, LDSZ) == hipSuccess);
    if (coop) {   // fused sc-path phase-A probe (1 step, B skipped)
        int steps1 = 1, probe1 = 1;
        void* pargs[] = { (void*)&W2, (void*)&b2, (void*)&lengths,
                          (void*)&steps1, (void*)&probe1 };
        hipError_t pe = hipLaunchCooperativeKernel((const void*)loop_fused,
                                                   dim3(NBLK), dim3(512), pargs,
                                                   LDSZ, stream);
        if (pe == hipSuccess) verify_fused<<<16, 256, 0, stream>>>(W2);
        else { (void)hipGetLastError(); coop = false; }
    }
    init_state<<<256, 256, 0, stream>>>();   // resets state + flags + hxbG(sc)

    bool launched = false;
    if (coop) {
        int stepsN = NS, probe0 = 0;
        void* args[] = { (void*)&W2, (void*)&b2, (void*)&lengths,
                         (void*)&stepsN, (void*)&probe0 };
        hipError_t ce = hipLaunchCooperativeKernel((const void*)loop_fused,
                                                   dim3(NBLK), dim3(512), args,
                                                   LDSZ, stream);
        if (ce == hipSuccess) launched = true;
        else (void)hipGetLastError();
    }
    if (!launched) {
        for (int t = 0; t < NS; ++t) {
            step_gemm<<<dim3(4, 40), 256, 0, stream>>>(t, 0);
            step_update<<<NB, 256, 0, stream>>>(W2, b2, lengths, t);
        }
    }
    final_out<<<1, 256, 0, stream>>>(Wo, bo, out);
}

// Round 17
// 9081.724 us; speedup vs baseline: 25.9204x; 1.1089x over previous
//
#include <hip/hip_runtime.h>
#include <math.h>

#define NB 128
#define NS 256
#define ND 512
#define NBS (NB*NS)   // 32768
#define KE 544        // 512 x | 10 back | 20 cnn | 1 bias | 1 pad
#define NC 2560       // 2048 cell gates + 512 leap hidden

typedef unsigned short u16;
typedef __attribute__((ext_vector_type(8))) short s8v;     // 8 bf16
typedef __attribute__((ext_vector_type(4))) float f4v;     // 4 f32 acc
typedef __attribute__((ext_vector_type(4))) unsigned uv4;  // 16B asm payload
typedef __attribute__((ext_vector_type(2))) double dv2;    // 16B asm payload

static constexpr size_t PSA  = (size_t)NBS * KE;
static constexpr size_t PSWE = (size_t)NC  * KE;
static constexpr size_t PSWS = (size_t)NC  * ND;
static constexpr size_t PSH  = (size_t)NB  * ND;

// ---------------- device-global scratch ----------------
// cached-only set (preamble, fallback, host ladder):
__device__ double g_A[(size_t)NBS * KE];
__device__ u16    g_Ab[3 * PSA];
__device__ float  g_Pre[(size_t)NBS * NC];    // [t][b][n]
__device__ double g_Aproj[(size_t)NBS * 40];
__device__ double g_gum[NS * NB * 2];
__device__ double g_hx[NB * ND];
__device__ u16    g_hxb[3 * NB * ND];
__device__ double g_c[NB * ND];
__device__ float  g_gbufF[NB * NC];
__device__ double g_final[NB * ND];
__device__ float  g_Wext[PSWE];
__device__ u16    g_Wextb[3 * PSWE];
__device__ float  g_Wstep[PSWS];
__device__ u16    g_Wstepb[3 * PSWS];
__device__ double g_lpart[32][NB][2];
// sc-only set (persistent loop; written only via sc0sc1):
__device__ u16    g_hxbG[3 * NB * ND];
__device__ float  g_gbufG[NB * 2048];
__device__ double g_lpartG[32][NB][2];
// flags (atomics — coherence point):
__device__ int    g_aflag[160 * 32];
__device__ int    g_hxf[NB * 32];
__device__ int    g_ok, g_bad, g_badstep, g_badfused;

__device__ __forceinline__ double sigd(double x) { return 1.0 / (1.0 + exp(-x)); }
__device__ __forceinline__ u16 f2bf(float f) {
    unsigned u = __float_as_uint(f);
    return (u16)((u + 0x7FFFu + ((u >> 16) & 1u)) >> 16);   // RNE
}
__device__ __forceinline__ float bf2f(u16 b) { return __uint_as_float(((unsigned)b) << 16); }
__device__ __forceinline__ void decomp3(float f, u16& b0, u16& b1, u16& b2) {
    b0 = f2bf(f); float r1 = f - bf2f(b0);
    b1 = f2bf(r1); float r2 = r1 - bf2f(b1);
    b2 = f2bf(r2);
}
__device__ __forceinline__ size_t pre_ix(int m, int n) {
    return ((size_t)(m & 255) * NB + (m >> 8)) * NC + n;    // -> [s][b][n]
}
__device__ __forceinline__ void put_Ab(size_t ix, float f) {
    u16 b0, b1, b2; decomp3(f, b0, b1, b2);
    g_Ab[ix] = b0; g_Ab[PSA + ix] = b1; g_Ab[2 * PSA + ix] = b2;
}

// ---- coherence-point (MALL) access helpers ----
__device__ __forceinline__ void sc_store_f32(float* p, float v) {
    asm volatile("global_store_dword %0, %1, off sc0 sc1" :: "v"(p), "v"(v) : "memory");
}
__device__ __forceinline__ void sc_store_u16(u16* p, unsigned v) {
    asm volatile("global_store_short %0, %1, off sc0 sc1" :: "v"(p), "v"(v) : "memory");
}
__device__ __forceinline__ void sc_store_u32(void* p, unsigned v) {
    asm volatile("global_store_dword %0, %1, off sc0 sc1" :: "v"(p), "v"(v) : "memory");
}
__device__ __forceinline__ void sc_store_d2(double* p, dv2 v) {
    asm volatile("global_store_dwordx4 %0, %1, off sc0 sc1" :: "v"(p), "v"(v) : "memory");
}
#define SC_WAIT() do { asm volatile("s_waitcnt vmcnt(0)" ::: "memory"); \
                       __builtin_amdgcn_sched_barrier(0); } while (0)

#define MFMA_BF16 __builtin_amdgcn_mfma_f32_16x16x32_bf16
#define STEP6(AP,AC,A0,A1,A2,B0,B1,B2) \
    AP = MFMA_BF16(A0, B0, AP, 0, 0, 0); \
    AC = MFMA_BF16(A0, B1, AC, 0, 0, 0); \
    AC = MFMA_BF16(A1, B0, AC, 0, 0, 0); \
    AC = MFMA_BF16(A0, B2, AC, 0, 0, 0); \
    AC = MFMA_BF16(A1, B1, AC, 0, 0, 0); \
    AC = MFMA_BF16(A2, B0, AC, 0, 0, 0);

// ---------------- bf16 MFMA layout probe ----------------
__global__ void probe_bf16() {
    int l = threadIdx.x, lr = l & 15, lk = l >> 4;
    s8v a, b;
#pragma unroll
    for (int e = 0; e < 8; ++e) {
        int k = 8 * lk + e;
        a[e] = (short)f2bf((float)(((3 * lr + 7 * k) % 13) + 1));
        b[e] = (short)f2bf((float)(((5 * k + 11 * lr) % 17) + 1));
    }
    f4v d = {0.f, 0.f, 0.f, 0.f};
    d = MFMA_BF16(a, b, d, 0, 0, 0);
    bool okl = true;
#pragma unroll
    for (int r = 0; r < 4; ++r) {
        int row = 4 * lk + r, col = lr;
        int e = 0;
        for (int k = 0; k < 32; ++k)
            e += (((3 * row + 7 * k) % 13) + 1) * (((5 * k + 11 * col) % 17) + 1);
        if (d[r] != (float)e) okl = false;
    }
    unsigned long long vote = __ballot(okl);
    if (l == 0) {
        g_ok = (vote == 0xFFFFFFFFFFFFFFFFull) ? 1 : 0;
        g_bad = 0; g_badstep = 0; g_badfused = 0;
    }
}

// ---------------- init (state + flags; hxbG via sc only) ----------------
__global__ void init_state() {
    int i = blockIdx.x * 256 + threadIdx.x;
    if (i < 160 * 32) g_aflag[i] = 0;
    if (i < NB * 32)  g_hxf[i]  = 0;
    if (i < NB * ND) {
        g_hx[i] = 0.0; g_c[i] = 0.0;
        g_hxb[i] = 0; g_hxb[PSH + i] = 0; g_hxb[2 * PSH + i] = 0;
    }
    if (i < NB * ND / 2) {
#pragma unroll
        for (int p = 0; p < 3; ++p)
            sc_store_u32((void*)(g_hxbG + (size_t)p * PSH + 2 * i), 0u);
    }
}

// ---------------- weight repack + bf16x3 ----------------
__global__ __launch_bounds__(256) void build_w(const float* __restrict__ cWih,
                                               const float* __restrict__ cWhh,
                                               const float* __restrict__ W1,
                                               const float* __restrict__ b1) {
    int n = blockIdx.x;
    for (int c = threadIdx.x; c < KE; c += 256) {
        float we;
        if (n < 2048) we = (c < 512) ? cWih[(size_t)n * 512 + c] : 0.f;
        else {
            int n2 = n - 2048;
            if      (c < 512)  we = W1[(size_t)n2 * 1054 + 512 + c];
            else if (c < 522)  we = W1[(size_t)n2 * 1054 + 1024 + (c - 512)];
            else if (c < 542)  we = W1[(size_t)n2 * 1054 + 1034 + (c - 522)];
            else if (c == 542) we = b1[n2];
            else               we = 0.f;
        }
        size_t ix = (size_t)n * KE + c;
        g_Wext[ix] = we;
        u16 b0, b1_, b2; decomp3(we, b0, b1_, b2);
        g_Wextb[ix] = b0; g_Wextb[PSWE + ix] = b1_; g_Wextb[2 * PSWE + ix] = b2;
        if (c < 512) {
            float ws = (n < 2048) ? cWhh[(size_t)n * 512 + c]
                                  : W1[(size_t)(n - 2048) * 1054 + c];
            size_t ix2 = (size_t)n * ND + c;
            g_Wstep[ix2] = ws;
            decomp3(ws, b0, b1_, b2);
            g_Wstepb[ix2] = b0; g_Wstepb[PSWS + ix2] = b1_; g_Wstepb[2 * PSWS + ix2] = b2;
        }
    }
}

// ---------------- gumbel: JAX partitionable threefry2x32, key (0,42) ----------------
__device__ __forceinline__ unsigned rotl32(unsigned x, int r) { return (x << r) | (x >> (32 - r)); }

__global__ void gumbel_init() {
    unsigned p = blockIdx.x * 256 + threadIdx.x;
    if (p >= 65536u) return;
    unsigned k0 = 0u, k1 = 42u;
    unsigned ks2 = k0 ^ k1 ^ 0x1BD11BDAu;
    unsigned x0 = 0u, x1 = p;
    x0 += k0; x1 += k1;
#define RND(r) { x0 += x1; x1 = rotl32(x1, (r)); x1 ^= x0; }
    RND(13) RND(15) RND(26) RND(6)
    x0 += k1;  x1 += ks2 + 1u;
    RND(17) RND(29) RND(16) RND(24)
    x0 += ks2; x1 += k0 + 2u;
    RND(13) RND(15) RND(26) RND(6)
    x0 += k0;  x1 += k1 + 3u;
    RND(17) RND(29) RND(16) RND(24)
    x0 += k1;  x1 += ks2 + 4u;
    RND(13) RND(15) RND(26) RND(6)
    x0 += ks2; x1 += k0 + 5u;
#undef RND
    unsigned bits = x0 ^ x1;
    float u = __uint_as_float((bits >> 9) | 0x3f800000u) - 1.0f;
    g_gum[p] = log(-log((double)u + 1e-20) + 1e-20);
}

// ---------------- embedding gather+sum ----------------
__global__ __launch_bounds__(128) void embed_sum(const int* __restrict__ seqs,
                                                 const float* __restrict__ emb) {
    int bs = blockIdx.x;
    int tid = threadIdx.x;
    __shared__ int idxs[16];
    if (tid < 16) idxs[tid] = seqs[(size_t)bs * 16 + tid];
    __syncthreads();
    double a0 = 0, a1 = 0, a2 = 0, a3 = 0;
    for (int v = 0; v < 16; ++v) {
        const float4* row = (const float4*)(emb + (size_t)idxs[v] * ND);
        float4 e = row[tid];
        a0 += (double)e.x; a1 += (double)e.y; a2 += (double)e.z; a3 += (double)e.w;
    }
    size_t base = (size_t)bs * KE + tid * 4;
    double* o = g_A + base;
    o[0] = a0; o[1] = a1; o[2] = a2; o[3] = a3;
    put_Ab(base + 0, (float)a0); put_Ab(base + 1, (float)a1);
    put_Ab(base + 2, (float)a2); put_Ab(base + 3, (float)a3);
    if (tid == 0) {
        g_A[(size_t)bs * KE + 542] = 1.0; g_A[(size_t)bs * KE + 543] = 0.0;
        put_Ab((size_t)bs * KE + 542, 1.0f); put_Ab((size_t)bs * KE + 543, 0.0f);
    }
}

// ---------------- f64 vector GEMM (Aproj only) ----------------
__global__ __launch_bounds__(256) void gemm_f64(
    const double* __restrict__ A, int lda,
    const float* __restrict__ W, int ldw,
    double* __restrict__ C, int ldc,
    int M, int N, int K) {
    __shared__ double As[16][66];
    __shared__ double Ws[16][66];
    int m0 = blockIdx.x * 64, n0 = blockIdx.y * 64;
    int tid = threadIdx.x, tx = tid & 15, ty = tid >> 4;
    double acc[4][4] = {};
    for (int k0 = 0; k0 < K; k0 += 16) {
        for (int i = tid; i < 1024; i += 256) {
            int r = i >> 4, c = i & 15;
            As[c][r] = (m0 + r < M && k0 + c < K) ? A[(size_t)(m0 + r) * lda + k0 + c] : 0.0;
            Ws[c][r] = (n0 + r < N && k0 + c < K) ? (double)W[(size_t)(n0 + r) * ldw + k0 + c] : 0.0;
        }
        __syncthreads();
#pragma unroll
        for (int kk = 0; kk < 16; ++kk) {
            double a0 = As[kk][ty*4], a1 = As[kk][ty*4+1], a2 = As[kk][ty*4+2], a3 = As[kk][ty*4+3];
            double w0 = Ws[kk][tx*4], w1 = Ws[kk][tx*4+1], w2 = Ws[kk][tx*4+2], w3 = Ws[kk][tx*4+3];
            acc[0][0] += a0*w0; acc[0][1] += a0*w1; acc[0][2] += a0*w2; acc[0][3] += a0*w3;
            acc[1][0] += a1*w0; acc[1][1] += a1*w1; acc[1][2] += a1*w2; acc[1][3] += a1*w3;
            acc[2][0] += a2*w0; acc[2][1] += a2*w1; acc[2][2] += a2*w2; acc[2][3] += a2*w3;
            acc[3][0] += a3*w0; acc[3][1] += a3*w1; acc[3][2] += a3*w2; acc[3][3] += a3*w3;
        }
        __syncthreads();
    }
#pragma unroll
    for (int i = 0; i < 4; ++i)
#pragma unroll
        for (int j = 0; j < 4; ++j) {
            int m = m0 + ty*4 + i, n = n0 + tx*4 + j;
            if (m < M && n < N) C[(size_t)m * ldc + n] = acc[i][j];
        }
}

// ---------------- reverse LSTM ----------------
__global__ __launch_bounds__(64) void rev_lstm(const float* __restrict__ Whh) {
    int b = blockIdx.x;
    int tid = threadIdx.x;
    __shared__ double h[10], cc[10], g[40], wsh[400];
    for (int i = tid; i < 400; i += 64) wsh[i] = (double)Whh[i];
    if (tid < 10) { h[tid] = 0.0; cc[tid] = 0.0; }
    __syncthreads();
    for (int s = NS - 1; s >= 0; --s) {
        if (tid < 40) {
            double acc = g_Aproj[((size_t)b * NS + s) * 40 + tid];
#pragma unroll
            for (int k = 0; k < 10; ++k) acc += h[k] * wsh[tid * 10 + k];
            g[tid] = acc;
        }
        __syncthreads();
        if (tid < 10) {
            double gi = g[tid], gf = g[10 + tid], gg = g[20 + tid], go = g[30 + tid];
            double cn = sigd(gf) * cc[tid] + sigd(gi) * tanh(gg);
            cc[tid] = cn;
            double hn = sigd(go) * tanh(cn);
            h[tid] = hn;
            size_t ix = ((size_t)b * NS + s) * KE + 512 + tid;
            g_A[ix] = hn;
            put_Ab(ix, (float)hn);
        }
        __syncthreads();
    }
}

// ---------------- conv1d + relu ----------------
__global__ __launch_bounds__(256) void conv_relu(const float* __restrict__ w) {
    int b = blockIdx.x, s0 = blockIdx.y * 8;
    int tid = threadIdx.x, grp = tid >> 5, lane = tid & 31;
    __shared__ double xs[10][ND];
    for (int i = tid; i < 10 * ND; i += 256) {
        int r = i >> 9, d = i & (ND - 1);
        int s = s0 - 1 + r;
        xs[r][d] = (s >= 0 && s < NS) ? g_A[((size_t)b * NS + s) * KE + d] : 0.0;
    }
    __syncthreads();
    int s = s0 + grp;
    for (int o = 0; o < 20; ++o) {
        const float* wo = w + (size_t)o * 1536;
        double acc = 0.0;
        for (int d = lane; d < ND; d += 32) {
            acc += xs[grp][d]     * (double)wo[d*3]
                 + xs[grp + 1][d] * (double)wo[d*3 + 1]
                 + xs[grp + 2][d] * (double)wo[d*3 + 2];
        }
        for (int m = 16; m > 0; m >>= 1) acc += __shfl_xor(acc, m, 32);
        if (lane == 0) {
            double v = acc > 0.0 ? acc : 0.0;
            size_t ix = ((size_t)b * NS + s) * KE + 522 + o;
            g_A[ix] = v;
            put_Ab(ix, (float)v);
        }
    }
}

// ---------------- big GEMM: g_Pre[t][b][n] = g_A @ g_Wext^T ----------------
__global__ __launch_bounds__(256) void big_gemm() {
    __shared__ __align__(16) unsigned char shms[36864];
    int tid = threadIdx.x;
    int n0 = blockIdx.x * 64, m0 = blockIdx.y * 64;
    if (g_ok) {
        u16* usA = (u16*)shms;
        u16* usB = usA + 9216;
        int lane = tid & 63, wave = tid >> 6;
        int wm = (wave & 1) * 32, wn = (wave >> 1) * 32;
        int lr = lane & 15, lk = lane >> 4;
        f4v z = {0.f,0.f,0.f,0.f};
        f4v aP00=z,aP01=z,aP10=z,aP11=z, aC00=z,aC01=z,aC10=z,aC11=z;
        for (int k0 = 0; k0 < KE; k0 += 32) {
            for (int i = tid; i < 1536; i += 256) {
                if (i < 768) {
                    int p = i >> 8, rem = i & 255, r = rem >> 2, sg = rem & 3;
                    *(uint4*)(void*)(usA + p*3072 + r*48 + sg*8) =
                        *(const uint4*)(const void*)(g_Ab + (size_t)p*PSA + (size_t)(m0+r)*KE + k0 + sg*8);
                } else {
                    int j = i - 768;
                    int p = j >> 8, rem = j & 255, r = rem >> 2, sg = rem & 3;
                    *(uint4*)(void*)(usB + p*3072 + r*48 + sg*8) =
                        *(const uint4*)(const void*)(g_Wextb + (size_t)p*PSWE + (size_t)(n0+r)*KE + k0 + sg*8);
                }
            }
            __syncthreads();
            const u16* pa = usA + (wm + lr) * 48 + 8 * lk;
            const u16* pb = usB + (wn + lr) * 48 + 8 * lk;
            s8v a0_0 = *(const s8v*)(const void*)(pa);
            s8v a0_1 = *(const s8v*)(const void*)(pa + 768);
            s8v a1_0 = *(const s8v*)(const void*)(pa + 3072);
            s8v a1_1 = *(const s8v*)(const void*)(pa + 3840);
            s8v a2_0 = *(const s8v*)(const void*)(pa + 6144);
            s8v a2_1 = *(const s8v*)(const void*)(pa + 6912);
            s8v b0_0 = *(const s8v*)(const void*)(pb);
            s8v b0_1 = *(const s8v*)(const void*)(pb + 768);
            s8v b1_0 = *(const s8v*)(const void*)(pb + 3072);
            s8v b1_1 = *(const s8v*)(const void*)(pb + 3840);
            s8v b2_0 = *(const s8v*)(const void*)(pb + 6144);
            s8v b2_1 = *(const s8v*)(const void*)(pb + 6912);
            STEP6(aP00, aC00, a0_0, a1_0, a2_0, b0_0, b1_0, b2_0)
            STEP6(aP01, aC01, a0_0, a1_0, a2_0, b0_1, b1_1, b2_1)
            STEP6(aP10, aC10, a0_1, a1_1, a2_1, b0_0, b1_0, b2_0)
            STEP6(aP11, aC11, a0_1, a1_1, a2_1, b0_1, b1_1, b2_1)
            __syncthreads();
        }
        int rb = m0 + wm + 4 * lk, cb0 = n0 + wn + lr, cb1 = cb0 + 16;
#pragma unroll
        for (int r = 0; r < 4; ++r) {
            g_Pre[pre_ix(rb + r, cb0)]      = aP00[r] + aC00[r];
            g_Pre[pre_ix(rb + r, cb1)]      = aP01[r] + aC01[r];
            g_Pre[pre_ix(rb + 16 + r, cb0)] = aP10[r] + aC10[r];
            g_Pre[pre_ix(rb + 16 + r, cb1)] = aP11[r] + aC11[r];
        }
    } else {
        double* Asd = (double*)shms;
        double* Wsd = Asd + 64 * 33;
        int tx = tid & 15, ty = tid >> 4;
        double acc[4][4] = {};
        for (int k0 = 0; k0 < KE; k0 += 32) {
            for (int i = tid; i < 2048; i += 256) {
                int r = i >> 5, c = i & 31;
                Asd[r * 33 + c] = g_A[(size_t)(m0 + r) * KE + k0 + c];
                Wsd[r * 33 + c] = (double)g_Wext[(size_t)(n0 + r) * KE + k0 + c];
            }
            __syncthreads();
            for (int kk = 0; kk < 32; ++kk) {
                double a0 = Asd[(ty*4)*33+kk], a1 = Asd[(ty*4+1)*33+kk], a2 = Asd[(ty*4+2)*33+kk], a3 = Asd[(ty*4+3)*33+kk];
                double w0 = Wsd[(tx*4)*33+kk], w1 = Wsd[(tx*4+1)*33+kk], w2 = Wsd[(tx*4+2)*33+kk], w3 = Wsd[(tx*4+3)*33+kk];
                acc[0][0] += a0*w0; acc[0][1] += a0*w1; acc[0][2] += a0*w2; acc[0][3] += a0*w3;
                acc[1][0] += a1*w0; acc[1][1] += a1*w1; acc[1][2] += a1*w2; acc[1][3] += a1*w3;
                acc[2][0] += a2*w0; acc[2][1] += a2*w1; acc[2][2] += a2*w2; acc[2][3] += a2*w3;
                acc[3][0] += a3*w0; acc[3][1] += a3*w1; acc[3][2] += a3*w2; acc[3][3] += a3*w3;
            }
            __syncthreads();
        }
#pragma unroll
        for (int i = 0; i < 4; ++i)
#pragma unroll
            for (int j = 0; j < 4; ++j)
                g_Pre[pre_ix(m0 + ty*4 + i, n0 + tx*4 + j)] = (float)acc[i][j];
    }
}

// ---------------- sample-verify g_Pre ----------------
__global__ void verify_pre() {
    int s = blockIdx.x * 256 + threadIdx.x;
    unsigned m = ((unsigned)s * 2654435761u) & 32767u;
    unsigned n = ((unsigned)s * 40503u + 7u) % 2560u;
    double dot = 0.0;
    const double* ar = g_A + (size_t)m * KE;
    const float*  wr = g_Wext + (size_t)n * KE;
    for (int c = 0; c < KE; ++c) dot += ar[c] * (double)wr[c];
    double got = (double)g_Pre[pre_ix((int)m, (int)n)];
    if (fabs(got - dot) > 1e-4 * (1.0 + fabs(dot))) atomicOr(&g_bad, 1);
}

// ---------------- full vector recompute of g_Pre (only if ok && bad) ----------------
__global__ __launch_bounds__(256) void big_fix() {
    if (!(g_ok && g_bad)) return;
    __shared__ double As[64][33];
    __shared__ double Ws[64][33];
    int tid = threadIdx.x, tx = tid & 15, ty = tid >> 4;
    for (int tile = blockIdx.x; tile < (NC/64) * (NBS/64); tile += gridDim.x) {
        int n0 = (tile % (NC/64)) * 64, m0 = (tile / (NC/64)) * 64;
        double acc[4][4] = {};
        for (int k0 = 0; k0 < KE; k0 += 32) {
            for (int i = tid; i < 2048; i += 256) {
                int r = i >> 5, c = i & 31;
                As[r][c] = g_A[(size_t)(m0 + r) * KE + k0 + c];
                Ws[r][c] = (double)g_Wext[(size_t)(n0 + r) * KE + k0 + c];
            }
            __syncthreads();
            for (int kk = 0; kk < 32; ++kk) {
                double a0 = As[ty*4][kk], a1 = As[ty*4+1][kk], a2 = As[ty*4+2][kk], a3 = As[ty*4+3][kk];
                double w0 = Ws[tx*4][kk], w1 = Ws[tx*4+1][kk], w2 = Ws[tx*4+2][kk], w3 = Ws[tx*4+3][kk];
                acc[0][0] += a0*w0; acc[0][1] += a0*w1; acc[0][2] += a0*w2; acc[0][3] += a0*w3;
                acc[1][0] += a1*w0; acc[1][1] += a1*w1; acc[1][2] += a1*w2; acc[1][3] += a1*w3;
                acc[2][0] += a2*w0; acc[2][1] += a2*w1; acc[2][2] += a2*w2; acc[2][3] += a2*w3;
                acc[3][0] += a3*w0; acc[3][1] += a3*w1; acc[3][2] += a3*w2; acc[3][3] += a3*w3;
            }
            __syncthreads();
        }
#pragma unroll
        for (int i = 0; i < 4; ++i)
#pragma unroll
            for (int j = 0; j < 4; ++j)
                g_Pre[pre_ix(m0 + ty*4 + i, n0 + tx*4 + j)] = (float)acc[i][j];
        __syncthreads();
    }
}

// ---------------- synthetic hx (cached + sc sets) ----------------
__global__ void synth_hx() {
    int i = blockIdx.x * 256 + threadIdx.x;
    if (i >= NB * ND) return;
    unsigned h = (unsigned)i * 2654435761u;
    float v = (float)((h >> 8) & 0xFFFFu) / 65536.0f - 0.5f;
    g_hx[i] = (double)v;
    u16 b0, b1, b2; decomp3(v, b0, b1, b2);
    g_hxb[i] = b0; g_hxb[PSH + i] = b1; g_hxb[2 * PSH + i] = b2;
    sc_store_u16(g_hxbG + i, b0);
    sc_store_u16(g_hxbG + PSH + i, b1);
    sc_store_u16(g_hxbG + 2 * PSH + i, b2);
}

// ---------------- standalone step GEMM (probe + host ladder; cached set) ----------------
__global__ __launch_bounds__(256) void step_gemm(int t, int probe) {
    __shared__ double shd[3168];
    int tid = threadIdx.x;
    int m0 = blockIdx.x * 32, n0 = blockIdx.y * 64;
    int use_mfma = g_ok && (probe || !g_badstep);
    if (use_mfma) {
        int lane = tid & 63, wave = tid >> 6;
        int wm = (wave & 1) * 16, wn = (wave >> 1) * 32;
        int lr = lane & 15, lk = lane >> 4;
        size_t ha  = (size_t)(m0 + wm + lr) * ND;
        size_t wb0 = (size_t)(n0 + wn + lr) * ND;
        size_t wb1 = (size_t)(n0 + wn + 16 + lr) * ND;
        f4v z = {0.f,0.f,0.f,0.f};
        f4v aP0=z, aP1=z, aC0=z, aC1=z;
        for (int k0 = 0; k0 < ND; k0 += 32) {
            int kk = k0 + 8 * lk;
            s8v a0  = *(const s8v*)(const void*)(g_hxb + ha + kk);
            s8v a1  = *(const s8v*)(const void*)(g_hxb + PSH + ha + kk);
            s8v a2  = *(const s8v*)(const void*)(g_hxb + 2*PSH + ha + kk);
            s8v b00 = *(const s8v*)(const void*)(g_Wstepb + wb0 + kk);
            s8v b01 = *(const s8v*)(const void*)(g_Wstepb + wb1 + kk);
            s8v b10 = *(const s8v*)(const void*)(g_Wstepb + PSWS + wb0 + kk);
            s8v b11 = *(const s8v*)(const void*)(g_Wstepb + PSWS + wb1 + kk);
            s8v b20 = *(const s8v*)(const void*)(g_Wstepb + 2*PSWS + wb0 + kk);
            s8v b21 = *(const s8v*)(const void*)(g_Wstepb + 2*PSWS + wb1 + kk);
            STEP6(aP0, aC0, a0, a1, a2, b00, b10, b20)
            STEP6(aP1, aC1, a0, a1, a2, b01, b11, b21)
        }
        int rb = m0 + wm + 4 * lk, cb0 = n0 + wn + lr, cb1 = cb0 + 16;
#pragma unroll
        for (int r = 0; r < 4; ++r) {
            g_gbufF[(size_t)(rb + r) * NC + cb0] = aP0[r] + aC0[r]
                + g_Pre[((size_t)t * NB + rb + r) * NC + cb0];
            g_gbufF[(size_t)(rb + r) * NC + cb1] = aP1[r] + aC1[r]
                + g_Pre[((size_t)t * NB + rb + r) * NC + cb1];
        }
    } else {
        double* Asd = shd;
        double* Wsd = shd + 1056;
        int tx = tid & 15, ty = tid >> 4;
        double acc[2][4] = {};
        for (int k0 = 0; k0 < ND; k0 += 32) {
            for (int i = tid; i < 1024; i += 256) {
                int r = i >> 5, c = i & 31;
                Asd[r * 33 + c] = g_hx[(size_t)(m0 + r) * ND + k0 + c];
            }
            for (int i = tid; i < 2048; i += 256) {
                int r = i >> 5, c = i & 31;
                Wsd[r * 33 + c] = (double)g_Wstep[(size_t)(n0 + r) * ND + k0 + c];
            }
            __syncthreads();
            for (int kk = 0; kk < 32; ++kk) {
                double a0 = Asd[(ty*2)*33+kk], a1 = Asd[(ty*2+1)*33+kk];
                double w0 = Wsd[(tx*4)*33+kk], w1 = Wsd[(tx*4+1)*33+kk], w2 = Wsd[(tx*4+2)*33+kk], w3 = Wsd[(tx*4+3)*33+kk];
                acc[0][0] += a0*w0; acc[0][1] += a0*w1; acc[0][2] += a0*w2; acc[0][3] += a0*w3;
                acc[1][0] += a1*w0; acc[1][1] += a1*w1; acc[1][2] += a1*w2; acc[1][3] += a1*w3;
            }
            __syncthreads();
        }
#pragma unroll
        for (int i = 0; i < 2; ++i)
#pragma unroll
            for (int j = 0; j < 4; ++j) {
                int m = m0 + ty*2 + i, n = n0 + tx*4 + j;
                g_gbufF[(size_t)m * NC + n] = (float)(acc[i][j]
                    + (double)g_Pre[((size_t)t * NB + m) * NC + n]);
            }
    }
}

// ---------------- verify standalone step ----------------
__global__ void verify_step() {
    int s = blockIdx.x * 256 + threadIdx.x;
    unsigned m = ((unsigned)s * 2654435761u) & 127u;
    unsigned n = ((unsigned)s * 40503u + 7u) % 2560u;
    double dot = 0.0;
    const double* hr = g_hx + (size_t)m * ND;
    const float*  wr = g_Wstep + (size_t)n * ND;
    for (int c = 0; c < ND; ++c) dot += hr[c] * (double)wr[c];
    dot += (double)g_Pre[(size_t)m * NC + n];
    double got = (double)g_gbufF[(size_t)m * NC + n];
    if (fabs(got - dot) > 1e-4 * (1.0 + fabs(dot))) atomicOr(&g_badstep, 1);
}

// ---------------- verify fused probe output (sc buffers) ----------------
__global__ void verify_fused(const float* __restrict__ W2) {
    int s = blockIdx.x * 256 + threadIdx.x;    // 4096 samples
    unsigned m = ((unsigned)s * 2654435761u) & 127u;
    unsigned h2 = (unsigned)s * 40503u + 7u;
    const double* hr = g_hx + (size_t)m * ND;
    if (s & 1) {
        unsigned q = h2 & 31u;
        double p0 = 0.0, p1 = 0.0;
        for (int c = 0; c < 16; ++c) {
            int col = q * 16 + c;
            const float* wr = g_Wstep + (size_t)(2048 + col) * ND;
            double dot = 0.0;
            for (int k = 0; k < ND; ++k) dot += hr[k] * (double)wr[k];
            dot += (double)g_Pre[(size_t)m * NC + 2048 + col];
            double hh = dot > 0.0 ? dot : 0.0;
            p0 += hh * (double)W2[col];
            p1 += hh * (double)W2[512 + col];
        }
        if (fabs(g_lpartG[q][m][0] - p0) > 1e-4 * (1.0 + fabs(p0)) ||
            fabs(g_lpartG[q][m][1] - p1) > 1e-4 * (1.0 + fabs(p1)))
            atomicOr(&g_badfused, 1);
    } else {
        unsigned n = h2 % 2048u;
        double dot = 0.0;
        const float* wr = g_Wstep + (size_t)n * ND;
        for (int k = 0; k < ND; ++k) dot += hr[k] * (double)wr[k];
        dot += (double)g_Pre[(size_t)m * NC + n];
        double got = (double)g_gbufG[(size_t)m * 2048 + n];
        if (fabs(got - dot) > 1e-4 * (1.0 + fabs(dot))) atomicOr(&g_badfused, 1);
    }
}

// ---------------- standalone per-step update (host ladder; cached set) ----------------
__global__ __launch_bounds__(256) void step_update(
    const float* __restrict__ W2, const float* __restrict__ b2,
    const int* __restrict__ lengths, int t) {
    __shared__ double red[8];
    __shared__ double skipsh[2];
    int b = blockIdx.x, tid = threadIdx.x, lane = tid & 63, wave = tid >> 6;
    const float* gb = g_gbufF + (size_t)b * NC;
    double p0 = 0.0, p1 = 0.0;
    for (int j = tid; j < ND; j += 256) {
        double h = (double)gb[2048 + j];
        h = h > 0.0 ? h : 0.0;
        p0 += h * (double)W2[j];
        p1 += h * (double)W2[ND + j];
    }
    for (int off = 32; off > 0; off >>= 1) {
        p0 += __shfl_down(p0, off, 64);
        p1 += __shfl_down(p1, off, 64);
    }
    if (lane == 0) { red[wave*2] = p0; red[wave*2+1] = p1; }
    __syncthreads();
    if (tid == 0) {
        double l0 = red[0]+red[2]+red[4]+red[6] + (double)b2[0];
        double l1 = red[1]+red[3]+red[5]+red[7] + (double)b2[1];
        double mx = fmax(l0, l1);
        double sh0 = l0 - mx, sh1 = l1 - mx;
        double lsum = log(exp(sh0) + exp(sh1));
        double y0 = (sh0 - lsum) - g_gum[(size_t)t * (NB * 2) + b * 2 + 0];
        double y1 = (sh1 - lsum) - g_gum[(size_t)t * (NB * 2) + b * 2 + 1];
        double xx0 = y0 / 1e-5, xx1 = y1 / 1e-5;
        double mm = fmax(xx0, xx1);
        double e0 = exp(xx0 - mm), e1 = exp(xx1 - mm);
        double inv = 1.0 / (e0 + e1);
        skipsh[0] = e0 * inv; skipsh[1] = e1 * inv;
    }
    __syncthreads();
    double s0 = skipsh[0], s1 = skipsh[1];
    bool isFinal = (t == lengths[b] - 1);
#pragma unroll
    for (int e = 0; e < 2; ++e) {
        int j = tid + 256 * e;
        size_t ix = (size_t)b * ND + j;
        double gi = (double)gb[j], gf = (double)gb[ND + j];
        double gg = (double)gb[2*ND + j], go = (double)gb[3*ND + j];
        double cn = sigd(gf) * g_c[ix] + sigd(gi) * tanh(gg);
        double shx = sigd(go) * tanh(cn);
        double hn = g_hx[ix] * s1 + shx * s0;
        g_c[ix] = cn; g_hx[ix] = hn;
        u16 w0, w1, w2x; decomp3((float)hn, w0, w1, w2x);
        g_hxb[ix] = w0; g_hxb[PSH + ix] = w1; g_hxb[2 * PSH + ix] = w2x;
        if (isFinal) g_final[ix] = hn;
    }
}

// ---------------- persistent flag-synced loop (r13 structure: 160 blocks x 16 cols) ----------------
__global__ __launch_bounds__(512, 1) void loop_fused(const float* __restrict__ W2,
                                                     const float* __restrict__ b2,
                                                     const int* __restrict__ lengths,
                                                     int steps, int probe) {
    __shared__ __align__(16) unsigned char shm[53504];
    int bid = blockIdx.x, tid = threadIdx.x;
    int nc0 = bid * 16;
    int w = tid >> 6, lane = tid & 63;
    int lr = lane & 15, lk = lane >> 4;
    int path = g_ok && !g_badfused;
    double c0 = 0.0, h0 = 0.0;                 // register state elem (row=bid, j=tid)
    int mylen = (bid < NB) ? lengths[bid] : -1;
    u16*    Wl     = (u16*)shm;                // 48KB bf16x3 weights (path)
    float*  Wfb    = (float*)shm;              // fallback overlay (stride 521, 33KB)
    float*  W2l    = (float*)(shm + 49152);    // 4KB
    double* skipsh = (double*)(shm + 53248);
    if (path) {
        for (int i = tid; i < 3072; i += 512) {
            int p = i >> 10, rem = i & 1023, kk = rem >> 6, l = rem & 63;
            int col = l & 15, k8 = l >> 4;
            *(uint4*)(void*)(Wl + (size_t)p*8192 + kk*512 + l*8) =
                *(const uint4*)(const void*)(g_Wstepb + (size_t)p*PSWS
                      + (size_t)(nc0 + col)*ND + kk*32 + k8*8);
        }
    } else {
        for (int i = tid; i < 16*512; i += 512)
            Wfb[(i >> 9)*521 + (i & 511)] = g_Wstep[(size_t)(nc0 + (i >> 9))*ND + (i & 511)];
    }
    for (int i = tid; i < 1024; i += 512) W2l[i] = W2[i];
    __syncthreads();
    int r0 = 16*w + 4*lk;
    float preA[4];
    if (path) {
#pragma unroll
        for (int r = 0; r < 4; ++r)
            preA[r] = g_Pre[((size_t)0 * NB + r0 + r) * NC + nc0 + lr];
    }
    for (int t = 0; t < steps; ++t) {
        if (path) {
            // ================= SC PATH (no fences) =================
            if (t > 0) {
                for (;;) {
                    bool ok = true;
                    if (lane < 16)
                        ok = (__hip_atomic_load(&g_hxf[(16*w + lane)*32],
                               __ATOMIC_RELAXED, __HIP_MEMORY_SCOPE_AGENT) >= t);
                    if (__all(ok)) break;
                    __builtin_amdgcn_s_sleep(1);
                }
            }
            f4v z = {0.f,0.f,0.f,0.f};
            f4v aP = z, aC = z;
            size_t ha = (size_t)(16*w + lr) * ND;
#pragma unroll
            for (int h = 0; h < 2; ++h) {
                uv4 U0[8], U1[8], U2[8];
#pragma unroll
                for (int kk = 0; kk < 8; ++kk) {     // issue 24 MALL loads
                    int kb = (8*h + kk)*32 + 8*lk;
                    const u16* p0 = g_hxbG + ha + kb;
                    const u16* p1 = g_hxbG + PSH + ha + kb;
                    const u16* p2 = g_hxbG + 2*PSH + ha + kb;
                    asm volatile("global_load_dwordx4 %0, %3, off sc0 sc1\n\t"
                                 "global_load_dwordx4 %1, %4, off sc0 sc1\n\t"
                                 "global_load_dwordx4 %2, %5, off sc0 sc1"
                                 : "=v"(U0[kk]), "=v"(U1[kk]), "=v"(U2[kk])
                                 : "v"(p0), "v"(p1), "v"(p2));
                }
                SC_WAIT();
#pragma unroll
                for (int kk = 0; kk < 8; ++kk) {     // consume
                    const u16* wp = Wl + (8*h + kk)*512 + lane*8;
                    s8v B0 = *(const s8v*)(const void*)(wp);
                    s8v B1 = *(const s8v*)(const void*)(wp + 8192);
                    s8v B2 = *(const s8v*)(const void*)(wp + 16384);
                    s8v A0 = __builtin_bit_cast(s8v, U0[kk]);
                    s8v A1 = __builtin_bit_cast(s8v, U1[kk]);
                    s8v A2 = __builtin_bit_cast(s8v, U2[kk]);
                    STEP6(aP, aC, A0, A1, A2, B0, B1, B2)
                }
            }
            if (bid < NB) {
#pragma unroll
                for (int r = 0; r < 4; ++r) {
                    float v = aP[r] + aC[r] + preA[r];
                    sc_store_f32(g_gbufG + (size_t)(r0 + r) * 2048 + nc0 + lr, v);
                }
            } else {
                int colg = nc0 - 2048 + lr;
                double q0[4], q1[4];
#pragma unroll
                for (int r = 0; r < 4; ++r) {
                    float v = aP[r] + aC[r] + preA[r];
                    double hh = v > 0.f ? (double)v : 0.0;
                    q0[r] = hh * (double)W2l[colg];
                    q1[r] = hh * (double)W2l[512 + colg];
                }
#pragma unroll
                for (int m = 8; m > 0; m >>= 1)
#pragma unroll
                    for (int r = 0; r < 4; ++r) {
                        q0[r] += __shfl_xor(q0[r], m, 16);
                        q1[r] += __shfl_xor(q1[r], m, 16);
                    }
                if (lr == 0) {
#pragma unroll
                    for (int r = 0; r < 4; ++r) {
                        dv2 q; q[0] = q0[r]; q[1] = q1[r];
                        sc_store_d2(&g_lpartG[bid - NB][r0 + r][0], q);
                    }
                }
            }
            asm volatile("s_waitcnt vmcnt(0)" ::: "memory");
            __syncthreads();
            if (tid == 0)
                __hip_atomic_store(&g_aflag[bid*32], t + 1, __ATOMIC_RELAXED,
                                   __HIP_MEMORY_SCOPE_AGENT);
            __syncthreads();
            {   // prefetch next Pre slice (read-only, cached & warm)
                int tn = (t + 1 < steps) ? t + 1 : t;
#pragma unroll
                for (int r = 0; r < 4; ++r)
                    preA[r] = g_Pre[((size_t)tn * NB + r0 + r) * NC + nc0 + lr];
            }
            // ---- phase B (row owner) ----
            if (!probe && bid < NB) {
                if (tid < 160) {
                    while (__hip_atomic_load(&g_aflag[tid*32], __ATOMIC_RELAXED,
                             __HIP_MEMORY_SCOPE_AGENT) < t + 1)
                        __builtin_amdgcn_s_sleep(1);
                }
                __syncthreads();
                float gi_f, gf_f, gg_f, go_f;
                {
                    const float* gp = g_gbufG + (size_t)bid * 2048 + tid;
                    asm volatile("global_load_dword %0, %4, off sc0 sc1\n\t"
                                 "global_load_dword %1, %5, off sc0 sc1\n\t"
                                 "global_load_dword %2, %6, off sc0 sc1\n\t"
                                 "global_load_dword %3, %7, off sc0 sc1"
                                 : "=v"(gi_f), "=v"(gf_f), "=v"(gg_f), "=v"(go_f)
                                 : "v"(gp), "v"(gp + 512), "v"(gp + 1024), "v"(gp + 1536));
                }
                double p0 = 0.0, p1 = 0.0;
                if (tid < 32) {
                    dv2 lp;
                    const double* lpp = &g_lpartG[tid][bid][0];
                    asm volatile("global_load_dwordx4 %0, %1, off sc0 sc1"
                                 : "=v"(lp) : "v"(lpp));
                    asm volatile("s_waitcnt vmcnt(0)" ::: "memory");
                    p0 = lp[0]; p1 = lp[1];
                }
                __builtin_amdgcn_sched_barrier(0);
                if (tid < 64) {
#pragma unroll
                    for (int m = 16; m > 0; m >>= 1) {
                        p0 += __shfl_xor(p0, m, 32);
                        p1 += __shfl_xor(p1, m, 32);
                    }
                }
                if (tid == 0) {
                    double l0 = p0 + (double)b2[0], l1 = p1 + (double)b2[1];
                    double mx = fmax(l0, l1);
                    double sh0 = l0 - mx, sh1 = l1 - mx;
                    double lsum = log(exp(sh0) + exp(sh1));
                    double y0 = (sh0 - lsum) - g_gum[(size_t)t * (NB*2) + bid*2 + 0];
                    double y1 = (sh1 - lsum) - g_gum[(size_t)t * (NB*2) + bid*2 + 1];
                    double xx0 = y0 / 1e-5, xx1 = y1 / 1e-5;
                    double mm = fmax(xx0, xx1);
                    double e0 = exp(xx0 - mm), e1 = exp(xx1 - mm);
                    double inv = 1.0 / (e0 + e1);
                    skipsh[0] = e0 * inv; skipsh[1] = e1 * inv;
                }
                __syncthreads();
                SC_WAIT();                           // gbuf loads ready
                double s0 = skipsh[0], s1 = skipsh[1];
                bool isFinal = (t == mylen - 1);
                size_t ix = (size_t)bid * ND + tid;
                double gi = (double)gi_f, gf = (double)gf_f;
                double gg = (double)gg_f, go = (double)go_f;
                double cn = sigd(gf) * c0 + sigd(gi) * tanh(gg);
                double shx = sigd(go) * tanh(cn);
                double hn = h0 * s1 + shx * s0;
                c0 = cn; h0 = hn;
                u16 w0_, w1_, w2_; decomp3((float)hn, w0_, w1_, w2_);
                sc_store_u16(g_hxbG + ix, w0_);
                sc_store_u16(g_hxbG + PSH + ix, w1_);
                sc_store_u16(g_hxbG + 2*PSH + ix, w2_);
                if (isFinal) g_final[ix] = hn;
                asm volatile("s_waitcnt vmcnt(0)" ::: "memory");
                __syncthreads();
                if (tid == 0)
                    __hip_atomic_store(&g_hxf[bid*32], t + 1, __ATOMIC_RELAXED,
                                       __HIP_MEMORY_SCOPE_AGENT);
            }
        } else {
            // ================= FENCED FALLBACK (f64 vector, cached set) =================
            if (t > 0) {
                if (tid < NB) {
                    while (__hip_atomic_load(&g_hxf[tid*32], __ATOMIC_RELAXED,
                             __HIP_MEMORY_SCOPE_AGENT) < t)
                        __builtin_amdgcn_s_sleep(1);
                }
                __syncthreads();
                if (tid == 0) __builtin_amdgcn_fence(__ATOMIC_ACQUIRE, "agent");
                __syncthreads();
            }
            int col = tid & 15, rgrp = tid >> 4;
            double q0[4] = {}, q1[4] = {};
#pragma unroll
            for (int rr = 0; rr < 4; ++rr) {
                int row = rgrp*4 + rr;
                const double* hr = g_hx + (size_t)row * ND;
                double dot = 0.0;
                for (int k = 0; k < ND; ++k) dot += hr[k] * (double)Wfb[col*521 + k];
                float v = (float)(dot + (double)g_Pre[((size_t)t * NB + row) * NC + nc0 + col]);
                if (bid < NB) {
                    g_gbufF[(size_t)row * 2048 + nc0 + col] = v;
                } else {
                    double hh = v > 0.f ? (double)v : 0.0;
                    q0[rr] = hh * (double)W2l[nc0 - 2048 + col];
                    q1[rr] = hh * (double)W2l[512 + nc0 - 2048 + col];
                }
            }
            if (bid >= NB) {
#pragma unroll
                for (int m = 8; m > 0; m >>= 1)
#pragma unroll
                    for (int rr = 0; rr < 4; ++rr) {
                        q0[rr] += __shfl_xor(q0[rr], m, 16);
                        q1[rr] += __shfl_xor(q1[rr], m, 16);
                    }
                if (col == 0)
#pragma unroll
                    for (int rr = 0; rr < 4; ++rr) {
                        g_lpart[bid - NB][rgrp*4 + rr][0] = q0[rr];
                        g_lpart[bid - NB][rgrp*4 + rr][1] = q1[rr];
                    }
            }
            __syncthreads();
            if (tid == 0) {
                __builtin_amdgcn_fence(__ATOMIC_RELEASE, "agent");
                __hip_atomic_store(&g_aflag[bid*32], t + 1, __ATOMIC_RELAXED,
                                   __HIP_MEMORY_SCOPE_AGENT);
            }
            __syncthreads();
            if (!probe && bid < NB) {
                if (tid < 160) {
                    while (__hip_atomic_load(&g_aflag[tid*32], __ATOMIC_RELAXED,
                             __HIP_MEMORY_SCOPE_AGENT) < t + 1)
                        __builtin_amdgcn_s_sleep(1);
                }
                __syncthreads();
                if (tid == 0) __builtin_amdgcn_fence(__ATOMIC_ACQUIRE, "agent");
                __syncthreads();
                double p0 = 0.0, p1 = 0.0;
                if (tid < 32) { p0 = g_lpart[tid][bid][0]; p1 = g_lpart[tid][bid][1]; }
                if (tid < 64) {
#pragma unroll
                    for (int m = 16; m > 0; m >>= 1) {
                        p0 += __shfl_xor(p0, m, 32);
                        p1 += __shfl_xor(p1, m, 32);
                    }
                }
                if (tid == 0) {
                    double l0 = p0 + (double)b2[0], l1 = p1 + (double)b2[1];
                    double mx = fmax(l0, l1);
                    double sh0 = l0 - mx, sh1 = l1 - mx;
                    double lsum = log(exp(sh0) + exp(sh1));
                    double y0 = (sh0 - lsum) - g_gum[(size_t)t * (NB*2) + bid*2 + 0];
                    double y1 = (sh1 - lsum) - g_gum[(size_t)t * (NB*2) + bid*2 + 1];
                    double xx0 = y0 / 1e-5, xx1 = y1 / 1e-5;
                    double mm = fmax(xx0, xx1);
                    double e0 = exp(xx0 - mm), e1 = exp(xx1 - mm);
                    double inv = 1.0 / (e0 + e1);
                    skipsh[0] = e0 * inv; skipsh[1] = e1 * inv;
                }
                __syncthreads();
                double s0 = skipsh[0], s1 = skipsh[1];
                bool isFinal = (t == mylen - 1);
                int j = tid;
                size_t ix = (size_t)bid * ND + j;
                const float* gb = g_gbufF + (size_t)bid * 2048;
                double gi = (double)gb[j], gf = (double)gb[512 + j];
                double gg = (double)gb[1024 + j], go = (double)gb[1536 + j];
                double cn = sigd(gf) * c0 + sigd(gi) * tanh(gg);
                double shx = sigd(go) * tanh(cn);
                double hn = h0 * s1 + shx * s0;
                c0 = cn; h0 = hn;
                g_hx[ix] = hn;
                if (isFinal) g_final[ix] = hn;
                __syncthreads();
                if (tid == 0) {
                    __builtin_amdgcn_fence(__ATOMIC_RELEASE, "agent");
                    __hip_atomic_store(&g_hxf[bid*32], t + 1, __ATOMIC_RELAXED,
                                       __HIP_MEMORY_SCOPE_AGENT);
                }
            }
        }
    }
}

// ---------------- final projection ----------------
__global__ __launch_bounds__(256) void final_out(const float* __restrict__ Wo,
                                                 const float* __restrict__ bo,
                                                 float* __restrict__ out) {
    int tid = threadIdx.x;
    int b = tid >> 1, k = tid & 1;
    double acc = 0.0;
    const double* f = g_final + (size_t)b * ND;
    const float* w = Wo + (size_t)k * ND;
    for (int d = 0; d < ND; ++d) acc += f[d] * (double)w[d];
    out[b * 2 + k] = (float)(acc + (double)bo[k]);
}

// ---------------- host launcher ----------------
extern "C" void kernel_launch(void* const* d_in, const int* in_sizes, int n_in,
                              void* d_out, int out_size, void* d_ws, size_t ws_size,
                              hipStream_t stream) {
    (void)in_sizes; (void)n_in; (void)d_ws; (void)ws_size; (void)out_size;
    const int*   seqs    = (const int*)d_in[0];
    const int*   lengths = (const int*)d_in[2];
    const float* emb     = (const float*)d_in[5];
    const float* revWih  = (const float*)d_in[6];
    const float* revWhh  = (const float*)d_in[7];
    const float* convw   = (const float*)d_in[8];
    const float* W1      = (const float*)d_in[9];
    const float* b1      = (const float*)d_in[10];
    const float* W2      = (const float*)d_in[11];
    const float* b2      = (const float*)d_in[12];
    const float* cWih    = (const float*)d_in[13];
    const float* cWhh    = (const float*)d_in[14];
    const float* Wo      = (const float*)d_in[15];
    const float* bo      = (const float*)d_in[16];
    float* out = (float*)d_out;

    double *A_p = nullptr, *Ap_p = nullptr;
    hipGetSymbolAddress((void**)&A_p,  HIP_SYMBOL(g_A));
    hipGetSymbolAddress((void**)&Ap_p, HIP_SYMBOL(g_Aproj));

    probe_bf16<<<1, 64, 0, stream>>>();
    build_w<<<NC, 256, 0, stream>>>(cWih, cWhh, W1, b1);
    gumbel_init<<<256, 256, 0, stream>>>();
    embed_sum<<<NBS, 128, 0, stream>>>(seqs, emb);

    gemm_f64<<<dim3(NBS / 64, 1), 256, 0, stream>>>(A_p, KE, revWih, ND, Ap_p, 40,
                                                    NBS, 40, ND);
    rev_lstm<<<NB, 64, 0, stream>>>(revWhh);
    conv_relu<<<dim3(NB, NS / 8), 256, 0, stream>>>(convw);

    big_gemm<<<dim3(NC / 64, NBS / 64), 256, 0, stream>>>();
    verify_pre<<<32, 256, 0, stream>>>();
    big_fix<<<2048, 256, 0, stream>>>();

    // probes on synthetic state
    synth_hx<<<256, 256, 0, stream>>>();
    step_gemm<<<dim3(4, 40), 256, 0, stream>>>(0, 1);
    verify_step<<<8, 256, 0, stream>>>();
    {   // fused sc-path phase-A probe (1 step, B skipped)
        int steps1 = 1, probe1 = 1;
        void* pargs[] = { (void*)&W2, (void*)&b2, (void*)&lengths,
                          (void*)&steps1, (void*)&probe1 };
        hipError_t pe = hipLaunchCooperativeKernel((const void*)loop_fused,
                                                   dim3(160), dim3(512), pargs, 0, stream);
        if (pe == hipSuccess) verify_fused<<<16, 256, 0, stream>>>(W2);
        else (void)hipGetLastError();
    }
    init_state<<<256, 256, 0, stream>>>();   // resets state + flags + hxbG(sc)

    int stepsN = NS, probe0 = 0;
    void* args[] = { (void*)&W2, (void*)&b2, (void*)&lengths,
                     (void*)&stepsN, (void*)&probe0 };
    hipError_t ce = hipLaunchCooperativeKernel((const void*)loop_fused,
                                               dim3(160), dim3(512), args, 0, stream);
    if (ce != hipSuccess) {
        (void)hipGetLastError();
        for (int t = 0; t < NS; ++t) {
            step_gemm<<<dim3(4, 40), 256, 0, stream>>>(t, 0);
            step_update<<<NB, 256, 0, stream>>>(W2, b2, lengths, t);
        }
    }
    final_out<<<1, 256, 0, stream>>>(Wo, bo, out);
}

// Round 18
// 8889.426 us; speedup vs baseline: 26.4811x; 1.0216x over previous
//
#include <hip/hip_runtime.h>
#include <math.h>

#define NB 128
#define NS 256
#define ND 512
#define NBS (NB*NS)   // 32768
#define KE 544        // 512 x | 10 back | 20 cnn | 1 bias | 1 pad
#define NC 2560       // 2048 cell gates + 512 leap hidden

typedef unsigned short u16;
typedef __attribute__((ext_vector_type(8))) short s8v;     // 8 bf16
typedef __attribute__((ext_vector_type(4))) float f4v;     // 4 f32 acc
typedef __attribute__((ext_vector_type(4))) unsigned uv4;  // 16B asm payload
typedef __attribute__((ext_vector_type(2))) double dv2;    // 16B asm payload

static constexpr size_t PSA  = (size_t)NBS * KE;
static constexpr size_t PSWE = (size_t)NC  * KE;
static constexpr size_t PSWS = (size_t)NC  * ND;
static constexpr size_t PSH  = (size_t)NB  * ND;

// ---------------- device-global scratch ----------------
// cached-only set (preamble, fallback, host ladder):
__device__ double g_A[(size_t)NBS * KE];
__device__ u16    g_Ab[3 * PSA];
__device__ float  g_Pre[(size_t)NBS * NC];    // [t][b][n]
__device__ double g_Aproj[(size_t)NBS * 40];
__device__ double g_gum[NS * NB * 2];
__device__ double g_hx[NB * ND];
__device__ u16    g_hxb[3 * NB * ND];
__device__ double g_c[NB * ND];
__device__ float  g_gbufF[NB * NC];
__device__ double g_final[NB * ND];
__device__ float  g_Wext[PSWE];
__device__ u16    g_Wextb[3 * PSWE];
__device__ float  g_Wstep[PSWS];
__device__ u16    g_Wstepb[3 * PSWS];
__device__ double g_lpart[32][NB][2];
// sc-only set (persistent loop; written only via sc0sc1):
__device__ u16    g_hxbG[3 * NB * ND];
__device__ float  g_gbufG[NB * 2048];
__device__ double g_lpartG[32][NB][2];
// flags (atomics — coherence point):
__device__ int    g_aflag[160 * 32];
__device__ int    g_hxf[NB * 32];
__device__ int    g_ok, g_bad, g_badstep, g_badfused;

__device__ __forceinline__ double sigd(double x) { return 1.0 / (1.0 + exp(-x)); }
__device__ __forceinline__ u16 f2bf(float f) {
    unsigned u = __float_as_uint(f);
    return (u16)((u + 0x7FFFu + ((u >> 16) & 1u)) >> 16);   // RNE
}
__device__ __forceinline__ float bf2f(u16 b) { return __uint_as_float(((unsigned)b) << 16); }
__device__ __forceinline__ void decomp3(float f, u16& b0, u16& b1, u16& b2) {
    b0 = f2bf(f); float r1 = f - bf2f(b0);
    b1 = f2bf(r1); float r2 = r1 - bf2f(b1);
    b2 = f2bf(r2);
}
__device__ __forceinline__ size_t pre_ix(int m, int n) {
    return ((size_t)(m & 255) * NB + (m >> 8)) * NC + n;    // -> [s][b][n]
}
__device__ __forceinline__ void put_Ab(size_t ix, float f) {
    u16 b0, b1, b2; decomp3(f, b0, b1, b2);
    g_Ab[ix] = b0; g_Ab[PSA + ix] = b1; g_Ab[2 * PSA + ix] = b2;
}

// ---- coherence-point (MALL) access helpers ----
__device__ __forceinline__ void sc_store_f32(float* p, float v) {
    asm volatile("global_store_dword %0, %1, off sc0 sc1" :: "v"(p), "v"(v) : "memory");
}
__device__ __forceinline__ void sc_store_u16(u16* p, unsigned v) {
    asm volatile("global_store_short %0, %1, off sc0 sc1" :: "v"(p), "v"(v) : "memory");
}
__device__ __forceinline__ void sc_store_u32(void* p, unsigned v) {
    asm volatile("global_store_dword %0, %1, off sc0 sc1" :: "v"(p), "v"(v) : "memory");
}
__device__ __forceinline__ void sc_store_d2(double* p, dv2 v) {
    asm volatile("global_store_dwordx4 %0, %1, off sc0 sc1" :: "v"(p), "v"(v) : "memory");
}
#define SC_WAIT() do { asm volatile("s_waitcnt vmcnt(0)" ::: "memory"); \
                       __builtin_amdgcn_sched_barrier(0); } while (0)

#define MFMA_BF16 __builtin_amdgcn_mfma_f32_16x16x32_bf16
#define STEP6(AP,AC,A0,A1,A2,B0,B1,B2) \
    AP = MFMA_BF16(A0, B0, AP, 0, 0, 0); \
    AC = MFMA_BF16(A0, B1, AC, 0, 0, 0); \
    AC = MFMA_BF16(A1, B0, AC, 0, 0, 0); \
    AC = MFMA_BF16(A0, B2, AC, 0, 0, 0); \
    AC = MFMA_BF16(A1, B1, AC, 0, 0, 0); \
    AC = MFMA_BF16(A2, B0, AC, 0, 0, 0);

// ---------------- bf16 MFMA layout probe ----------------
__global__ void probe_bf16() {
    int l = threadIdx.x, lr = l & 15, lk = l >> 4;
    s8v a, b;
#pragma unroll
    for (int e = 0; e < 8; ++e) {
        int k = 8 * lk + e;
        a[e] = (short)f2bf((float)(((3 * lr + 7 * k) % 13) + 1));
        b[e] = (short)f2bf((float)(((5 * k + 11 * lr) % 17) + 1));
    }
    f4v d = {0.f, 0.f, 0.f, 0.f};
    d = MFMA_BF16(a, b, d, 0, 0, 0);
    bool okl = true;
#pragma unroll
    for (int r = 0; r < 4; ++r) {
        int row = 4 * lk + r, col = lr;
        int e = 0;
        for (int k = 0; k < 32; ++k)
            e += (((3 * row + 7 * k) % 13) + 1) * (((5 * k + 11 * col) % 17) + 1);
        if (d[r] != (float)e) okl = false;
    }
    unsigned long long vote = __ballot(okl);
    if (l == 0) {
        g_ok = (vote == 0xFFFFFFFFFFFFFFFFull) ? 1 : 0;
        g_bad = 0; g_badstep = 0; g_badfused = 0;
    }
}

// ---------------- init (state + flags; hxbG via sc only) ----------------
__global__ void init_state() {
    int i = blockIdx.x * 256 + threadIdx.x;
    if (i < 160 * 32) g_aflag[i] = 0;
    if (i < NB * 32)  g_hxf[i]  = 0;
    if (i < NB * ND) {
        g_hx[i] = 0.0; g_c[i] = 0.0;
        g_hxb[i] = 0; g_hxb[PSH + i] = 0; g_hxb[2 * PSH + i] = 0;
    }
    if (i < NB * ND / 2) {
#pragma unroll
        for (int p = 0; p < 3; ++p)
            sc_store_u32((void*)(g_hxbG + (size_t)p * PSH + 2 * i), 0u);
    }
}

// ---------------- weight repack + bf16x3 ----------------
__global__ __launch_bounds__(256) void build_w(const float* __restrict__ cWih,
                                               const float* __restrict__ cWhh,
                                               const float* __restrict__ W1,
                                               const float* __restrict__ b1) {
    int n = blockIdx.x;
    for (int c = threadIdx.x; c < KE; c += 256) {
        float we;
        if (n < 2048) we = (c < 512) ? cWih[(size_t)n * 512 + c] : 0.f;
        else {
            int n2 = n - 2048;
            if      (c < 512)  we = W1[(size_t)n2 * 1054 + 512 + c];
            else if (c < 522)  we = W1[(size_t)n2 * 1054 + 1024 + (c - 512)];
            else if (c < 542)  we = W1[(size_t)n2 * 1054 + 1034 + (c - 522)];
            else if (c == 542) we = b1[n2];
            else               we = 0.f;
        }
        size_t ix = (size_t)n * KE + c;
        g_Wext[ix] = we;
        u16 b0, b1_, b2; decomp3(we, b0, b1_, b2);
        g_Wextb[ix] = b0; g_Wextb[PSWE + ix] = b1_; g_Wextb[2 * PSWE + ix] = b2;
        if (c < 512) {
            float ws = (n < 2048) ? cWhh[(size_t)n * 512 + c]
                                  : W1[(size_t)(n - 2048) * 1054 + c];
            size_t ix2 = (size_t)n * ND + c;
            g_Wstep[ix2] = ws;
            decomp3(ws, b0, b1_, b2);
            g_Wstepb[ix2] = b0; g_Wstepb[PSWS + ix2] = b1_; g_Wstepb[2 * PSWS + ix2] = b2;
        }
    }
}

// ---------------- gumbel: JAX partitionable threefry2x32, key (0,42) ----------------
__device__ __forceinline__ unsigned rotl32(unsigned x, int r) { return (x << r) | (x >> (32 - r)); }

__global__ void gumbel_init() {
    unsigned p = blockIdx.x * 256 + threadIdx.x;
    if (p >= 65536u) return;
    unsigned k0 = 0u, k1 = 42u;
    unsigned ks2 = k0 ^ k1 ^ 0x1BD11BDAu;
    unsigned x0 = 0u, x1 = p;
    x0 += k0; x1 += k1;
#define RND(r) { x0 += x1; x1 = rotl32(x1, (r)); x1 ^= x0; }
    RND(13) RND(15) RND(26) RND(6)
    x0 += k1;  x1 += ks2 + 1u;
    RND(17) RND(29) RND(16) RND(24)
    x0 += ks2; x1 += k0 + 2u;
    RND(13) RND(15) RND(26) RND(6)
    x0 += k0;  x1 += k1 + 3u;
    RND(17) RND(29) RND(16) RND(24)
    x0 += k1;  x1 += ks2 + 4u;
    RND(13) RND(15) RND(26) RND(6)
    x0 += ks2; x1 += k0 + 5u;
#undef RND
    unsigned bits = x0 ^ x1;
    float u = __uint_as_float((bits >> 9) | 0x3f800000u) - 1.0f;
    g_gum[p] = log(-log((double)u + 1e-20) + 1e-20);
}

// ---------------- embedding gather+sum ----------------
__global__ __launch_bounds__(128) void embed_sum(const int* __restrict__ seqs,
                                                 const float* __restrict__ emb) {
    int bs = blockIdx.x;
    int tid = threadIdx.x;
    __shared__ int idxs[16];
    if (tid < 16) idxs[tid] = seqs[(size_t)bs * 16 + tid];
    __syncthreads();
    double a0 = 0, a1 = 0, a2 = 0, a3 = 0;
    for (int v = 0; v < 16; ++v) {
        const float4* row = (const float4*)(emb + (size_t)idxs[v] * ND);
        float4 e = row[tid];
        a0 += (double)e.x; a1 += (double)e.y; a2 += (double)e.z; a3 += (double)e.w;
    }
    size_t base = (size_t)bs * KE + tid * 4;
    double* o = g_A + base;
    o[0] = a0; o[1] = a1; o[2] = a2; o[3] = a3;
    put_Ab(base + 0, (float)a0); put_Ab(base + 1, (float)a1);
    put_Ab(base + 2, (float)a2); put_Ab(base + 3, (float)a3);
    if (tid == 0) {
        g_A[(size_t)bs * KE + 542] = 1.0; g_A[(size_t)bs * KE + 543] = 0.0;
        put_Ab((size_t)bs * KE + 542, 1.0f); put_Ab((size_t)bs * KE + 543, 0.0f);
    }
}

// ---------------- f64 vector GEMM (Aproj only) ----------------
__global__ __launch_bounds__(256) void gemm_f64(
    const double* __restrict__ A, int lda,
    const float* __restrict__ W, int ldw,
    double* __restrict__ C, int ldc,
    int M, int N, int K) {
    __shared__ double As[16][66];
    __shared__ double Ws[16][66];
    int m0 = blockIdx.x * 64, n0 = blockIdx.y * 64;
    int tid = threadIdx.x, tx = tid & 15, ty = tid >> 4;
    double acc[4][4] = {};
    for (int k0 = 0; k0 < K; k0 += 16) {
        for (int i = tid; i < 1024; i += 256) {
            int r = i >> 4, c = i & 15;
            As[c][r] = (m0 + r < M && k0 + c < K) ? A[(size_t)(m0 + r) * lda + k0 + c] : 0.0;
            Ws[c][r] = (n0 + r < N && k0 + c < K) ? (double)W[(size_t)(n0 + r) * ldw + k0 + c] : 0.0;
        }
        __syncthreads();
#pragma unroll
        for (int kk = 0; kk < 16; ++kk) {
            double a0 = As[kk][ty*4], a1 = As[kk][ty*4+1], a2 = As[kk][ty*4+2], a3 = As[kk][ty*4+3];
            double w0 = Ws[kk][tx*4], w1 = Ws[kk][tx*4+1], w2 = Ws[kk][tx*4+2], w3 = Ws[kk][tx*4+3];
            acc[0][0] += a0*w0; acc[0][1] += a0*w1; acc[0][2] += a0*w2; acc[0][3] += a0*w3;
            acc[1][0] += a1*w0; acc[1][1] += a1*w1; acc[1][2] += a1*w2; acc[1][3] += a1*w3;
            acc[2][0] += a2*w0; acc[2][1] += a2*w1; acc[2][2] += a2*w2; acc[2][3] += a2*w3;
            acc[3][0] += a3*w0; acc[3][1] += a3*w1; acc[3][2] += a3*w2; acc[3][3] += a3*w3;
        }
        __syncthreads();
    }
#pragma unroll
    for (int i = 0; i < 4; ++i)
#pragma unroll
        for (int j = 0; j < 4; ++j) {
            int m = m0 + ty*4 + i, n = n0 + tx*4 + j;
            if (m < M && n < N) C[(size_t)m * ldc + n] = acc[i][j];
        }
}

// ---------------- reverse LSTM ----------------
__global__ __launch_bounds__(64) void rev_lstm(const float* __restrict__ Whh) {
    int b = blockIdx.x;
    int tid = threadIdx.x;
    __shared__ double h[10], cc[10], g[40], wsh[400];
    for (int i = tid; i < 400; i += 64) wsh[i] = (double)Whh[i];
    if (tid < 10) { h[tid] = 0.0; cc[tid] = 0.0; }
    __syncthreads();
    for (int s = NS - 1; s >= 0; --s) {
        if (tid < 40) {
            double acc = g_Aproj[((size_t)b * NS + s) * 40 + tid];
#pragma unroll
            for (int k = 0; k < 10; ++k) acc += h[k] * wsh[tid * 10 + k];
            g[tid] = acc;
        }
        __syncthreads();
        if (tid < 10) {
            double gi = g[tid], gf = g[10 + tid], gg = g[20 + tid], go = g[30 + tid];
            double cn = sigd(gf) * cc[tid] + sigd(gi) * tanh(gg);
            cc[tid] = cn;
            double hn = sigd(go) * tanh(cn);
            h[tid] = hn;
            size_t ix = ((size_t)b * NS + s) * KE + 512 + tid;
            g_A[ix] = hn;
            put_Ab(ix, (float)hn);
        }
        __syncthreads();
    }
}

// ---------------- conv1d + relu ----------------
__global__ __launch_bounds__(256) void conv_relu(const float* __restrict__ w) {
    int b = blockIdx.x, s0 = blockIdx.y * 8;
    int tid = threadIdx.x, grp = tid >> 5, lane = tid & 31;
    __shared__ double xs[10][ND];
    for (int i = tid; i < 10 * ND; i += 256) {
        int r = i >> 9, d = i & (ND - 1);
        int s = s0 - 1 + r;
        xs[r][d] = (s >= 0 && s < NS) ? g_A[((size_t)b * NS + s) * KE + d] : 0.0;
    }
    __syncthreads();
    int s = s0 + grp;
    for (int o = 0; o < 20; ++o) {
        const float* wo = w + (size_t)o * 1536;
        double acc = 0.0;
        for (int d = lane; d < ND; d += 32) {
            acc += xs[grp][d]     * (double)wo[d*3]
                 + xs[grp + 1][d] * (double)wo[d*3 + 1]
                 + xs[grp + 2][d] * (double)wo[d*3 + 2];
        }
        for (int m = 16; m > 0; m >>= 1) acc += __shfl_xor(acc, m, 32);
        if (lane == 0) {
            double v = acc > 0.0 ? acc : 0.0;
            size_t ix = ((size_t)b * NS + s) * KE + 522 + o;
            g_A[ix] = v;
            put_Ab(ix, (float)v);
        }
    }
}

// ---------------- big GEMM: g_Pre[t][b][n] = g_A @ g_Wext^T (128x128 tile) ----------------
__global__ __launch_bounds__(256) void big_gemm() {
    __shared__ __align__(16) unsigned char shms[61440];   // A 30KB | B 30KB (u16, [3][128][40])
    int tid = threadIdx.x;
    int n0 = blockIdx.x * 128, m0 = blockIdx.y * 128;
    if (g_ok) {
        u16* usA = (u16*)shms;
        u16* usB = usA + 15360;
        int lane = tid & 63, wave = tid >> 6;
        int wm = (wave & 1) * 64, wn = (wave >> 1) * 64;
        int lr = lane & 15, lk = lane >> 4;
        f4v acc[4][4];
#pragma unroll
        for (int i = 0; i < 4; ++i)
#pragma unroll
            for (int j = 0; j < 4; ++j) { f4v z = {0.f,0.f,0.f,0.f}; acc[i][j] = z; }
        for (int k0 = 0; k0 < KE; k0 += 32) {
            for (int i = tid; i < 3072; i += 256) {
                int isB = i >= 1536, ii = i - isB * 1536;
                int p = ii >> 9, rem = ii & 511, r = rem >> 2, sg = rem & 3;
                const u16* src = (isB ? g_Wextb + (size_t)p*PSWE + (size_t)(n0 + r)*KE
                                      : g_Ab   + (size_t)p*PSA  + (size_t)(m0 + r)*KE)
                                 + k0 + sg*8;
                u16* dst = (isB ? usB : usA) + p*5120 + r*40 + sg*8;
                *(uint4*)(void*)dst = *(const uint4*)(const void*)src;
            }
            __syncthreads();
            s8v Af[4][3];
#pragma unroll
            for (int fr = 0; fr < 4; ++fr)
#pragma unroll
                for (int p = 0; p < 3; ++p)
                    Af[fr][p] = *(const s8v*)(const void*)(usA + p*5120 + (wm + fr*16 + lr)*40 + 8*lk);
#pragma unroll
            for (int fc = 0; fc < 4; ++fc) {
                s8v B0 = *(const s8v*)(const void*)(usB + 0*5120 + (wn + fc*16 + lr)*40 + 8*lk);
                s8v B1 = *(const s8v*)(const void*)(usB + 1*5120 + (wn + fc*16 + lr)*40 + 8*lk);
                s8v B2 = *(const s8v*)(const void*)(usB + 2*5120 + (wn + fc*16 + lr)*40 + 8*lk);
#pragma unroll
                for (int fr = 0; fr < 4; ++fr) {
                    f4v a = acc[fr][fc];
                    a = MFMA_BF16(Af[fr][0], B0, a, 0, 0, 0);
                    a = MFMA_BF16(Af[fr][0], B1, a, 0, 0, 0);
                    a = MFMA_BF16(Af[fr][1], B0, a, 0, 0, 0);
                    a = MFMA_BF16(Af[fr][0], B2, a, 0, 0, 0);
                    a = MFMA_BF16(Af[fr][1], B1, a, 0, 0, 0);
                    a = MFMA_BF16(Af[fr][2], B0, a, 0, 0, 0);
                    acc[fr][fc] = a;
                }
            }
            __syncthreads();
        }
#pragma unroll
        for (int fr = 0; fr < 4; ++fr)
#pragma unroll
            for (int fc = 0; fc < 4; ++fc)
#pragma unroll
                for (int r = 0; r < 4; ++r)
                    g_Pre[pre_ix(m0 + wm + fr*16 + 4*lk + r, n0 + wn + fc*16 + lr)]
                        = acc[fr][fc][r];
    } else {
        double* Asd = (double*)shms;
        double* Wsd = Asd + 64 * 33;
        int tx = tid & 15, ty = tid >> 4;
        // fallback works on 64x64 quadrants of the 128x128 block, sequentially
        for (int qm = 0; qm < 2; ++qm)
        for (int qn = 0; qn < 2; ++qn) {
            int mq = m0 + qm * 64, nq = n0 + qn * 64;
            double acc[4][4] = {};
            for (int k0 = 0; k0 < KE; k0 += 32) {
                for (int i = tid; i < 2048; i += 256) {
                    int r = i >> 5, c = i & 31;
                    Asd[r * 33 + c] = g_A[(size_t)(mq + r) * KE + k0 + c];
                    Wsd[r * 33 + c] = (double)g_Wext[(size_t)(nq + r) * KE + k0 + c];
                }
                __syncthreads();
                for (int kk = 0; kk < 32; ++kk) {
                    double a0 = Asd[(ty*4)*33+kk], a1 = Asd[(ty*4+1)*33+kk], a2 = Asd[(ty*4+2)*33+kk], a3 = Asd[(ty*4+3)*33+kk];
                    double w0 = Wsd[(tx*4)*33+kk], w1 = Wsd[(tx*4+1)*33+kk], w2 = Wsd[(tx*4+2)*33+kk], w3 = Wsd[(tx*4+3)*33+kk];
                    acc[0][0] += a0*w0; acc[0][1] += a0*w1; acc[0][2] += a0*w2; acc[0][3] += a0*w3;
                    acc[1][0] += a1*w0; acc[1][1] += a1*w1; acc[1][2] += a1*w2; acc[1][3] += a1*w3;
                    acc[2][0] += a2*w0; acc[2][1] += a2*w1; acc[2][2] += a2*w2; acc[2][3] += a2*w3;
                    acc[3][0] += a3*w0; acc[3][1] += a3*w1; acc[3][2] += a3*w2; acc[3][3] += a3*w3;
                }
                __syncthreads();
            }
#pragma unroll
            for (int i = 0; i < 4; ++i)
#pragma unroll
                for (int j = 0; j < 4; ++j)
                    g_Pre[pre_ix(mq + ty*4 + i, nq + tx*4 + j)] = (float)acc[i][j];
            __syncthreads();
        }
    }
}

// ---------------- sample-verify g_Pre ----------------
__global__ void verify_pre() {
    int s = blockIdx.x * 256 + threadIdx.x;
    unsigned m = ((unsigned)s * 2654435761u) & 32767u;
    unsigned n = ((unsigned)s * 40503u + 7u) % 2560u;
    double dot = 0.0;
    const double* ar = g_A + (size_t)m * KE;
    const float*  wr = g_Wext + (size_t)n * KE;
    for (int c = 0; c < KE; ++c) dot += ar[c] * (double)wr[c];
    double got = (double)g_Pre[pre_ix((int)m, (int)n)];
    if (fabs(got - dot) > 1e-4 * (1.0 + fabs(dot))) atomicOr(&g_bad, 1);
}

// ---------------- full vector recompute of g_Pre (only if ok && bad) ----------------
__global__ __launch_bounds__(256) void big_fix() {
    if (!(g_ok && g_bad)) return;
    __shared__ double As[64][33];
    __shared__ double Ws[64][33];
    int tid = threadIdx.x, tx = tid & 15, ty = tid >> 4;
    for (int tile = blockIdx.x; tile < (NC/64) * (NBS/64); tile += gridDim.x) {
        int n0 = (tile % (NC/64)) * 64, m0 = (tile / (NC/64)) * 64;
        double acc[4][4] = {};
        for (int k0 = 0; k0 < KE; k0 += 32) {
            for (int i = tid; i < 2048; i += 256) {
                int r = i >> 5, c = i & 31;
                As[r][c] = g_A[(size_t)(m0 + r) * KE + k0 + c];
                Ws[r][c] = (double)g_Wext[(size_t)(n0 + r) * KE + k0 + c];
            }
            __syncthreads();
            for (int kk = 0; kk < 32; ++kk) {
                double a0 = As[ty*4][kk], a1 = As[ty*4+1][kk], a2 = As[ty*4+2][kk], a3 = As[ty*4+3][kk];
                double w0 = Ws[tx*4][kk], w1 = Ws[tx*4+1][kk], w2 = Ws[tx*4+2][kk], w3 = Ws[tx*4+3][kk];
                acc[0][0] += a0*w0; acc[0][1] += a0*w1; acc[0][2] += a0*w2; acc[0][3] += a0*w3;
                acc[1][0] += a1*w0; acc[1][1] += a1*w1; acc[1][2] += a1*w2; acc[1][3] += a1*w3;
                acc[2][0] += a2*w0; acc[2][1] += a2*w1; acc[2][2] += a2*w2; acc[2][3] += a2*w3;
                acc[3][0] += a3*w0; acc[3][1] += a3*w1; acc[3][2] += a3*w2; acc[3][3] += a3*w3;
            }
            __syncthreads();
        }
#pragma unroll
        for (int i = 0; i < 4; ++i)
#pragma unroll
            for (int j = 0; j < 4; ++j)
                g_Pre[pre_ix(m0 + ty*4 + i, n0 + tx*4 + j)] = (float)acc[i][j];
        __syncthreads();
    }
}

// ---------------- synthetic hx (cached + sc sets) ----------------
__global__ void synth_hx() {
    int i = blockIdx.x * 256 + threadIdx.x;
    if (i >= NB * ND) return;
    unsigned h = (unsigned)i * 2654435761u;
    float v = (float)((h >> 8) & 0xFFFFu) / 65536.0f - 0.5f;
    g_hx[i] = (double)v;
    u16 b0, b1, b2; decomp3(v, b0, b1, b2);
    g_hxb[i] = b0; g_hxb[PSH + i] = b1; g_hxb[2 * PSH + i] = b2;
    sc_store_u16(g_hxbG + i, b0);
    sc_store_u16(g_hxbG + PSH + i, b1);
    sc_store_u16(g_hxbG + 2 * PSH + i, b2);
}

// ---------------- standalone step GEMM (probe + host ladder; cached set) ----------------
__global__ __launch_bounds__(256) void step_gemm(int t, int probe) {
    __shared__ double shd[3168];
    int tid = threadIdx.x;
    int m0 = blockIdx.x * 32, n0 = blockIdx.y * 64;
    int use_mfma = g_ok && (probe || !g_badstep);
    if (use_mfma) {
        int lane = tid & 63, wave = tid >> 6;
        int wm = (wave & 1) * 16, wn = (wave >> 1) * 32;
        int lr = lane & 15, lk = lane >> 4;
        size_t ha  = (size_t)(m0 + wm + lr) * ND;
        size_t wb0 = (size_t)(n0 + wn + lr) * ND;
        size_t wb1 = (size_t)(n0 + wn + 16 + lr) * ND;
        f4v z = {0.f,0.f,0.f,0.f};
        f4v aP0=z, aP1=z, aC0=z, aC1=z;
        for (int k0 = 0; k0 < ND; k0 += 32) {
            int kk = k0 + 8 * lk;
            s8v a0  = *(const s8v*)(const void*)(g_hxb + ha + kk);
            s8v a1  = *(const s8v*)(const void*)(g_hxb + PSH + ha + kk);
            s8v a2  = *(const s8v*)(const void*)(g_hxb + 2*PSH + ha + kk);
            s8v b00 = *(const s8v*)(const void*)(g_Wstepb + wb0 + kk);
            s8v b01 = *(const s8v*)(const void*)(g_Wstepb + wb1 + kk);
            s8v b10 = *(const s8v*)(const void*)(g_Wstepb + PSWS + wb0 + kk);
            s8v b11 = *(const s8v*)(const void*)(g_Wstepb + PSWS + wb1 + kk);
            s8v b20 = *(const s8v*)(const void*)(g_Wstepb + 2*PSWS + wb0 + kk);
            s8v b21 = *(const s8v*)(const void*)(g_Wstepb + 2*PSWS + wb1 + kk);
            STEP6(aP0, aC0, a0, a1, a2, b00, b10, b20)
            STEP6(aP1, aC1, a0, a1, a2, b01, b11, b21)
        }
        int rb = m0 + wm + 4 * lk, cb0 = n0 + wn + lr, cb1 = cb0 + 16;
#pragma unroll
        for (int r = 0; r < 4; ++r) {
            g_gbufF[(size_t)(rb + r) * NC + cb0] = aP0[r] + aC0[r]
                + g_Pre[((size_t)t * NB + rb + r) * NC + cb0];
            g_gbufF[(size_t)(rb + r) * NC + cb1] = aP1[r] + aC1[r]
                + g_Pre[((size_t)t * NB + rb + r) * NC + cb1];
        }
    } else {
        double* Asd = shd;
        double* Wsd = shd + 1056;
        int tx = tid & 15, ty = tid >> 4;
        double acc[2][4] = {};
        for (int k0 = 0; k0 < ND; k0 += 32) {
            for (int i = tid; i < 1024; i += 256) {
                int r = i >> 5, c = i & 31;
                Asd[r * 33 + c] = g_hx[(size_t)(m0 + r) * ND + k0 + c];
            }
            for (int i = tid; i < 2048; i += 256) {
                int r = i >> 5, c = i & 31;
                Wsd[r * 33 + c] = (double)g_Wstep[(size_t)(n0 + r) * ND + k0 + c];
            }
            __syncthreads();
            for (int kk = 0; kk < 32; ++kk) {
                double a0 = Asd[(ty*2)*33+kk], a1 = Asd[(ty*2+1)*33+kk];
                double w0 = Wsd[(tx*4)*33+kk], w1 = Wsd[(tx*4+1)*33+kk], w2 = Wsd[(tx*4+2)*33+kk], w3 = Wsd[(tx*4+3)*33+kk];
                acc[0][0] += a0*w0; acc[0][1] += a0*w1; acc[0][2] += a0*w2; acc[0][3] += a0*w3;
                acc[1][0] += a1*w0; acc[1][1] += a1*w1; acc[1][2] += a1*w2; acc[1][3] += a1*w3;
            }
            __syncthreads();
        }
#pragma unroll
        for (int i = 0; i < 2; ++i)
#pragma unroll
            for (int j = 0; j < 4; ++j) {
                int m = m0 + ty*2 + i, n = n0 + tx*4 + j;
                g_gbufF[(size_t)m * NC + n] = (float)(acc[i][j]
                    + (double)g_Pre[((size_t)t * NB + m) * NC + n]);
            }
    }
}

// ---------------- verify standalone step ----------------
__global__ void verify_step() {
    int s = blockIdx.x * 256 + threadIdx.x;
    unsigned m = ((unsigned)s * 2654435761u) & 127u;
    unsigned n = ((unsigned)s * 40503u + 7u) % 2560u;
    double dot = 0.0;
    const double* hr = g_hx + (size_t)m * ND;
    const float*  wr = g_Wstep + (size_t)n * ND;
    for (int c = 0; c < ND; ++c) dot += hr[c] * (double)wr[c];
    dot += (double)g_Pre[(size_t)m * NC + n];
    double got = (double)g_gbufF[(size_t)m * NC + n];
    if (fabs(got - dot) > 1e-4 * (1.0 + fabs(dot))) atomicOr(&g_badstep, 1);
}

// ---------------- verify fused probe output (sc buffers) ----------------
__global__ void verify_fused(const float* __restrict__ W2) {
    int s = blockIdx.x * 256 + threadIdx.x;    // 4096 samples
    unsigned m = ((unsigned)s * 2654435761u) & 127u;
    unsigned h2 = (unsigned)s * 40503u + 7u;
    const double* hr = g_hx + (size_t)m * ND;
    if (s & 1) {
        unsigned q = h2 & 31u;
        double p0 = 0.0, p1 = 0.0;
        for (int c = 0; c < 16; ++c) {
            int col = q * 16 + c;
            const float* wr = g_Wstep + (size_t)(2048 + col) * ND;
            double dot = 0.0;
            for (int k = 0; k < ND; ++k) dot += hr[k] * (double)wr[k];
            dot += (double)g_Pre[(size_t)m * NC + 2048 + col];
            double hh = dot > 0.0 ? dot : 0.0;
            p0 += hh * (double)W2[col];
            p1 += hh * (double)W2[512 + col];
        }
        if (fabs(g_lpartG[q][m][0] - p0) > 1e-4 * (1.0 + fabs(p0)) ||
            fabs(g_lpartG[q][m][1] - p1) > 1e-4 * (1.0 + fabs(p1)))
            atomicOr(&g_badfused, 1);
    } else {
        unsigned n = h2 % 2048u;
        double dot = 0.0;
        const float* wr = g_Wstep + (size_t)n * ND;
        for (int k = 0; k < ND; ++k) dot += hr[k] * (double)wr[k];
        dot += (double)g_Pre[(size_t)m * NC + n];
        double got = (double)g_gbufG[(size_t)m * 2048 + n];
        if (fabs(got - dot) > 1e-4 * (1.0 + fabs(dot))) atomicOr(&g_badfused, 1);
    }
}

// ---------------- standalone per-step update (host ladder; cached set) ----------------
__global__ __launch_bounds__(256) void step_update(
    const float* __restrict__ W2, const float* __restrict__ b2,
    const int* __restrict__ lengths, int t) {
    __shared__ double red[8];
    __shared__ double skipsh[2];
    int b = blockIdx.x, tid = threadIdx.x, lane = tid & 63, wave = tid >> 6;
    const float* gb = g_gbufF + (size_t)b * NC;
    double p0 = 0.0, p1 = 0.0;
    for (int j = tid; j < ND; j += 256) {
        double h = (double)gb[2048 + j];
        h = h > 0.0 ? h : 0.0;
        p0 += h * (double)W2[j];
        p1 += h * (double)W2[ND + j];
    }
    for (int off = 32; off > 0; off >>= 1) {
        p0 += __shfl_down(p0, off, 64);
        p1 += __shfl_down(p1, off, 64);
    }
    if (lane == 0) { red[wave*2] = p0; red[wave*2+1] = p1; }
    __syncthreads();
    if (tid == 0) {
        double l0 = red[0]+red[2]+red[4]+red[6] + (double)b2[0];
        double l1 = red[1]+red[3]+red[5]+red[7] + (double)b2[1];
        double mx = fmax(l0, l1);
        double sh0 = l0 - mx, sh1 = l1 - mx;
        double lsum = log(exp(sh0) + exp(sh1));
        double y0 = (sh0 - lsum) - g_gum[(size_t)t * (NB * 2) + b * 2 + 0];
        double y1 = (sh1 - lsum) - g_gum[(size_t)t * (NB * 2) + b * 2 + 1];
        double xx0 = y0 / 1e-5, xx1 = y1 / 1e-5;
        double mm = fmax(xx0, xx1);
        double e0 = exp(xx0 - mm), e1 = exp(xx1 - mm);
        double inv = 1.0 / (e0 + e1);
        skipsh[0] = e0 * inv; skipsh[1] = e1 * inv;
    }
    __syncthreads();
    double s0 = skipsh[0], s1 = skipsh[1];
    bool isFinal = (t == lengths[b] - 1);
#pragma unroll
    for (int e = 0; e < 2; ++e) {
        int j = tid + 256 * e;
        size_t ix = (size_t)b * ND + j;
        double gi = (double)gb[j], gf = (double)gb[ND + j];
        double gg = (double)gb[2*ND + j], go = (double)gb[3*ND + j];
        double cn = sigd(gf) * g_c[ix] + sigd(gi) * tanh(gg);
        double shx = sigd(go) * tanh(cn);
        double hn = g_hx[ix] * s1 + shx * s0;
        g_c[ix] = cn; g_hx[ix] = hn;
        u16 w0, w1, w2x; decomp3((float)hn, w0, w1, w2x);
        g_hxb[ix] = w0; g_hxb[PSH + ix] = w1; g_hxb[2 * PSH + ix] = w2x;
        if (isFinal) g_final[ix] = hn;
    }
}

// ---------------- persistent flag-synced loop (160 blocks x 16 cols, sc path) ----------------
__global__ __launch_bounds__(512, 1) void loop_fused(const float* __restrict__ W2,
                                                     const float* __restrict__ b2,
                                                     const int* __restrict__ lengths,
                                                     int steps, int probe) {
    __shared__ __align__(16) unsigned char shm[53504];
    int bid = blockIdx.x, tid = threadIdx.x;
    int nc0 = bid * 16;
    int w = tid >> 6, lane = tid & 63;
    int lr = lane & 15, lk = lane >> 4;
    int path = g_ok && !g_badfused;
    double c0 = 0.0, h0 = 0.0;                 // register state elem (row=bid, j=tid)
    int mylen = (bid < NB) ? lengths[bid] : -1;
    u16*    Wl     = (u16*)shm;                // 48KB bf16x3 weights (path)
    float*  Wfb    = (float*)shm;              // fallback overlay (stride 521, 33KB)
    float*  W2l    = (float*)(shm + 49152);    // 4KB
    double* skipsh = (double*)(shm + 53248);
    if (path) {
        for (int i = tid; i < 3072; i += 512) {
            int p = i >> 10, rem = i & 1023, kk = rem >> 6, l = rem & 63;
            int col = l & 15, k8 = l >> 4;
            *(uint4*)(void*)(Wl + (size_t)p*8192 + kk*512 + l*8) =
                *(const uint4*)(const void*)(g_Wstepb + (size_t)p*PSWS
                      + (size_t)(nc0 + col)*ND + kk*32 + k8*8);
        }
    } else {
        for (int i = tid; i < 16*512; i += 512)
            Wfb[(i >> 9)*521 + (i & 511)] = g_Wstep[(size_t)(nc0 + (i >> 9))*ND + (i & 511)];
    }
    for (int i = tid; i < 1024; i += 512) W2l[i] = W2[i];
    __syncthreads();
    int r0 = 16*w + 4*lk;
    float preA[4];
    if (path) {
#pragma unroll
        for (int r = 0; r < 4; ++r)
            preA[r] = g_Pre[((size_t)0 * NB + r0 + r) * NC + nc0 + lr];
    }
    for (int t = 0; t < steps; ++t) {
        if (path) {
            // ================= SC PATH (no fences) =================
            if (t > 0) {
                for (;;) {
                    bool ok = true;
                    if (lane < 16)
                        ok = (__hip_atomic_load(&g_hxf[(16*w + lane)*32],
                               __ATOMIC_RELAXED, __HIP_MEMORY_SCOPE_AGENT) >= t);
                    if (__all(ok)) break;
                    __builtin_amdgcn_s_sleep(1);
                }
            }
            f4v z = {0.f,0.f,0.f,0.f};
            f4v aP = z, aC = z;
            size_t ha = (size_t)(16*w + lr) * ND;
#pragma unroll
            for (int h = 0; h < 2; ++h) {
                uv4 U0[8], U1[8], U2[8];
#pragma unroll
                for (int kk = 0; kk < 8; ++kk) {     // issue 24 MALL loads
                    int kb = (8*h + kk)*32 + 8*lk;
                    const u16* p0 = g_hxbG + ha + kb;
                    const u16* p1 = g_hxbG + PSH + ha + kb;
                    const u16* p2 = g_hxbG + 2*PSH + ha + kb;
                    asm volatile("global_load_dwordx4 %0, %3, off sc0 sc1\n\t"
                                 "global_load_dwordx4 %1, %4, off sc0 sc1\n\t"
                                 "global_load_dwordx4 %2, %5, off sc0 sc1"
                                 : "=v"(U0[kk]), "=v"(U1[kk]), "=v"(U2[kk])
                                 : "v"(p0), "v"(p1), "v"(p2));
                }
                SC_WAIT();
#pragma unroll
                for (int kk = 0; kk < 8; ++kk) {     // consume
                    const u16* wp = Wl + (8*h + kk)*512 + lane*8;
                    s8v B0 = *(const s8v*)(const void*)(wp);
                    s8v B1 = *(const s8v*)(const void*)(wp + 8192);
                    s8v B2 = *(const s8v*)(const void*)(wp + 16384);
                    s8v A0 = __builtin_bit_cast(s8v, U0[kk]);
                    s8v A1 = __builtin_bit_cast(s8v, U1[kk]);
                    s8v A2 = __builtin_bit_cast(s8v, U2[kk]);
                    STEP6(aP, aC, A0, A1, A2, B0, B1, B2)
                }
            }
            if (bid < NB) {
#pragma unroll
                for (int r = 0; r < 4; ++r) {
                    float v = aP[r] + aC[r] + preA[r];
                    sc_store_f32(g_gbufG + (size_t)(r0 + r) * 2048 + nc0 + lr, v);
                }
            } else {
                int colg = nc0 - 2048 + lr;
                double q0[4], q1[4];
#pragma unroll
                for (int r = 0; r < 4; ++r) {
                    float v = aP[r] + aC[r] + preA[r];
                    double hh = v > 0.f ? (double)v : 0.0;
                    q0[r] = hh * (double)W2l[colg];
                    q1[r] = hh * (double)W2l[512 + colg];
                }
#pragma unroll
                for (int m = 8; m > 0; m >>= 1)
#pragma unroll
                    for (int r = 0; r < 4; ++r) {
                        q0[r] += __shfl_xor(q0[r], m, 16);
                        q1[r] += __shfl_xor(q1[r], m, 16);
                    }
                if (lr == 0) {
#pragma unroll
                    for (int r = 0; r < 4; ++r) {
                        dv2 q; q[0] = q0[r]; q[1] = q1[r];
                        sc_store_d2(&g_lpartG[bid - NB][r0 + r][0], q);
                    }
                }
            }
            asm volatile("s_waitcnt vmcnt(0)" ::: "memory");
            __syncthreads();
            if (tid == 0)
                __hip_atomic_store(&g_aflag[bid*32], t + 1, __ATOMIC_RELAXED,
                                   __HIP_MEMORY_SCOPE_AGENT);
            __syncthreads();
            {   // prefetch next Pre slice (read-only, cached & warm)
                int tn = (t + 1 < steps) ? t + 1 : t;
#pragma unroll
                for (int r = 0; r < 4; ++r)
                    preA[r] = g_Pre[((size_t)tn * NB + r0 + r) * NC + nc0 + lr];
            }
            // ---- phase B (row owner) ----
            if (!probe && bid < NB) {
                if (tid < 160) {
                    while (__hip_atomic_load(&g_aflag[tid*32], __ATOMIC_RELAXED,
                             __HIP_MEMORY_SCOPE_AGENT) < t + 1)
                        __builtin_amdgcn_s_sleep(1);
                }
                __syncthreads();
                float gi_f, gf_f, gg_f, go_f;
                {
                    const float* gp = g_gbufG + (size_t)bid * 2048 + tid;
                    asm volatile("global_load_dword %0, %4, off sc0 sc1\n\t"
                                 "global_load_dword %1, %5, off sc0 sc1\n\t"
                                 "global_load_dword %2, %6, off sc0 sc1\n\t"
                                 "global_load_dword %3, %7, off sc0 sc1"
                                 : "=v"(gi_f), "=v"(gf_f), "=v"(gg_f), "=v"(go_f)
                                 : "v"(gp), "v"(gp + 512), "v"(gp + 1024), "v"(gp + 1536));
                }
                double p0 = 0.0, p1 = 0.0;
                if (tid < 32) {
                    dv2 lp;
                    const double* lpp = &g_lpartG[tid][bid][0];
                    asm volatile("global_load_dwordx4 %0, %1, off sc0 sc1"
                                 : "=v"(lp) : "v"(lpp));
                    asm volatile("s_waitcnt vmcnt(0)" ::: "memory");
                    p0 = lp[0]; p1 = lp[1];
                }
                __builtin_amdgcn_sched_barrier(0);
                if (tid < 64) {
#pragma unroll
                    for (int m = 16; m > 0; m >>= 1) {
                        p0 += __shfl_xor(p0, m, 32);
                        p1 += __shfl_xor(p1, m, 32);
                    }
                }
                if (tid == 0) {
                    double l0 = p0 + (double)b2[0], l1 = p1 + (double)b2[1];
                    double mx = fmax(l0, l1);
                    double sh0 = l0 - mx, sh1 = l1 - mx;
                    double lsum = log(exp(sh0) + exp(sh1));
                    double y0 = (sh0 - lsum) - g_gum[(size_t)t * (NB*2) + bid*2 + 0];
                    double y1 = (sh1 - lsum) - g_gum[(size_t)t * (NB*2) + bid*2 + 1];
                    double xx0 = y0 / 1e-5, xx1 = y1 / 1e-5;
                    double mm = fmax(xx0, xx1);
                    double e0 = exp(xx0 - mm), e1 = exp(xx1 - mm);
                    double inv = 1.0 / (e0 + e1);
                    skipsh[0] = e0 * inv; skipsh[1] = e1 * inv;
                }
                __syncthreads();
                SC_WAIT();                           // gbuf loads ready
                double s0 = skipsh[0], s1 = skipsh[1];
                bool isFinal = (t == mylen - 1);
                size_t ix = (size_t)bid * ND + tid;
                double gi = (double)gi_f, gf = (double)gf_f;
                double gg = (double)gg_f, go = (double)go_f;
                double cn = sigd(gf) * c0 + sigd(gi) * tanh(gg);
                double shx = sigd(go) * tanh(cn);
                double hn = h0 * s1 + shx * s0;
                c0 = cn; h0 = hn;
                u16 w0_, w1_, w2_; decomp3((float)hn, w0_, w1_, w2_);
                sc_store_u16(g_hxbG + ix, w0_);
                sc_store_u16(g_hxbG + PSH + ix, w1_);
                sc_store_u16(g_hxbG + 2*PSH + ix, w2_);
                if (isFinal) g_final[ix] = hn;
                asm volatile("s_waitcnt vmcnt(0)" ::: "memory");
                __syncthreads();
                if (tid == 0)
                    __hip_atomic_store(&g_hxf[bid*32], t + 1, __ATOMIC_RELAXED,
                                       __HIP_MEMORY_SCOPE_AGENT);
            }
        } else {
            // ================= FENCED FALLBACK (f64 vector, cached set) =================
            if (t > 0) {
                if (tid < NB) {
                    while (__hip_atomic_load(&g_hxf[tid*32], __ATOMIC_RELAXED,
                             __HIP_MEMORY_SCOPE_AGENT) < t)
                        __builtin_amdgcn_s_sleep(1);
                }
                __syncthreads();
                if (tid == 0) __builtin_amdgcn_fence(__ATOMIC_ACQUIRE, "agent");
                __syncthreads();
            }
            int col = tid & 15, rgrp = tid >> 4;
            double q0[4] = {}, q1[4] = {};
#pragma unroll
            for (int rr = 0; rr < 4; ++rr) {
                int row = rgrp*4 + rr;
                const double* hr = g_hx + (size_t)row * ND;
                double dot = 0.0;
                for (int k = 0; k < ND; ++k) dot += hr[k] * (double)Wfb[col*521 + k];
                float v = (float)(dot + (double)g_Pre[((size_t)t * NB + row) * NC + nc0 + col]);
                if (bid < NB) {
                    g_gbufF[(size_t)row * 2048 + nc0 + col] = v;
                } else {
                    double hh = v > 0.f ? (double)v : 0.0;
                    q0[rr] = hh * (double)W2l[nc0 - 2048 + col];
                    q1[rr] = hh * (double)W2l[512 + nc0 - 2048 + col];
                }
            }
            if (bid >= NB) {
#pragma unroll
                for (int m = 8; m > 0; m >>= 1)
#pragma unroll
                    for (int rr = 0; rr < 4; ++rr) {
                        q0[rr] += __shfl_xor(q0[rr], m, 16);
                        q1[rr] += __shfl_xor(q1[rr], m, 16);
                    }
                if (col == 0)
#pragma unroll
                    for (int rr = 0; rr < 4; ++rr) {
                        g_lpart[bid - NB][rgrp*4 + rr][0] = q0[rr];
                        g_lpart[bid - NB][rgrp*4 + rr][1] = q1[rr];
                    }
            }
            __syncthreads();
            if (tid == 0) {
                __builtin_amdgcn_fence(__ATOMIC_RELEASE, "agent");
                __hip_atomic_store(&g_aflag[bid*32], t + 1, __ATOMIC_RELAXED,
                                   __HIP_MEMORY_SCOPE_AGENT);
            }
            __syncthreads();
            if (!probe && bid < NB) {
                if (tid < 160) {
                    while (__hip_atomic_load(&g_aflag[tid*32], __ATOMIC_RELAXED,
                             __HIP_MEMORY_SCOPE_AGENT) < t + 1)
                        __builtin_amdgcn_s_sleep(1);
                }
                __syncthreads();
                if (tid == 0) __builtin_amdgcn_fence(__ATOMIC_ACQUIRE, "agent");
                __syncthreads();
                double p0 = 0.0, p1 = 0.0;
                if (tid < 32) { p0 = g_lpart[tid][bid][0]; p1 = g_lpart[tid][bid][1]; }
                if (tid < 64) {
#pragma unroll
                    for (int m = 16; m > 0; m >>= 1) {
                        p0 += __shfl_xor(p0, m, 32);
                        p1 += __shfl_xor(p1, m, 32);
                    }
                }
                if (tid == 0) {
                    double l0 = p0 + (double)b2[0], l1 = p1 + (double)b2[1];
                    double mx = fmax(l0, l1);
                    double sh0 = l0 - mx, sh1 = l1 - mx;
                    double lsum = log(exp(sh0) + exp(sh1));
                    double y0 = (sh0 - lsum) - g_gum[(size_t)t * (NB*2) + bid*2 + 0];
                    double y1 = (sh1 - lsum) - g_gum[(size_t)t * (NB*2) + bid*2 + 1];
                    double xx0 = y0 / 1e-5, xx1 = y1 / 1e-5;
                    double mm = fmax(xx0, xx1);
                    double e0 = exp(xx0 - mm), e1 = exp(xx1 - mm);
                    double inv = 1.0 / (e0 + e1);
                    skipsh[0] = e0 * inv; skipsh[1] = e1 * inv;
                }
                __syncthreads();
                double s0 = skipsh[0], s1 = skipsh[1];
                bool isFinal = (t == mylen - 1);
                int j = tid;
                size_t ix = (size_t)bid * ND + j;
                const float* gb = g_gbufF + (size_t)bid * 2048;
                double gi = (double)gb[j], gf = (double)gb[512 + j];
                double gg = (double)gb[1024 + j], go = (double)gb[1536 + j];
                double cn = sigd(gf) * c0 + sigd(gi) * tanh(gg);
                double shx = sigd(go) * tanh(cn);
                double hn = h0 * s1 + shx * s0;
                c0 = cn; h0 = hn;
                g_hx[ix] = hn;
                if (isFinal) g_final[ix] = hn;
                __syncthreads();
                if (tid == 0) {
                    __builtin_amdgcn_fence(__ATOMIC_RELEASE, "agent");
                    __hip_atomic_store(&g_hxf[bid*32], t + 1, __ATOMIC_RELAXED,
                                       __HIP_MEMORY_SCOPE_AGENT);
                }
            }
        }
    }
}

// ---------------- final projection ----------------
__global__ __launch_bounds__(256) void final_out(const float* __restrict__ Wo,
                                                 const float* __restrict__ bo,
                                                 float* __restrict__ out) {
    int tid = threadIdx.x;
    int b = tid >> 1, k = tid & 1;
    double acc = 0.0;
    const double* f = g_final + (size_t)b * ND;
    const float* w = Wo + (size_t)k * ND;
    for (int d = 0; d < ND; ++d) acc += f[d] * (double)w[d];
    out[b * 2 + k] = (float)(acc + (double)bo[k]);
}

// ---------------- host launcher ----------------
extern "C" void kernel_launch(void* const* d_in, const int* in_sizes, int n_in,
                              void* d_out, int out_size, void* d_ws, size_t ws_size,
                              hipStream_t stream) {
    (void)in_sizes; (void)n_in; (void)d_ws; (void)ws_size; (void)out_size;
    const int*   seqs    = (const int*)d_in[0];
    const int*   lengths = (const int*)d_in[2];
    const float* emb     = (const float*)d_in[5];
    const float* revWih  = (const float*)d_in[6];
    const float* revWhh  = (const float*)d_in[7];
    const float* convw   = (const float*)d_in[8];
    const float* W1      = (const float*)d_in[9];
    const float* b1      = (const float*)d_in[10];
    const float* W2      = (const float*)d_in[11];
    const float* b2      = (const float*)d_in[12];
    const float* cWih    = (const float*)d_in[13];
    const float* cWhh    = (const float*)d_in[14];
    const float* Wo      = (const float*)d_in[15];
    const float* bo      = (const float*)d_in[16];
    float* out = (float*)d_out;

    double *A_p = nullptr, *Ap_p = nullptr;
    hipGetSymbolAddress((void**)&A_p,  HIP_SYMBOL(g_A));
    hipGetSymbolAddress((void**)&Ap_p, HIP_SYMBOL(g_Aproj));

    probe_bf16<<<1, 64, 0, stream>>>();
    build_w<<<NC, 256, 0, stream>>>(cWih, cWhh, W1, b1);
    gumbel_init<<<256, 256, 0, stream>>>();
    embed_sum<<<NBS, 128, 0, stream>>>(seqs, emb);

    gemm_f64<<<dim3(NBS / 64, 1), 256, 0, stream>>>(A_p, KE, revWih, ND, Ap_p, 40,
                                                    NBS, 40, ND);
    rev_lstm<<<NB, 64, 0, stream>>>(revWhh);
    conv_relu<<<dim3(NB, NS / 8), 256, 0, stream>>>(convw);

    big_gemm<<<dim3(NC / 128, NBS / 128), 256, 0, stream>>>();
    verify_pre<<<32, 256, 0, stream>>>();
    big_fix<<<2048, 256, 0, stream>>>();

    // probes on synthetic state
    synth_hx<<<256, 256, 0, stream>>>();
    step_gemm<<<dim3(4, 40), 256, 0, stream>>>(0, 1);
    verify_step<<<8, 256, 0, stream>>>();
    {   // fused sc-path phase-A probe (1 step, B skipped)
        int steps1 = 1, probe1 = 1;
        void* pargs[] = { (void*)&W2, (void*)&b2, (void*)&lengths,
                          (void*)&steps1, (void*)&probe1 };
        hipError_t pe = hipLaunchCooperativeKernel((const void*)loop_fused,
                                                   dim3(160), dim3(512), pargs, 0, stream);
        if (pe == hipSuccess) verify_fused<<<16, 256, 0, stream>>>(W2);
        else (void)hipGetLastError();
    }
    init_state<<<256, 256, 0, stream>>>();   // resets state + flags + hxbG(sc)

    int stepsN = NS, probe0 = 0;
    void* args[] = { (void*)&W2, (void*)&b2, (void*)&lengths,
                     (void*)&stepsN, (void*)&probe0 };
    hipError_t ce = hipLaunchCooperativeKernel((const void*)loop_fused,
                                               dim3(160), dim3(512), args, 0, stream);
    if (ce != hipSuccess) {
        (void)hipGetLastError();
        for (int t = 0; t < NS; ++t) {
            step_gemm<<<dim3(4, 40), 256, 0, stream>>>(t, 0);
            step_update<<<NB, 256, 0, stream>>>(W2, b2, lengths, t);
        }
    }
    final_out<<<1, 256, 0, stream>>>(Wo, bo, out);
}